// Round 10
// baseline (1040.827 us; speedup 1.0000x reference)
//
#include <hip/hip_runtime.h>
#include <math.h>

// Graphormer3D forward — round 9: R8 + 32x32x16 MFMA GEMM K-loop
// (fewer matrix-pipe cycles per K-step), merged bias-weight cast.
// B=4 N=256 D=768 H=32 HD=24 L=12 F=3072 K=128
constexpr int B_ = 4, N_ = 256, D_ = 768, H_ = 32, HD_ = 24, L_ = 12, F_ = 3072, K_ = 128;
constexpr float SCALE_ = 0.20412414523193150f;   // HD^-0.5
constexpr float ISQRT2_ = 0.70710678118654752f;

typedef short bf16x8 __attribute__((ext_vector_type(8)));
typedef float f32x4 __attribute__((ext_vector_type(4)));
typedef float f32x16 __attribute__((ext_vector_type(16)));
typedef unsigned short u16x4 __attribute__((ext_vector_type(4)));
typedef unsigned short u16x8 __attribute__((ext_vector_type(8)));
typedef unsigned int u32x4 __attribute__((ext_vector_type(4)));

#define DEV __device__ __forceinline__
#define MFMA16(a, b, c) __builtin_amdgcn_mfma_f32_16x16x32_bf16(a, b, c, 0, 0, 0)
#define MFMA32(a, b, c) __builtin_amdgcn_mfma_f32_32x32x16_bf16(a, b, c, 0, 0, 0)

DEV void gload_lds16(const unsigned short* g, unsigned short* l) {
  __builtin_amdgcn_global_load_lds(
      (const __attribute__((address_space(1))) unsigned int*)(g),
      (__attribute__((address_space(3))) unsigned int*)(l), 16, 0, 0);
}

DEV float gelu_f(float x) { return 0.5f * x * (1.0f + erff(x * ISQRT2_)); }

DEV unsigned short f2bf(float f) {  // RNE f32 -> bf16
  unsigned u = __float_as_uint(f);
  return (unsigned short)((u + 0x7FFFu + ((u >> 16) & 1u)) >> 16);
}
DEV float bf2f(unsigned short u) { return __uint_as_float(((unsigned)u) << 16); }
DEV unsigned packbf(float a, float b) {
  return (unsigned)f2bf(a) | ((unsigned)f2bf(b) << 16);
}
DEV bf16x8 u4_to_bf8(u32x4 x) { union { u32x4 a; bf16x8 b; } u; u.a = x; return u.b; }

// deterministic block(256) reductions
DEV float breduce_sum(float v, float* sred, int tid) {
#pragma unroll
  for (int o = 32; o > 0; o >>= 1) v += __shfl_xor(v, o);
  if ((tid & 63) == 0) sred[tid >> 6] = v;
  __syncthreads();
  v = (sred[0] + sred[1]) + (sred[2] + sred[3]);
  __syncthreads();
  return v;
}

// ---------------------------------------------------------------------------
// bias-MLP weights (bp_w1 4096 float4 | bp_w2 1024 float4) -> bf16, 1 dispatch
__global__ __launch_bounds__(256) void cast_bias_kernel(
    const float* __restrict__ w1f, const float* __restrict__ w2f,
    unsigned short* __restrict__ d1, unsigned short* __restrict__ d2) {
  const int i = blockIdx.x * 256 + threadIdx.x;  // < 5120
  const float* s;
  unsigned short* d;
  int j;
  if (i < 4096) { s = w1f; d = d1; j = i; }
  else { s = w2f; d = d2; j = i - 4096; }
  const float4 v = ((const float4*)s)[j];
  u16x4 o = {f2bf(v.x), f2bf(v.y), f2bf(v.z), f2bf(v.w)};
  ((u16x4*)d)[j] = o;
}

// per-layer weights -> rotating arena (qkv | wo | w1 | w2), 32B read/16B write
__global__ __launch_bounds__(256) void castlayer_kernel(
    const float* __restrict__ wqkv, const float* __restrict__ wo,
    const float* __restrict__ w1, const float* __restrict__ w2,
    unsigned short* __restrict__ arena) {
  const unsigned i = blockIdx.x * 256 + threadIdx.x;  // u16x8 unit
  const float* s; unsigned j;
  if (i < 221184u) { s = wqkv; j = i; }
  else if (i < 294912u) { s = wo; j = i - 221184u; }
  else if (i < 589824u) { s = w1; j = i - 294912u; }
  else { s = w2; j = i - 589824u; }
  const float4 a = ((const float4*)s)[2u * j];
  const float4 b = ((const float4*)s)[2u * j + 1u];
  u16x8 o = {f2bf(a.x), f2bf(a.y), f2bf(a.z), f2bf(a.w),
             f2bf(b.x), f2bf(b.y), f2bf(b.z), f2bf(b.w)};
  ((u16x8*)arena)[i] = o;
}

// head weights (nq,nk,nv,en_w1) -> headsb; 294912 u16x8 units, grid 1152
__global__ __launch_bounds__(256) void castheads_kernel(
    const float* __restrict__ a, const float* __restrict__ b,
    const float* __restrict__ c, const float* __restrict__ d,
    unsigned short* __restrict__ arena) {
  const unsigned i = blockIdx.x * 256 + threadIdx.x;
  const unsigned r = i / 73728u;
  const unsigned j = i - r * 73728u;
  const float* s = (r == 0) ? a : (r == 1) ? b : (r == 2) ? c : d;
  const float4 a0 = ((const float4*)s)[2u * j];
  const float4 a1 = ((const float4*)s)[2u * j + 1u];
  u16x8 o = {f2bf(a0.x), f2bf(a0.y), f2bf(a0.z), f2bf(a0.w),
             f2bf(a1.x), f2bf(a1.y), f2bf(a1.z), f2bf(a1.w)};
  ((u16x8*)arena)[i] = o;
}

// ---------------------------------------------------------------------------
// Kernel 1: per-(b,i) edge precompute (f32)
__global__ __launch_bounds__(256) void edge_pre_kernel(
    const int* __restrict__ atoms, const float* __restrict__ pos,
    const float* __restrict__ gbf_mul, const float* __restrict__ gbf_bias,
    const float* __restrict__ gbf_means, const float* __restrict__ gbf_stds,
    float* __restrict__ deltaw, float* __restrict__ xvalw, float* __restrict__ nsumw)
{
  const int tid = threadIdx.x;
  const int bi = blockIdx.x;
  const int b = bi >> 8;
  __shared__ float spos[3];
  __shared__ float sxv[256];
  __shared__ int   spad[256];
  __shared__ float red[256];
  if (tid < 3) spos[tid] = pos[(size_t)bi * 3 + tid];
  __syncthreads();
  {
    const int j = tid;
    const float px = pos[(size_t)(b * N_ + j) * 3 + 0];
    const float py = pos[(size_t)(b * N_ + j) * 3 + 1];
    const float pz = pos[(size_t)(b * N_ + j) * 3 + 2];
    const float dx = px - spos[0], dy = py - spos[1], dz = pz - spos[2];
    const float sq = dx * dx + dy * dy + dz * dz;
    const float dist = sqrtf(fmaxf(sq, 1e-24f));
    const float inv = 1.f / (dist + 1e-5f);
    const size_t e = (size_t)bi * N_ + j;
    deltaw[e * 3 + 0] = dx * inv;
    deltaw[e * 3 + 1] = dy * inv;
    deltaw[e * 3 + 2] = dz * inv;
    const int et = atoms[bi] * 64 + atoms[b * N_ + j];
    const float xv = gbf_mul[et] * dist + gbf_bias[et];
    xvalw[e] = xv;
    sxv[j] = xv;
    spad[j] = (atoms[b * N_ + j] == 0);
  }
  __syncthreads();
  const int k = tid & 127;
  const float mean = gbf_means[k];
  const float st = fabsf(gbf_stds[k]) + 1e-5f;
  const float istd = 1.f / st;
  const float coef = 0.39894228040143268f * istd;
  float acc = 0.f;
  const int jbase = tid >> 7;
  for (int t = 0; t < 128; ++t) {
    const int j = jbase + (t << 1);
    if (!spad[j]) {
      const float z = (sxv[j] - mean) * istd;
      acc += __expf(-0.5f * z * z) * coef;
    }
  }
  red[tid] = acc;
  __syncthreads();
  if (tid < 128) nsumw[(size_t)bi * K_ + tid] = red[tid] + red[tid + 128];
}

// ---------------------------------------------------------------------------
// Kernel 2 (MFMA, register datapath): bias MLP per 64-edge tile.
__global__ __launch_bounds__(256) void bias_mfma_kernel(
    const float* __restrict__ xvalw, const int* __restrict__ atoms,
    const float* __restrict__ gbf_means, const float* __restrict__ gbf_stds,
    const unsigned short* __restrict__ w1b, const float* __restrict__ b1,
    const unsigned short* __restrict__ w2b, const float* __restrict__ b2,
    unsigned short* __restrict__ biasb)
{
  __shared__ __align__(16) unsigned short sw1[128 * 128];  // 32 KB, swizzled
  __shared__ __align__(16) unsigned short sw2[32 * 128];   // 8 KB, swizzled
  __shared__ float smean[128], sistd[128], scoef[128], sb1[128], sb2[32];
  const int tid = threadIdx.x;
  const int l = tid & 63;
  const int w = tid >> 6;
  const size_t e0 = (size_t)blockIdx.x * 64;
  const int bB = (int)(e0 >> 16);
  const int iI = (int)((e0 >> 8) & 255);
  const int j0 = (int)(e0 & 255);
  const int lr = l & 15;
  const int lg = l >> 4;

  {
    const int rin = l >> 4;
    const int slot = l & 15;
#pragma unroll
    for (int q = 0; q < 8; ++q) {
      const int rbase = w * 32 + q * 4;
      const int row = rbase + rin;
      const int gs = slot ^ (row & 15);
      gload_lds16(w1b + row * 128 + gs * 8, &sw1[rbase * 128]);
    }
#pragma unroll
    for (int q = 0; q < 2; ++q) {
      const int rbase = w * 8 + q * 4;
      const int row = rbase + rin;
      const int gs = slot ^ (row & 15);
      gload_lds16(w2b + row * 128 + gs * 8, &sw2[rbase * 128]);
    }
  }
  if (tid < 128) {
    const float st = fabsf(gbf_stds[tid]) + 1e-5f;
    const float is = 1.f / st;
    smean[tid] = gbf_means[tid];
    sistd[tid] = is;
    scoef[tid] = 0.39894228040143268f * is;
    sb1[tid] = b1[tid];
  } else if (tid < 160) {
    sb2[tid - 128] = b2[tid - 128];
  }
  const int el = w * 16 + lr;
  const float xv = xvalw[e0 + el];
  const bool padq = (atoms[bB * N_ + j0 + el] == 0);
  __syncthreads();

  bf16x8 bG[4];
#pragma unroll
  for (int ks = 0; ks < 4; ++ks) {
    u16x8 t;
#pragma unroll
    for (int j = 0; j < 8; ++j) {
      const int k = ks * 32 + lg * 8 + j;
      const float z = (xv - smean[k]) * sistd[k];
      t[j] = f2bf(__expf(-0.5f * z * z) * scoef[k]);
    }
    union { u16x8 a; bf16x8 b; } u; u.a = t;
    bG[ks] = u.b;
  }

  f32x4 accM[8];
#pragma unroll
  for (int f = 0; f < 8; ++f) accM[f] = (f32x4)0.f;
#pragma unroll
  for (int ks = 0; ks < 4; ++ks) {
#pragma unroll
    for (int f = 0; f < 8; ++f) {
      const int row = f * 16 + lr;
      const int sl = (ks * 4 + lg) ^ (row & 15);
      const bf16x8 aW = *(const bf16x8*)&sw1[row * 128 + (sl << 3)];
      accM[f] = MFMA16(aW, bG[ks], accM[f]);
    }
  }

  unsigned pm[8][2];
#pragma unroll
  for (int f = 0; f < 8; ++f) {
    float g[4];
#pragma unroll
    for (int r = 0; r < 4; ++r)
      g[r] = gelu_f(accM[f][r] + sb1[f * 16 + lg * 4 + r]);
    pm[f][0] = packbf(g[0], g[1]);
    pm[f][1] = packbf(g[2], g[3]);
  }

  f32x4 accH[2];
  accH[0] = (f32x4)0.f; accH[1] = (f32x4)0.f;
#pragma unroll
  for (int ks = 0; ks < 4; ++ks) {
    const int s0 = ((((lg << 1)) & 3) << 4) + lr;
    const int s1 = ((((lg << 1) + 1) & 3) << 4) + lr;
    const int sel = lg >> 1;
    const unsigned a0 = __shfl(pm[2 * ks][0], s0), b0 = __shfl(pm[2 * ks + 1][0], s0);
    const unsigned a1 = __shfl(pm[2 * ks][1], s0), b1v = __shfl(pm[2 * ks + 1][1], s0);
    const unsigned a2 = __shfl(pm[2 * ks][0], s1), b2v = __shfl(pm[2 * ks + 1][0], s1);
    const unsigned a3 = __shfl(pm[2 * ks][1], s1), b3v = __shfl(pm[2 * ks + 1][1], s1);
    u32x4 bw;
    bw.x = sel ? b0 : a0;
    bw.y = sel ? b1v : a1;
    bw.z = sel ? b2v : a2;
    bw.w = sel ? b3v : a3;
    const bf16x8 bMid = u4_to_bf8(bw);
#pragma unroll
    for (int hf = 0; hf < 2; ++hf) {
      const int row = hf * 16 + lr;
      const int sl = (ks * 4 + lg) ^ (row & 15);
      const bf16x8 aW2 = *(const bf16x8*)&sw2[row * 128 + (sl << 3)];
      accH[hf] = MFMA16(aW2, bMid, accH[hf]);
    }
  }

  const size_t obase = (((size_t)bB * H_) * N_ + iI) * N_ + j0 + el;
#pragma unroll
  for (int hf = 0; hf < 2; ++hf) {
#pragma unroll
    for (int r = 0; r < 4; ++r) {
      const int h = hf * 16 + lg * 4 + r;
      const unsigned short v = padq ? (unsigned short)0xFF80
                                    : f2bf(accH[hf][r] + sb2[h]);
      biasb[obase + (size_t)h * N_ * N_] = v;
    }
  }
}

// ---------------------------------------------------------------------------
// Kernel 3: node init
__global__ __launch_bounds__(256) void node_init_kernel(
    const int* __restrict__ atoms, const int* __restrict__ tags,
    const float* __restrict__ atom_emb, const float* __restrict__ tag_emb,
    const float* __restrict__ nsumw, const float* __restrict__ ep_w,
    const float* __restrict__ ep_b, float* __restrict__ hbuf)
{
  const int bi = blockIdx.x;
  const int tid = threadIdx.x;
  __shared__ float ns[K_];
  if (tid < K_) ns[tid] = nsumw[(size_t)bi * K_ + tid];
  __syncthreads();
  const int at = atoms[bi], tg = tags[bi];
  for (int d = tid; d < D_; d += 256) {
    float acc = tag_emb[tg * D_ + d] + atom_emb[at * D_ + d] + ep_b[d];
    const float* w = ep_w + (size_t)d * K_;
#pragma unroll 8
    for (int kk = 0; kk < K_; ++kk) acc = fmaf(ns[kk], w[kk], acc);
    hbuf[(size_t)bi * D_ + d] = acc;
  }
}

// ---------------------------------------------------------------------------
// LayerNorm -> bf16 out (used once, before layer 0)
__global__ __launch_bounds__(256) void ln_kernel(
    const float* __restrict__ x, const float* __restrict__ gg,
    const float* __restrict__ bb, unsigned short* __restrict__ y)
{
  const int bi = blockIdx.x;
  const int tid = threadIdx.x;
  __shared__ float sred[4];
  const float* row = x + (size_t)bi * D_;
  const float v0 = row[tid], v1 = row[tid + 256], v2 = row[tid + 512];
  float s = breduce_sum(v0 + v1 + v2, sred, tid);
  const float mean = s * (1.f / 768.f);
  const float d0 = v0 - mean, d1 = v1 - mean, d2 = v2 - mean;
  float q = breduce_sum(d0 * d0 + d1 * d1 + d2 * d2, sred, tid);
  const float inv = rsqrtf(q * (1.f / 768.f) + 1e-5f);
  unsigned short* out = y + (size_t)bi * D_;
  out[tid]       = f2bf(d0 * inv * gg[tid]       + bb[tid]);
  out[tid + 256] = f2bf(d1 * inv * gg[tid + 256] + bb[tid + 256]);
  out[tid + 512] = f2bf(d2 * inv * gg[tid + 512] + bb[tid + 512]);
}

// ---------------------------------------------------------------------------
// Split-K reduce + residual + bias + LayerNorm -> bf16 y (and updated hbuf).
template <int S>
__global__ __launch_bounds__(256) void reduce_ln_kernel(
    const float* __restrict__ P, const float* __restrict__ bias,
    float* __restrict__ hbuf, const float* __restrict__ gg,
    const float* __restrict__ bb, unsigned short* __restrict__ y)
{
  const int row = blockIdx.x;
  const int tid = threadIdx.x;
  __shared__ float sred[4];
  float h[3];
#pragma unroll
  for (int t = 0; t < 3; ++t) {
    const int c = tid + (t << 8);
    float s = bias[c];
#pragma unroll
    for (int z = 0; z < S; ++z)
      s += P[((size_t)z * (B_ * N_) + row) * 768 + c];
    const float hv = hbuf[(size_t)row * 768 + c] + s;
    hbuf[(size_t)row * 768 + c] = hv;
    h[t] = hv;
  }
  float sm = breduce_sum(h[0] + h[1] + h[2], sred, tid);
  const float mean = sm * (1.f / 768.f);
  const float d0 = h[0] - mean, d1 = h[1] - mean, d2 = h[2] - mean;
  float q = breduce_sum(d0 * d0 + d1 * d1 + d2 * d2, sred, tid);
  const float inv = rsqrtf(q * (1.f / 768.f) + 1e-5f);
  unsigned short* out = y + (size_t)row * 768;
  out[tid]       = f2bf(d0 * inv * gg[tid]       + bb[tid]);
  out[tid + 256] = f2bf(d1 * inv * gg[tid + 256] + bb[tid + 256]);
  out[tid + 512] = f2bf(d2 * inv * gg[tid + 512] + bb[tid + 512]);
}

// ---------------------------------------------------------------------------
// MFMA GEMM: A bf16 [M,lda], W bf16 [N,ldw], 64x64 tile, BK=64, 4 waves,
// double-buffered global_load_lds (pre-swizzled source), drain-barrier loop.
// K-loop uses 32x32x16 MFMA: wave (wm,wn) owns quadrant, 4 MFMA32/K-step.
// C/D layout: col=lane&31, row=(reg&3)+8*(reg>>2)+4*(lane>>5).
// EPI: 0 bias; 1 gelu(bias+); 3 segment-bias (768-chunks, gelu on seg 3);
//      4 split-K raw partial (blockIdx.z selects K-slice, C offset z*M*N).
template <int EPI, int OB>
__global__ __launch_bounds__(256) void gemm_mfma(
    const unsigned short* __restrict__ A, const unsigned short* __restrict__ W,
    const float* __restrict__ bias, const float* __restrict__ bias2,
    const float* __restrict__ bias3, const float* __restrict__ bias4,
    float* __restrict__ C, unsigned short* __restrict__ Cb,
    int M, int N, int K, int lda, int ldw)
{
  if (EPI == 4) {
    const int z = blockIdx.z;
    A += (size_t)z * K;
    W += (size_t)z * K;
    C += (size_t)z * M * N;
  }
  __shared__ __align__(16) unsigned short sA[2][64 * 64];
  __shared__ __align__(16) unsigned short sB[2][64 * 64];
  const int tid = threadIdx.x;
  const int l = tid & 63;
  const int w = tid >> 6;
  const int m0 = blockIdx.y * 64;
  const int n0 = blockIdx.x * 64;
  const int wm = w >> 1, wn = w & 1;
  const int l31 = l & 31;
  const int kg = l >> 5;               // k-group 0/1 within 16-k slice
  const int r0 = (w << 4) + (l >> 3);  // staging row
  const int s0 = (l & 7) ^ (r0 & 7);   // pre-swizzled k-slot

  const int arow = (wm << 5) + l31;    // A fragment row within 64-tile
  const int brow = (wn << 5) + l31;    // B (W) fragment row within 64-tile

  f32x16 acc = (f32x16)0.f;

  auto stage = [&](int buf, int t) {
    const size_t kb = (size_t)t << 6;
    unsigned short* lA = &sA[buf][(w << 4) << 6];
    unsigned short* lB = &sB[buf][(w << 4) << 6];
    gload_lds16(A + (size_t)(m0 + r0) * lda + kb + (s0 << 3), lA);
    gload_lds16(A + (size_t)(m0 + r0 + 8) * lda + kb + (s0 << 3), lA + 8 * 64);
    gload_lds16(W + (size_t)(n0 + r0) * ldw + kb + (s0 << 3), lB);
    gload_lds16(W + (size_t)(n0 + r0 + 8) * ldw + kb + (s0 << 3), lB + 8 * 64);
  };

  stage(0, 0);
  const int nt = K >> 6;
  for (int t = 0; t < nt; ++t) {
    __syncthreads();   // drains vmcnt: buf[t&1] staged; prev reads done
    if (t + 1 < nt) stage((t + 1) & 1, t + 1);
    const unsigned short* bA = sA[t & 1];
    const unsigned short* bBs = sB[t & 1];
    bf16x8 af[4], bfr[4];
#pragma unroll
    for (int s4 = 0; s4 < 4; ++s4) {
      const int slot = (s4 << 1) + kg;
      af[s4] = *(const bf16x8*)&bA[(arow << 6) + ((slot ^ (arow & 7)) << 3)];
      bfr[s4] = *(const bf16x8*)&bBs[(brow << 6) + ((slot ^ (brow & 7)) << 3)];
    }
#pragma unroll
    for (int s4 = 0; s4 < 4; ++s4) acc = MFMA32(af[s4], bfr[s4], acc);
  }

  const int n = n0 + (wn << 5) + l31;
  float bv = 0.f;
  int seg = 0;
  if (EPI == 3) {
    seg = n / 768;
    const float* bp = (seg == 0) ? bias : (seg == 1) ? bias2
                     : (seg == 2) ? bias3 : bias4;
    bv = bp[n - seg * 768];
  } else if (EPI != 4) {
    bv = bias[n];
  }
#pragma unroll
  for (int r = 0; r < 16; ++r) {
    const int m = m0 + (wm << 5) + (r & 3) + ((r >> 2) << 3) + (kg << 2);
    float v = acc[r] + bv;
    if (EPI == 1) v = gelu_f(v);
    if (EPI == 3 && seg == 3) v = gelu_f(v);
    if (OB) Cb[(size_t)m * N + n] = f2bf(v);
    else C[(size_t)m * N + n] = v;
  }
}

// ---------------------------------------------------------------------------
// MFMA attention, bf16 Q/K/V inputs. grid = (B*H, 4), block = 256 (4 waves).
// PV path: unnormalized P in sP, per-lane invr[] applied to O (defer-norm).
template <bool PROBS>
__global__ __launch_bounds__(256) void attn_mfma_kernel(
    const unsigned short* __restrict__ Q, const unsigned short* __restrict__ Kp,
    const unsigned short* __restrict__ Vp, const int stride,
    const unsigned short* __restrict__ biasb, unsigned short* __restrict__ obuf,
    unsigned short* __restrict__ aprob)
{
  __shared__ __align__(16) unsigned short sK[256 * 40];   // [j][d pad40]
  __shared__ __align__(16) unsigned short sVt[32 * 264];  // [d][j pad264]
  __shared__ __align__(16) unsigned short sP[64 * 264];   // [i_loc][j pad264]
  const int tid = threadIdx.x;
  const int l = tid & 63, w = tid >> 6;
  const int bh = blockIdx.x, b = bh >> 5, hh = bh & 31;
  const int i0 = blockIdx.y * 64;
  const int lr = l & 15, lg = l >> 4;

#pragma unroll
  for (int it = 0; it < 3; ++it) {
    const int c = tid + (it << 8);        // < 768
    const int row = c / 3, part = c - row * 3;
    *(u16x8*)&sK[row * 40 + part * 8] =
        *(const u16x8*)&Kp[(size_t)(b * N_ + row) * stride + hh * HD_ + part * 8];
  }
  {
    u16x8 z = {0, 0, 0, 0, 0, 0, 0, 0};
    *(u16x8*)&sK[tid * 40 + 24] = z;
  }
  if (!PROBS) {
    const int j = tid;
    const unsigned short* vr = &Vp[(size_t)(b * N_ + j) * stride + hh * HD_];
    const u16x8 v0 = *(const u16x8*)vr;
    const u16x8 v1 = *(const u16x8*)(vr + 8);
    const u16x8 v2 = *(const u16x8*)(vr + 16);
#pragma unroll
    for (int d = 0; d < 8; ++d) {
      sVt[d * 264 + j] = v0[d];
      sVt[(8 + d) * 264 + j] = v1[d];
      sVt[(16 + d) * 264 + j] = v2[d];
    }
  }
  bf16x8 aQ;
  if (lg < 3) {
    const u16x8 q = *(const u16x8*)&Q[(size_t)(b * N_ + i0 + (w << 4) + lr) * stride + hh * HD_ + lg * 8];
    union { u16x8 a; bf16x8 b; } u; u.a = q;
    aQ = u.b;
  } else {
    bf16x8 t = {0, 0, 0, 0, 0, 0, 0, 0};
    aQ = t;
  }
  __syncthreads();

  f32x4 acc[16];
#pragma unroll
  for (int ni = 0; ni < 16; ++ni) {
    const bf16x8 bK = *(const bf16x8*)&sK[(ni * 16 + lr) * 40 + lg * 8];
    acc[ni] = MFMA16(aQ, bK, (f32x4)0.f);
  }

  float invr[4];
#pragma unroll
  for (int r = 0; r < 4; ++r) {
    const int iloc = (w << 4) + lg * 4 + r;
    const unsigned short* bp =
        &biasb[(((size_t)(b * H_ + hh)) * N_ + i0 + iloc) * N_ + lr];
    float mx = -INFINITY;
#pragma unroll
    for (int ni = 0; ni < 16; ++ni) {
      const float s = acc[ni][r] * SCALE_ + bf2f(bp[ni * 16]);
      acc[ni][r] = s;
      mx = fmaxf(mx, s);
    }
    mx = fmaxf(mx, __shfl_xor(mx, 1));
    mx = fmaxf(mx, __shfl_xor(mx, 2));
    mx = fmaxf(mx, __shfl_xor(mx, 4));
    mx = fmaxf(mx, __shfl_xor(mx, 8));
    float sum = 0.f;
#pragma unroll
    for (int ni = 0; ni < 16; ++ni) {
      const float e = __expf(acc[ni][r] - mx);
      acc[ni][r] = e;
      sum += e;
    }
    sum += __shfl_xor(sum, 1);
    sum += __shfl_xor(sum, 2);
    sum += __shfl_xor(sum, 4);
    sum += __shfl_xor(sum, 8);
    const float inv = 1.f / sum;
    invr[r] = inv;
#pragma unroll
    for (int ni = 0; ni < 16; ++ni)
      sP[iloc * 264 + ni * 16 + lr] = f2bf(PROBS ? acc[ni][r] * inv
                                                 : acc[ni][r]);
  }
  __syncthreads();

  if (PROBS) {
#pragma unroll
    for (int it = 0; it < 8; ++it) {
      const int idx = tid + it * 256;     // < 2048
      const int row = idx >> 5, c = idx & 31;
      *(u16x8*)&aprob[(((size_t)(b * H_ + hh)) * N_ + i0 + row) * N_ + c * 8] =
          *(const u16x8*)&sP[row * 264 + c * 8];
    }
  } else {
    f32x4 accO[2];
    accO[0] = (f32x4)0.f; accO[1] = (f32x4)0.f;
#pragma unroll
    for (int ks = 0; ks < 8; ++ks) {
      const bf16x8 aP = *(const bf16x8*)&sP[((w << 4) + lr) * 264 + ks * 32 + lg * 8];
      const bf16x8 bV0 = *(const bf16x8*)&sVt[lr * 264 + ks * 32 + lg * 8];
      const bf16x8 bV1 = *(const bf16x8*)&sVt[(16 + lr) * 264 + ks * 32 + lg * 8];
      accO[0] = MFMA16(aP, bV0, accO[0]);
      accO[1] = MFMA16(aP, bV1, accO[1]);
    }
#pragma unroll
    for (int ni = 0; ni < 2; ++ni) {
      const int n = ni * 16 + lr;
      if (n < HD_) {
#pragma unroll
        for (int r = 0; r < 4; ++r) {
          const int i = i0 + (w << 4) + lg * 4 + r;
          obuf[(size_t)(b * N_ + i) * D_ + hh * HD_ + n] = f2bf(accO[ni][r] * invr[r]);
        }
      }
    }
  }
}

// ---------------------------------------------------------------------------
// Energy head (t1 bf16, rows strided)
__global__ __launch_bounds__(256) void engnode_kernel(
    const unsigned short* __restrict__ t1, const int stride,
    const float* __restrict__ en_w2, const float* __restrict__ en_b2,
    const float* __restrict__ eagg, const int* __restrict__ tags,
    float* __restrict__ engpn)
{
  const int bi = blockIdx.x;
  const int tid = threadIdx.x;
  __shared__ float sred[4];
  const unsigned short* row = t1 + (size_t)bi * stride;
  float acc = bf2f(row[tid]) * en_w2[tid] + bf2f(row[tid + 256]) * en_w2[tid + 256] +
              bf2f(row[tid + 512]) * en_w2[tid + 512];
  acc = breduce_sum(acc, sred, tid);
  if (tid == 0) {
    const int tg = tags[bi];
    engpn[bi] = (tg > 0) ? (acc + en_b2[0]) * eagg[tg] : 0.f;
  }
}

// engsum (blocks 0..3) + omask (blocks 4..7) merged
__global__ __launch_bounds__(256) void engsum_omask_kernel(
    const float* __restrict__ engpn, const int* __restrict__ tags,
    float* __restrict__ out)
{
  const int bid = blockIdx.x;
  const int tid = threadIdx.x;
  if (bid < 4) {
    __shared__ float sred[4];
    float v = breduce_sum(engpn[bid * N_ + tid], sred, tid);
    if (tid == 0) out[bid] = v;
  } else {
    const int idx = (bid - 4) * 256 + tid;
    out[4 + B_ * N_ * 3 + idx] = (tags[idx] > 0) ? 1.f : 0.f;
  }
}

// ---------------------------------------------------------------------------
// wv[c][b,h,j] = sum_d v[b,j,h*HD+d] * fc_w[h*HD+d]   (v bf16)
__global__ __launch_bounds__(256) void wv_kernel(
    const unsigned short* __restrict__ vn, const int stride,
    const float* __restrict__ f1w, const float* __restrict__ f2w,
    const float* __restrict__ f3w, float* __restrict__ wv)
{
  const int idx = blockIdx.x * 256 + threadIdx.x;
  const int j = idx & 255;
  const int hh = (idx >> 8) & 31;
  const int b = (idx >> 13) & 3;
  const int c = idx >> 15;
  const float* fw = (c == 0) ? f1w : ((c == 1) ? f2w : f3w);
  const unsigned short* vrow = vn + (size_t)(b * N_ + j) * stride + hh * HD_;
  const u16x8 v0 = *(const u16x8*)vrow;
  const u16x8 v1 = *(const u16x8*)(vrow + 8);
  const u16x8 v2 = *(const u16x8*)(vrow + 16);
  float acc = 0.f;
#pragma unroll
  for (int d = 0; d < 8; ++d) {
    acc = fmaf(bf2f(v0[d]), fw[hh * HD_ + d], acc);
    acc = fmaf(bf2f(v1[d]), fw[hh * HD_ + 8 + d], acc);
    acc = fmaf(bf2f(v2[d]), fw[hh * HD_ + 16 + d], acc);
  }
  wv[idx] = acc;
}

// merged-c nodeout: grid = BN
__global__ __launch_bounds__(256) void nodeout_kernel(
    const unsigned short* __restrict__ aprob, const float* __restrict__ wv,
    const float* __restrict__ deltaw, const float* __restrict__ f1b,
    const float* __restrict__ f2b, const float* __restrict__ f3b,
    float* __restrict__ out)
{
  const int bi = blockIdx.x;
  const int tid = threadIdx.x;
  const int b = bi >> 8;
  const int i = bi & 255;
  __shared__ float sred[4];
  const unsigned short* ap = aprob + (((size_t)b * H_) * N_ + i) * N_ + tid;
  const float* wv0 = wv + ((size_t)(0 * B_ + b) * H_) * N_ + tid;
  const float* wv1 = wv + ((size_t)(1 * B_ + b) * H_) * N_ + tid;
  const float* wv2 = wv + ((size_t)(2 * B_ + b) * H_) * N_ + tid;
  float s0 = 0.f, s1 = 0.f, s2 = 0.f;
  for (int hh = 0; hh < H_; ++hh) {
    const float p = bf2f(ap[(size_t)hh * N_ * N_]);
    s0 = fmaf(p, wv0[(size_t)hh * N_], s0);
    s1 = fmaf(p, wv1[(size_t)hh * N_], s1);
    s2 = fmaf(p, wv2[(size_t)hh * N_], s2);
  }
  const float* dl = &deltaw[((size_t)bi * N_ + tid) * 3];
  s0 *= dl[0];
  s1 *= dl[1];
  s2 *= dl[2];
  s0 = breduce_sum(s0, sred, tid);
  s1 = breduce_sum(s1, sred, tid);
  s2 = breduce_sum(s2, sred, tid);
  if (tid == 0) {
    out[4 + bi * 3 + 0] = s0 + f1b[0];
    out[4 + bi * 3 + 1] = s1 + f2b[0];
    out[4 + bi * 3 + 2] = s2 + f3b[0];
  }
}

// ---------------------------------------------------------------------------
extern "C" void kernel_launch(void* const* d_in, const int* in_sizes, int n_in,
                              void* d_out, int out_size, void* d_ws, size_t ws_size,
                              hipStream_t stream) {
  (void)in_sizes; (void)n_in; (void)out_size; (void)ws_size;
  const int*   atoms     = (const int*)  d_in[0];
  const int*   tags      = (const int*)  d_in[1];
  const float* pos       = (const float*)d_in[2];
  const float* atom_emb  = (const float*)d_in[4];
  const float* tag_emb   = (const float*)d_in[5];
  const float* gbf_means = (const float*)d_in[6];
  const float* gbf_stds  = (const float*)d_in[7];
  const float* gbf_mul   = (const float*)d_in[8];
  const float* gbf_bias  = (const float*)d_in[9];
  const float* bp_w1     = (const float*)d_in[10];
  const float* bp_b1     = (const float*)d_in[11];
  const float* bp_w2     = (const float*)d_in[12];
  const float* bp_b2     = (const float*)d_in[13];
  const float* ep_w      = (const float*)d_in[14];
  const float* ep_b      = (const float*)d_in[15];
  const float* ln1_g     = (const float*)d_in[16];
  const float* ln1_b     = (const float*)d_in[17];
  const float* wqkv      = (const float*)d_in[18];
  const float* bqkv      = (const float*)d_in[19];
  const float* wo        = (const float*)d_in[20];
  const float* bo        = (const float*)d_in[21];
  const float* ln2_g     = (const float*)d_in[22];
  const float* ln2_b     = (const float*)d_in[23];
  const float* w1        = (const float*)d_in[24];
  const float* b1        = (const float*)d_in[25];
  const float* w2        = (const float*)d_in[26];
  const float* b2        = (const float*)d_in[27];
  const float* fln_g     = (const float*)d_in[28];
  const float* fln_b     = (const float*)d_in[29];
  const float* en_w1     = (const float*)d_in[30];
  const float* en_b1     = (const float*)d_in[31];
  const float* en_w2     = (const float*)d_in[32];
  const float* en_b2     = (const float*)d_in[33];
  const float* eagg      = (const float*)d_in[34];
  const float* nq_w      = (const float*)d_in[35];
  const float* nq_b      = (const float*)d_in[36];
  const float* nk_w      = (const float*)d_in[37];
  const float* nk_b      = (const float*)d_in[38];
  const float* nv_w      = (const float*)d_in[39];
  const float* nv_b      = (const float*)d_in[40];
  const float* f1_w      = (const float*)d_in[41];
  const float* f1_b      = (const float*)d_in[42];
  const float* f2_w      = (const float*)d_in[43];
  const float* f2_b      = (const float*)d_in[44];
  const float* f3_w      = (const float*)d_in[45];
  const float* f3_b      = (const float*)d_in[46];

  char* wsB = (char*)d_ws;
  size_t off = 0;
  auto alloc = [&](size_t bytes) {
    void* p = wsB + off;
    off = (off + bytes + 255) & ~(size_t)255;
    return p;
  };
  unsigned short* biasb   = (unsigned short*)alloc((size_t)B_ * H_ * N_ * N_ * 2);
  unsigned short* aprobb  = (unsigned short*)alloc((size_t)B_ * H_ * N_ * N_ * 2);
  float*          deltaw  = (float*)alloc((size_t)B_ * N_ * N_ * 3 * 4);
  float*          xvalw   = (float*)alloc((size_t)B_ * N_ * N_ * 4);
  float*          nsumw   = (float*)alloc((size_t)B_ * N_ * K_ * 4);
  float*          hbuf    = (float*)alloc((size_t)B_ * N_ * D_ * 4);
  unsigned short* qkvb    = (unsigned short*)alloc((size_t)B_ * N_ * 3 * D_ * 2);
  unsigned short* qn4b    = (unsigned short*)alloc((size_t)B_ * N_ * 3072 * 2);
  unsigned short* ybf     = (unsigned short*)alloc((size_t)B_ * N_ * D_ * 2);
  unsigned short* obf     = (unsigned short*)alloc((size_t)B_ * N_ * D_ * 2);
  unsigned short* midbf   = (unsigned short*)alloc((size_t)B_ * N_ * F_ * 2);
  unsigned short* outbf   = (unsigned short*)alloc((size_t)B_ * N_ * D_ * 2);
  unsigned short* arena   = (unsigned short*)alloc((size_t)7077888 * 2);
  unsigned short* headsb  = (unsigned short*)alloc((size_t)2359296 * 2);
  unsigned short* bw1b    = (unsigned short*)alloc((size_t)K_ * K_ * 2);
  unsigned short* bw2b    = (unsigned short*)alloc((size_t)H_ * K_ * 2);
  float*          wopart  = (float*)alloc((size_t)2 * B_ * N_ * D_ * 4);
  float*          ffpart  = (float*)alloc((size_t)4 * B_ * N_ * D_ * 4);
  float*          wvb     = (float*)alloc((size_t)3 * B_ * H_ * N_ * 4);
  float*          engpn   = (float*)alloc((size_t)B_ * N_ * 4);

  const int BN = B_ * N_;  // 1024
  float* outp = (float*)d_out;
  const size_t OQKV = 0, OWO = 1769472, OW1 = 2359296, OW2 = 4718592;

  edge_pre_kernel<<<BN, 256, 0, stream>>>(atoms, pos, gbf_mul, gbf_bias,
                                          gbf_means, gbf_stds, deltaw, xvalw, nsumw);
  cast_bias_kernel<<<20, 256, 0, stream>>>(bp_w1, bp_w2, bw1b, bw2b);
  bias_mfma_kernel<<<B_ * N_ * N_ / 64, 256, 0, stream>>>(
      xvalw, atoms, gbf_means, gbf_stds, bw1b, bp_b1, bw2b, bp_b2, biasb);
  node_init_kernel<<<BN, 256, 0, stream>>>(atoms, tags, atom_emb, tag_emb,
                                           nsumw, ep_w, ep_b, hbuf);
  ln_kernel<<<BN, 256, 0, stream>>>(hbuf, ln1_g, ln1_b, ybf);

  for (int l = 0; l < L_; ++l) {
    castlayer_kernel<<<3456, 256, 0, stream>>>(
        wqkv + (size_t)l * 3 * D_ * D_, wo + (size_t)l * D_ * D_,
        w1 + (size_t)l * F_ * D_, w2 + (size_t)l * D_ * F_, arena);
    // QKV: [1024,2304] bf16
    gemm_mfma<0, 1><<<dim3(36, 16), 256, 0, stream>>>(
        ybf, arena + OQKV, bqkv + (size_t)l * 3 * D_, nullptr, nullptr, nullptr,
        nullptr, qkvb, BN, 3 * D_, D_, D_, D_);
    attn_mfma_kernel<false><<<dim3(B_ * H_, 4), 256, 0, stream>>>(
        qkvb, qkvb + D_, qkvb + 2 * D_, 3 * D_, biasb, obf, nullptr);
    // wo: split-K=2 partials, then reduce + res + ln2 -> ybf
    gemm_mfma<4, 0><<<dim3(12, 16, 2), 256, 0, stream>>>(
        obf, arena + OWO, nullptr, nullptr, nullptr, nullptr,
        wopart, nullptr, BN, D_, 384, D_, D_);
    reduce_ln_kernel<2><<<BN, 256, 0, stream>>>(
        wopart, bo + (size_t)l * D_, hbuf, ln2_g + (size_t)l * D_,
        ln2_b + (size_t)l * D_, ybf);
    // FFN1: gelu -> midbf bf16
    gemm_mfma<1, 1><<<dim3(48, 16), 256, 0, stream>>>(
        ybf, arena + OW1, b1 + (size_t)l * F_, nullptr, nullptr, nullptr,
        nullptr, midbf, BN, F_, D_, D_, D_);
    // FFN2: split-K=4 partials, then reduce + res + ln1(l+1) (or fln) -> y
    gemm_mfma<4, 0><<<dim3(12, 16, 4), 256, 0, stream>>>(
        midbf, arena + OW2, nullptr, nullptr, nullptr, nullptr,
        ffpart, nullptr, BN, D_, 768, F_, F_);
    const bool last = (l == L_ - 1);
    reduce_ln_kernel<4><<<BN, 256, 0, stream>>>(
        ffpart, b2 + (size_t)l * D_, hbuf,
        last ? fln_g : ln1_g + (size_t)(l + 1) * D_,
        last ? fln_b : ln1_b + (size_t)(l + 1) * D_,
        last ? outbf : ybf);
  }

  // head weights -> headsb: [nq | nk | nv | en_w1], 3072 rows of K=768
  castheads_kernel<<<1152, 256, 0, stream>>>(nq_w, nk_w, nv_w, en_w1, headsb);

  // merged head GEMM: N = 3072 (q|k|v|t1), gelu on the en segment, bf16 out
  gemm_mfma<3, 1><<<dim3(48, 16), 256, 0, stream>>>(
      outbf, headsb, nq_b, nk_b, nv_b, en_b1,
      nullptr, qn4b, BN, 3072, D_, D_, D_);

  attn_mfma_kernel<true><<<dim3(B_ * H_, 4), 256, 0, stream>>>(
      qn4b, qn4b + 768, qn4b + 1536, 3072, biasb, nullptr, aprobb);
  wv_kernel<<<3 * B_ * H_ * N_ / 256, 256, 0, stream>>>(
      qn4b + 1536, 3072, f1_w, f2_w, f3_w, wvb);
  nodeout_kernel<<<BN, 256, 0, stream>>>(aprobb, wvb, deltaw,
                                         f1_b, f2_b, f3_b, outp);

  engnode_kernel<<<BN, 256, 0, stream>>>(qn4b + 2304, 3072, en_w2, en_b2,
                                         eagg, tags, engpn);
  engsum_omask_kernel<<<8, 256, 0, stream>>>(engpn, tags, outp);
}

// Round 11
// 1027.241 us; speedup vs baseline: 1.0132x; 1.0132x over previous
//
#include <hip/hip_runtime.h>
#include <math.h>

// Graphormer3D forward — round 10: R8 structure (best 1020us) with 16x16 GEMM
// restored + s_setprio on attn/bias MFMA clusters + node_init/LN fuse.
// B=4 N=256 D=768 H=32 HD=24 L=12 F=3072 K=128
constexpr int B_ = 4, N_ = 256, D_ = 768, H_ = 32, HD_ = 24, L_ = 12, F_ = 3072, K_ = 128;
constexpr float SCALE_ = 0.20412414523193150f;   // HD^-0.5
constexpr float ISQRT2_ = 0.70710678118654752f;

typedef short bf16x8 __attribute__((ext_vector_type(8)));
typedef float f32x4 __attribute__((ext_vector_type(4)));
typedef unsigned short u16x4 __attribute__((ext_vector_type(4)));
typedef unsigned short u16x8 __attribute__((ext_vector_type(8)));
typedef unsigned int u32x4 __attribute__((ext_vector_type(4)));

#define DEV __device__ __forceinline__
#define MFMA16(a, b, c) __builtin_amdgcn_mfma_f32_16x16x32_bf16(a, b, c, 0, 0, 0)

DEV void gload_lds16(const unsigned short* g, unsigned short* l) {
  __builtin_amdgcn_global_load_lds(
      (const __attribute__((address_space(1))) unsigned int*)(g),
      (__attribute__((address_space(3))) unsigned int*)(l), 16, 0, 0);
}

DEV float gelu_f(float x) { return 0.5f * x * (1.0f + erff(x * ISQRT2_)); }

DEV unsigned short f2bf(float f) {  // RNE f32 -> bf16
  unsigned u = __float_as_uint(f);
  return (unsigned short)((u + 0x7FFFu + ((u >> 16) & 1u)) >> 16);
}
DEV float bf2f(unsigned short u) { return __uint_as_float(((unsigned)u) << 16); }
DEV unsigned packbf(float a, float b) {
  return (unsigned)f2bf(a) | ((unsigned)f2bf(b) << 16);
}
DEV bf16x8 u4_to_bf8(u32x4 x) { union { u32x4 a; bf16x8 b; } u; u.a = x; return u.b; }

// deterministic block(256) reductions
DEV float breduce_sum(float v, float* sred, int tid) {
#pragma unroll
  for (int o = 32; o > 0; o >>= 1) v += __shfl_xor(v, o);
  if ((tid & 63) == 0) sred[tid >> 6] = v;
  __syncthreads();
  v = (sred[0] + sred[1]) + (sred[2] + sred[3]);
  __syncthreads();
  return v;
}

// ---------------------------------------------------------------------------
// bias-MLP weights (bp_w1 4096 float4 | bp_w2 1024 float4) -> bf16, 1 dispatch
__global__ __launch_bounds__(256) void cast_bias_kernel(
    const float* __restrict__ w1f, const float* __restrict__ w2f,
    unsigned short* __restrict__ d1, unsigned short* __restrict__ d2) {
  const int i = blockIdx.x * 256 + threadIdx.x;  // < 5120
  const float* s;
  unsigned short* d;
  int j;
  if (i < 4096) { s = w1f; d = d1; j = i; }
  else { s = w2f; d = d2; j = i - 4096; }
  const float4 v = ((const float4*)s)[j];
  u16x4 o = {f2bf(v.x), f2bf(v.y), f2bf(v.z), f2bf(v.w)};
  ((u16x4*)d)[j] = o;
}

// per-layer weights -> rotating arena (qkv | wo | w1 | w2), 32B read/16B write
__global__ __launch_bounds__(256) void castlayer_kernel(
    const float* __restrict__ wqkv, const float* __restrict__ wo,
    const float* __restrict__ w1, const float* __restrict__ w2,
    unsigned short* __restrict__ arena) {
  const unsigned i = blockIdx.x * 256 + threadIdx.x;  // u16x8 unit
  const float* s; unsigned j;
  if (i < 221184u) { s = wqkv; j = i; }
  else if (i < 294912u) { s = wo; j = i - 221184u; }
  else if (i < 589824u) { s = w1; j = i - 294912u; }
  else { s = w2; j = i - 589824u; }
  const float4 a = ((const float4*)s)[2u * j];
  const float4 b = ((const float4*)s)[2u * j + 1u];
  u16x8 o = {f2bf(a.x), f2bf(a.y), f2bf(a.z), f2bf(a.w),
             f2bf(b.x), f2bf(b.y), f2bf(b.z), f2bf(b.w)};
  ((u16x8*)arena)[i] = o;
}

// head weights (nq,nk,nv,en_w1) -> headsb; 294912 u16x8 units, grid 1152
__global__ __launch_bounds__(256) void castheads_kernel(
    const float* __restrict__ a, const float* __restrict__ b,
    const float* __restrict__ c, const float* __restrict__ d,
    unsigned short* __restrict__ arena) {
  const unsigned i = blockIdx.x * 256 + threadIdx.x;
  const unsigned r = i / 73728u;
  const unsigned j = i - r * 73728u;
  const float* s = (r == 0) ? a : (r == 1) ? b : (r == 2) ? c : d;
  const float4 a0 = ((const float4*)s)[2u * j];
  const float4 a1 = ((const float4*)s)[2u * j + 1u];
  u16x8 o = {f2bf(a0.x), f2bf(a0.y), f2bf(a0.z), f2bf(a0.w),
             f2bf(a1.x), f2bf(a1.y), f2bf(a1.z), f2bf(a1.w)};
  ((u16x8*)arena)[i] = o;
}

// ---------------------------------------------------------------------------
// Kernel 1: per-(b,i) edge precompute (f32)
__global__ __launch_bounds__(256) void edge_pre_kernel(
    const int* __restrict__ atoms, const float* __restrict__ pos,
    const float* __restrict__ gbf_mul, const float* __restrict__ gbf_bias,
    const float* __restrict__ gbf_means, const float* __restrict__ gbf_stds,
    float* __restrict__ deltaw, float* __restrict__ xvalw, float* __restrict__ nsumw)
{
  const int tid = threadIdx.x;
  const int bi = blockIdx.x;
  const int b = bi >> 8;
  __shared__ float spos[3];
  __shared__ float sxv[256];
  __shared__ int   spad[256];
  __shared__ float red[256];
  if (tid < 3) spos[tid] = pos[(size_t)bi * 3 + tid];
  __syncthreads();
  {
    const int j = tid;
    const float px = pos[(size_t)(b * N_ + j) * 3 + 0];
    const float py = pos[(size_t)(b * N_ + j) * 3 + 1];
    const float pz = pos[(size_t)(b * N_ + j) * 3 + 2];
    const float dx = px - spos[0], dy = py - spos[1], dz = pz - spos[2];
    const float sq = dx * dx + dy * dy + dz * dz;
    const float dist = sqrtf(fmaxf(sq, 1e-24f));
    const float inv = 1.f / (dist + 1e-5f);
    const size_t e = (size_t)bi * N_ + j;
    deltaw[e * 3 + 0] = dx * inv;
    deltaw[e * 3 + 1] = dy * inv;
    deltaw[e * 3 + 2] = dz * inv;
    const int et = atoms[bi] * 64 + atoms[b * N_ + j];
    const float xv = gbf_mul[et] * dist + gbf_bias[et];
    xvalw[e] = xv;
    sxv[j] = xv;
    spad[j] = (atoms[b * N_ + j] == 0);
  }
  __syncthreads();
  const int k = tid & 127;
  const float mean = gbf_means[k];
  const float st = fabsf(gbf_stds[k]) + 1e-5f;
  const float istd = 1.f / st;
  const float coef = 0.39894228040143268f * istd;
  float acc = 0.f;
  const int jbase = tid >> 7;
  for (int t = 0; t < 128; ++t) {
    const int j = jbase + (t << 1);
    if (!spad[j]) {
      const float z = (sxv[j] - mean) * istd;
      acc += __expf(-0.5f * z * z) * coef;
    }
  }
  red[tid] = acc;
  __syncthreads();
  if (tid < 128) nsumw[(size_t)bi * K_ + tid] = red[tid] + red[tid + 128];
}

// ---------------------------------------------------------------------------
// Kernel 2 (MFMA, register datapath): bias MLP per 64-edge tile.
__global__ __launch_bounds__(256) void bias_mfma_kernel(
    const float* __restrict__ xvalw, const int* __restrict__ atoms,
    const float* __restrict__ gbf_means, const float* __restrict__ gbf_stds,
    const unsigned short* __restrict__ w1b, const float* __restrict__ b1,
    const unsigned short* __restrict__ w2b, const float* __restrict__ b2,
    unsigned short* __restrict__ biasb)
{
  __shared__ __align__(16) unsigned short sw1[128 * 128];  // 32 KB, swizzled
  __shared__ __align__(16) unsigned short sw2[32 * 128];   // 8 KB, swizzled
  __shared__ float smean[128], sistd[128], scoef[128], sb1[128], sb2[32];
  const int tid = threadIdx.x;
  const int l = tid & 63;
  const int w = tid >> 6;
  const size_t e0 = (size_t)blockIdx.x * 64;
  const int bB = (int)(e0 >> 16);
  const int iI = (int)((e0 >> 8) & 255);
  const int j0 = (int)(e0 & 255);
  const int lr = l & 15;
  const int lg = l >> 4;

  {
    const int rin = l >> 4;
    const int slot = l & 15;
#pragma unroll
    for (int q = 0; q < 8; ++q) {
      const int rbase = w * 32 + q * 4;
      const int row = rbase + rin;
      const int gs = slot ^ (row & 15);
      gload_lds16(w1b + row * 128 + gs * 8, &sw1[rbase * 128]);
    }
#pragma unroll
    for (int q = 0; q < 2; ++q) {
      const int rbase = w * 8 + q * 4;
      const int row = rbase + rin;
      const int gs = slot ^ (row & 15);
      gload_lds16(w2b + row * 128 + gs * 8, &sw2[rbase * 128]);
    }
  }
  if (tid < 128) {
    const float st = fabsf(gbf_stds[tid]) + 1e-5f;
    const float is = 1.f / st;
    smean[tid] = gbf_means[tid];
    sistd[tid] = is;
    scoef[tid] = 0.39894228040143268f * is;
    sb1[tid] = b1[tid];
  } else if (tid < 160) {
    sb2[tid - 128] = b2[tid - 128];
  }
  const int el = w * 16 + lr;
  const float xv = xvalw[e0 + el];
  const bool padq = (atoms[bB * N_ + j0 + el] == 0);
  __syncthreads();

  bf16x8 bG[4];
#pragma unroll
  for (int ks = 0; ks < 4; ++ks) {
    u16x8 t;
#pragma unroll
    for (int j = 0; j < 8; ++j) {
      const int k = ks * 32 + lg * 8 + j;
      const float z = (xv - smean[k]) * sistd[k];
      t[j] = f2bf(__expf(-0.5f * z * z) * scoef[k]);
    }
    union { u16x8 a; bf16x8 b; } u; u.a = t;
    bG[ks] = u.b;
  }

  f32x4 accM[8];
#pragma unroll
  for (int f = 0; f < 8; ++f) accM[f] = (f32x4)0.f;
  __builtin_amdgcn_s_setprio(1);
#pragma unroll
  for (int ks = 0; ks < 4; ++ks) {
#pragma unroll
    for (int f = 0; f < 8; ++f) {
      const int row = f * 16 + lr;
      const int sl = (ks * 4 + lg) ^ (row & 15);
      const bf16x8 aW = *(const bf16x8*)&sw1[row * 128 + (sl << 3)];
      accM[f] = MFMA16(aW, bG[ks], accM[f]);
    }
  }
  __builtin_amdgcn_s_setprio(0);

  unsigned pm[8][2];
#pragma unroll
  for (int f = 0; f < 8; ++f) {
    float g[4];
#pragma unroll
    for (int r = 0; r < 4; ++r)
      g[r] = gelu_f(accM[f][r] + sb1[f * 16 + lg * 4 + r]);
    pm[f][0] = packbf(g[0], g[1]);
    pm[f][1] = packbf(g[2], g[3]);
  }

  f32x4 accH[2];
  accH[0] = (f32x4)0.f; accH[1] = (f32x4)0.f;
#pragma unroll
  for (int ks = 0; ks < 4; ++ks) {
    const int s0 = ((((lg << 1)) & 3) << 4) + lr;
    const int s1 = ((((lg << 1) + 1) & 3) << 4) + lr;
    const int sel = lg >> 1;
    const unsigned a0 = __shfl(pm[2 * ks][0], s0), b0 = __shfl(pm[2 * ks + 1][0], s0);
    const unsigned a1 = __shfl(pm[2 * ks][1], s0), b1v = __shfl(pm[2 * ks + 1][1], s0);
    const unsigned a2 = __shfl(pm[2 * ks][0], s1), b2v = __shfl(pm[2 * ks + 1][0], s1);
    const unsigned a3 = __shfl(pm[2 * ks][1], s1), b3v = __shfl(pm[2 * ks + 1][1], s1);
    u32x4 bw;
    bw.x = sel ? b0 : a0;
    bw.y = sel ? b1v : a1;
    bw.z = sel ? b2v : a2;
    bw.w = sel ? b3v : a3;
    const bf16x8 bMid = u4_to_bf8(bw);
    __builtin_amdgcn_s_setprio(1);
#pragma unroll
    for (int hf = 0; hf < 2; ++hf) {
      const int row = hf * 16 + lr;
      const int sl = (ks * 4 + lg) ^ (row & 15);
      const bf16x8 aW2 = *(const bf16x8*)&sw2[row * 128 + (sl << 3)];
      accH[hf] = MFMA16(aW2, bMid, accH[hf]);
    }
    __builtin_amdgcn_s_setprio(0);
  }

  const size_t obase = (((size_t)bB * H_) * N_ + iI) * N_ + j0 + el;
#pragma unroll
  for (int hf = 0; hf < 2; ++hf) {
#pragma unroll
    for (int r = 0; r < 4; ++r) {
      const int h = hf * 16 + lg * 4 + r;
      const unsigned short v = padq ? (unsigned short)0xFF80
                                    : f2bf(accH[hf][r] + sb2[h]);
      biasb[obase + (size_t)h * N_ * N_] = v;
    }
  }
}

// ---------------------------------------------------------------------------
// Kernel 3: node init + fused ln1(layer 0) -> hbuf (f32) and ybf (bf16)
__global__ __launch_bounds__(256) void node_init_kernel(
    const int* __restrict__ atoms, const int* __restrict__ tags,
    const float* __restrict__ atom_emb, const float* __restrict__ tag_emb,
    const float* __restrict__ nsumw, const float* __restrict__ ep_w,
    const float* __restrict__ ep_b, const float* __restrict__ gg,
    const float* __restrict__ bb, float* __restrict__ hbuf,
    unsigned short* __restrict__ y)
{
  const int bi = blockIdx.x;
  const int tid = threadIdx.x;
  __shared__ float ns[K_];
  __shared__ float sred[4];
  if (tid < K_) ns[tid] = nsumw[(size_t)bi * K_ + tid];
  __syncthreads();
  const int at = atoms[bi], tg = tags[bi];
  float h[3];
#pragma unroll
  for (int t = 0; t < 3; ++t) {
    const int d = tid + (t << 8);
    float acc = tag_emb[tg * D_ + d] + atom_emb[at * D_ + d] + ep_b[d];
    const float* w = ep_w + (size_t)d * K_;
#pragma unroll 8
    for (int kk = 0; kk < K_; ++kk) acc = fmaf(ns[kk], w[kk], acc);
    hbuf[(size_t)bi * D_ + d] = acc;
    h[t] = acc;
  }
  float s = breduce_sum(h[0] + h[1] + h[2], sred, tid);
  const float mean = s * (1.f / 768.f);
  const float d0 = h[0] - mean, d1 = h[1] - mean, d2 = h[2] - mean;
  float q = breduce_sum(d0 * d0 + d1 * d1 + d2 * d2, sred, tid);
  const float inv = rsqrtf(q * (1.f / 768.f) + 1e-5f);
  unsigned short* out = y + (size_t)bi * D_;
  out[tid]       = f2bf(d0 * inv * gg[tid]       + bb[tid]);
  out[tid + 256] = f2bf(d1 * inv * gg[tid + 256] + bb[tid + 256]);
  out[tid + 512] = f2bf(d2 * inv * gg[tid + 512] + bb[tid + 512]);
}

// ---------------------------------------------------------------------------
// Split-K reduce + residual + bias + LayerNorm -> bf16 y (and updated hbuf).
template <int S>
__global__ __launch_bounds__(256) void reduce_ln_kernel(
    const float* __restrict__ P, const float* __restrict__ bias,
    float* __restrict__ hbuf, const float* __restrict__ gg,
    const float* __restrict__ bb, unsigned short* __restrict__ y)
{
  const int row = blockIdx.x;
  const int tid = threadIdx.x;
  __shared__ float sred[4];
  float h[3];
#pragma unroll
  for (int t = 0; t < 3; ++t) {
    const int c = tid + (t << 8);
    float s = bias[c];
#pragma unroll
    for (int z = 0; z < S; ++z)
      s += P[((size_t)z * (B_ * N_) + row) * 768 + c];
    const float hv = hbuf[(size_t)row * 768 + c] + s;
    hbuf[(size_t)row * 768 + c] = hv;
    h[t] = hv;
  }
  float sm = breduce_sum(h[0] + h[1] + h[2], sred, tid);
  const float mean = sm * (1.f / 768.f);
  const float d0 = h[0] - mean, d1 = h[1] - mean, d2 = h[2] - mean;
  float q = breduce_sum(d0 * d0 + d1 * d1 + d2 * d2, sred, tid);
  const float inv = rsqrtf(q * (1.f / 768.f) + 1e-5f);
  unsigned short* out = y + (size_t)row * 768;
  out[tid]       = f2bf(d0 * inv * gg[tid]       + bb[tid]);
  out[tid + 256] = f2bf(d1 * inv * gg[tid + 256] + bb[tid + 256]);
  out[tid + 512] = f2bf(d2 * inv * gg[tid + 512] + bb[tid + 512]);
}

// ---------------------------------------------------------------------------
// MFMA GEMM (R8 16x16 version): A bf16 [M,lda], W bf16 [N,ldw], 64x64 tile,
// BK=64, 4 waves, double-buffered global_load_lds, drain-barrier loop.
// EPI: 0 bias; 1 gelu(bias+); 3 segment-bias (768-chunks, gelu on seg 3);
//      4 split-K raw partial (blockIdx.z selects K-slice, C offset z*M*N).
template <int EPI, int OB>
__global__ __launch_bounds__(256) void gemm_mfma(
    const unsigned short* __restrict__ A, const unsigned short* __restrict__ W,
    const float* __restrict__ bias, const float* __restrict__ bias2,
    const float* __restrict__ bias3, const float* __restrict__ bias4,
    float* __restrict__ C, unsigned short* __restrict__ Cb,
    int M, int N, int K, int lda, int ldw)
{
  if (EPI == 4) {
    const int z = blockIdx.z;
    A += (size_t)z * K;
    W += (size_t)z * K;
    C += (size_t)z * M * N;
  }
  __shared__ __align__(16) unsigned short sA[2][64 * 64];
  __shared__ __align__(16) unsigned short sB[2][64 * 64];
  const int tid = threadIdx.x;
  const int l = tid & 63;
  const int w = tid >> 6;
  const int m0 = blockIdx.y * 64;
  const int n0 = blockIdx.x * 64;
  const int wm = w >> 1, wn = w & 1;
  const int lr = l & 15;
  const int lg = l >> 4;
  const int r0 = (w << 4) + (l >> 3);
  const int s0 = (l & 7) ^ (r0 & 7);

  f32x4 acc[2][2];
#pragma unroll
  for (int mi = 0; mi < 2; ++mi)
#pragma unroll
    for (int ni = 0; ni < 2; ++ni) acc[mi][ni] = (f32x4)0.f;

  auto stage = [&](int buf, int t) {
    const size_t kb = (size_t)t << 6;
    unsigned short* lA = &sA[buf][(w << 4) << 6];
    unsigned short* lB = &sB[buf][(w << 4) << 6];
    gload_lds16(A + (size_t)(m0 + r0) * lda + kb + (s0 << 3), lA);
    gload_lds16(A + (size_t)(m0 + r0 + 8) * lda + kb + (s0 << 3), lA + 8 * 64);
    gload_lds16(W + (size_t)(n0 + r0) * ldw + kb + (s0 << 3), lB);
    gload_lds16(W + (size_t)(n0 + r0 + 8) * ldw + kb + (s0 << 3), lB + 8 * 64);
  };

  stage(0, 0);
  const int nt = K >> 6;
  for (int t = 0; t < nt; ++t) {
    __syncthreads();   // drains vmcnt: buf[t&1] staged; prev reads done
    if (t + 1 < nt) stage((t + 1) & 1, t + 1);
    const unsigned short* bA = sA[t & 1];
    const unsigned short* bBs = sB[t & 1];
    bf16x8 af[2][2], bfr[2][2];
#pragma unroll
    for (int mi = 0; mi < 2; ++mi) {
      const int row = (wm << 5) + (mi << 4) + lr;
#pragma unroll
      for (int kk = 0; kk < 2; ++kk) {
        const int sl = ((kk << 2) + lg) ^ (row & 7);
        af[mi][kk] = *(const bf16x8*)&bA[(row << 6) + (sl << 3)];
      }
    }
#pragma unroll
    for (int ni = 0; ni < 2; ++ni) {
      const int row = (wn << 5) + (ni << 4) + lr;
#pragma unroll
      for (int kk = 0; kk < 2; ++kk) {
        const int sl = ((kk << 2) + lg) ^ (row & 7);
        bfr[ni][kk] = *(const bf16x8*)&bBs[(row << 6) + (sl << 3)];
      }
    }
#pragma unroll
    for (int kk = 0; kk < 2; ++kk)
#pragma unroll
      for (int mi = 0; mi < 2; ++mi)
#pragma unroll
        for (int ni = 0; ni < 2; ++ni)
          acc[mi][ni] = MFMA16(af[mi][kk], bfr[ni][kk], acc[mi][ni]);
  }

#pragma unroll
  for (int mi = 0; mi < 2; ++mi)
#pragma unroll
    for (int ni = 0; ni < 2; ++ni) {
      const int n = n0 + (wn << 5) + (ni << 4) + lr;
      float bv = 0.f;
      int seg = 0;
      if (EPI == 3) {
        seg = n / 768;
        const float* bp = (seg == 0) ? bias : (seg == 1) ? bias2
                         : (seg == 2) ? bias3 : bias4;
        bv = bp[n - seg * 768];
      } else if (EPI != 4) {
        bv = bias[n];
      }
#pragma unroll
      for (int r = 0; r < 4; ++r) {
        const int m = m0 + (wm << 5) + (mi << 4) + lg * 4 + r;
        float v = acc[mi][ni][r] + bv;
        if (EPI == 1) v = gelu_f(v);
        if (EPI == 3 && seg == 3) v = gelu_f(v);
        if (OB) Cb[(size_t)m * N + n] = f2bf(v);
        else C[(size_t)m * N + n] = v;
      }
    }
}

// ---------------------------------------------------------------------------
// MFMA attention, bf16 Q/K/V inputs. grid = (B*H, 4), block = 256 (4 waves).
// PV path: unnormalized P in sP, per-lane invr[] applied to O (defer-norm).
template <bool PROBS>
__global__ __launch_bounds__(256) void attn_mfma_kernel(
    const unsigned short* __restrict__ Q, const unsigned short* __restrict__ Kp,
    const unsigned short* __restrict__ Vp, const int stride,
    const unsigned short* __restrict__ biasb, unsigned short* __restrict__ obuf,
    unsigned short* __restrict__ aprob)
{
  __shared__ __align__(16) unsigned short sK[256 * 40];   // [j][d pad40]
  __shared__ __align__(16) unsigned short sVt[32 * 264];  // [d][j pad264]
  __shared__ __align__(16) unsigned short sP[64 * 264];   // [i_loc][j pad264]
  const int tid = threadIdx.x;
  const int l = tid & 63, w = tid >> 6;
  const int bh = blockIdx.x, b = bh >> 5, hh = bh & 31;
  const int i0 = blockIdx.y * 64;
  const int lr = l & 15, lg = l >> 4;

#pragma unroll
  for (int it = 0; it < 3; ++it) {
    const int c = tid + (it << 8);        // < 768
    const int row = c / 3, part = c - row * 3;
    *(u16x8*)&sK[row * 40 + part * 8] =
        *(const u16x8*)&Kp[(size_t)(b * N_ + row) * stride + hh * HD_ + part * 8];
  }
  {
    u16x8 z = {0, 0, 0, 0, 0, 0, 0, 0};
    *(u16x8*)&sK[tid * 40 + 24] = z;
  }
  if (!PROBS) {
    const int j = tid;
    const unsigned short* vr = &Vp[(size_t)(b * N_ + j) * stride + hh * HD_];
    const u16x8 v0 = *(const u16x8*)vr;
    const u16x8 v1 = *(const u16x8*)(vr + 8);
    const u16x8 v2 = *(const u16x8*)(vr + 16);
#pragma unroll
    for (int d = 0; d < 8; ++d) {
      sVt[d * 264 + j] = v0[d];
      sVt[(8 + d) * 264 + j] = v1[d];
      sVt[(16 + d) * 264 + j] = v2[d];
    }
  }
  bf16x8 aQ;
  if (lg < 3) {
    const u16x8 q = *(const u16x8*)&Q[(size_t)(b * N_ + i0 + (w << 4) + lr) * stride + hh * HD_ + lg * 8];
    union { u16x8 a; bf16x8 b; } u; u.a = q;
    aQ = u.b;
  } else {
    bf16x8 t = {0, 0, 0, 0, 0, 0, 0, 0};
    aQ = t;
  }
  __syncthreads();

  f32x4 acc[16];
  __builtin_amdgcn_s_setprio(1);
#pragma unroll
  for (int ni = 0; ni < 16; ++ni) {
    const bf16x8 bK = *(const bf16x8*)&sK[(ni * 16 + lr) * 40 + lg * 8];
    acc[ni] = MFMA16(aQ, bK, (f32x4)0.f);
  }
  __builtin_amdgcn_s_setprio(0);

  float invr[4];
#pragma unroll
  for (int r = 0; r < 4; ++r) {
    const int iloc = (w << 4) + lg * 4 + r;
    const unsigned short* bp =
        &biasb[(((size_t)(b * H_ + hh)) * N_ + i0 + iloc) * N_ + lr];
    float mx = -INFINITY;
#pragma unroll
    for (int ni = 0; ni < 16; ++ni) {
      const float s = acc[ni][r] * SCALE_ + bf2f(bp[ni * 16]);
      acc[ni][r] = s;
      mx = fmaxf(mx, s);
    }
    mx = fmaxf(mx, __shfl_xor(mx, 1));
    mx = fmaxf(mx, __shfl_xor(mx, 2));
    mx = fmaxf(mx, __shfl_xor(mx, 4));
    mx = fmaxf(mx, __shfl_xor(mx, 8));
    float sum = 0.f;
#pragma unroll
    for (int ni = 0; ni < 16; ++ni) {
      const float e = __expf(acc[ni][r] - mx);
      acc[ni][r] = e;
      sum += e;
    }
    sum += __shfl_xor(sum, 1);
    sum += __shfl_xor(sum, 2);
    sum += __shfl_xor(sum, 4);
    sum += __shfl_xor(sum, 8);
    const float inv = 1.f / sum;
    invr[r] = inv;
#pragma unroll
    for (int ni = 0; ni < 16; ++ni)
      sP[iloc * 264 + ni * 16 + lr] = f2bf(PROBS ? acc[ni][r] * inv
                                                 : acc[ni][r]);
  }
  __syncthreads();

  if (PROBS) {
#pragma unroll
    for (int it = 0; it < 8; ++it) {
      const int idx = tid + it * 256;     // < 2048
      const int row = idx >> 5, c = idx & 31;
      *(u16x8*)&aprob[(((size_t)(b * H_ + hh)) * N_ + i0 + row) * N_ + c * 8] =
          *(const u16x8*)&sP[row * 264 + c * 8];
    }
  } else {
    f32x4 accO[2];
    accO[0] = (f32x4)0.f; accO[1] = (f32x4)0.f;
    __builtin_amdgcn_s_setprio(1);
#pragma unroll
    for (int ks = 0; ks < 8; ++ks) {
      const bf16x8 aP = *(const bf16x8*)&sP[((w << 4) + lr) * 264 + ks * 32 + lg * 8];
      const bf16x8 bV0 = *(const bf16x8*)&sVt[lr * 264 + ks * 32 + lg * 8];
      const bf16x8 bV1 = *(const bf16x8*)&sVt[(16 + lr) * 264 + ks * 32 + lg * 8];
      accO[0] = MFMA16(aP, bV0, accO[0]);
      accO[1] = MFMA16(aP, bV1, accO[1]);
    }
    __builtin_amdgcn_s_setprio(0);
#pragma unroll
    for (int ni = 0; ni < 2; ++ni) {
      const int n = ni * 16 + lr;
      if (n < HD_) {
#pragma unroll
        for (int r = 0; r < 4; ++r) {
          const int i = i0 + (w << 4) + lg * 4 + r;
          obuf[(size_t)(b * N_ + i) * D_ + hh * HD_ + n] = f2bf(accO[ni][r] * invr[r]);
        }
      }
    }
  }
}

// ---------------------------------------------------------------------------
// Energy head (t1 bf16, rows strided)
__global__ __launch_bounds__(256) void engnode_kernel(
    const unsigned short* __restrict__ t1, const int stride,
    const float* __restrict__ en_w2, const float* __restrict__ en_b2,
    const float* __restrict__ eagg, const int* __restrict__ tags,
    float* __restrict__ engpn)
{
  const int bi = blockIdx.x;
  const int tid = threadIdx.x;
  __shared__ float sred[4];
  const unsigned short* row = t1 + (size_t)bi * stride;
  float acc = bf2f(row[tid]) * en_w2[tid] + bf2f(row[tid + 256]) * en_w2[tid + 256] +
              bf2f(row[tid + 512]) * en_w2[tid + 512];
  acc = breduce_sum(acc, sred, tid);
  if (tid == 0) {
    const int tg = tags[bi];
    engpn[bi] = (tg > 0) ? (acc + en_b2[0]) * eagg[tg] : 0.f;
  }
}

// engsum (blocks 0..3) + omask (blocks 4..7) merged
__global__ __launch_bounds__(256) void engsum_omask_kernel(
    const float* __restrict__ engpn, const int* __restrict__ tags,
    float* __restrict__ out)
{
  const int bid = blockIdx.x;
  const int tid = threadIdx.x;
  if (bid < 4) {
    __shared__ float sred[4];
    float v = breduce_sum(engpn[bid * N_ + tid], sred, tid);
    if (tid == 0) out[bid] = v;
  } else {
    const int idx = (bid - 4) * 256 + tid;
    out[4 + B_ * N_ * 3 + idx] = (tags[idx] > 0) ? 1.f : 0.f;
  }
}

// ---------------------------------------------------------------------------
// wv[c][b,h,j] = sum_d v[b,j,h*HD+d] * fc_w[h*HD+d]   (v bf16)
__global__ __launch_bounds__(256) void wv_kernel(
    const unsigned short* __restrict__ vn, const int stride,
    const float* __restrict__ f1w, const float* __restrict__ f2w,
    const float* __restrict__ f3w, float* __restrict__ wv)
{
  const int idx = blockIdx.x * 256 + threadIdx.x;
  const int j = idx & 255;
  const int hh = (idx >> 8) & 31;
  const int b = (idx >> 13) & 3;
  const int c = idx >> 15;
  const float* fw = (c == 0) ? f1w : ((c == 1) ? f2w : f3w);
  const unsigned short* vrow = vn + (size_t)(b * N_ + j) * stride + hh * HD_;
  const u16x8 v0 = *(const u16x8*)vrow;
  const u16x8 v1 = *(const u16x8*)(vrow + 8);
  const u16x8 v2 = *(const u16x8*)(vrow + 16);
  float acc = 0.f;
#pragma unroll
  for (int d = 0; d < 8; ++d) {
    acc = fmaf(bf2f(v0[d]), fw[hh * HD_ + d], acc);
    acc = fmaf(bf2f(v1[d]), fw[hh * HD_ + 8 + d], acc);
    acc = fmaf(bf2f(v2[d]), fw[hh * HD_ + 16 + d], acc);
  }
  wv[idx] = acc;
}

// merged-c nodeout: grid = BN
__global__ __launch_bounds__(256) void nodeout_kernel(
    const unsigned short* __restrict__ aprob, const float* __restrict__ wv,
    const float* __restrict__ deltaw, const float* __restrict__ f1b,
    const float* __restrict__ f2b, const float* __restrict__ f3b,
    float* __restrict__ out)
{
  const int bi = blockIdx.x;
  const int tid = threadIdx.x;
  const int b = bi >> 8;
  const int i = bi & 255;
  __shared__ float sred[4];
  const unsigned short* ap = aprob + (((size_t)b * H_) * N_ + i) * N_ + tid;
  const float* wv0 = wv + ((size_t)(0 * B_ + b) * H_) * N_ + tid;
  const float* wv1 = wv + ((size_t)(1 * B_ + b) * H_) * N_ + tid;
  const float* wv2 = wv + ((size_t)(2 * B_ + b) * H_) * N_ + tid;
  float s0 = 0.f, s1 = 0.f, s2 = 0.f;
  for (int hh = 0; hh < H_; ++hh) {
    const float p = bf2f(ap[(size_t)hh * N_ * N_]);
    s0 = fmaf(p, wv0[(size_t)hh * N_], s0);
    s1 = fmaf(p, wv1[(size_t)hh * N_], s1);
    s2 = fmaf(p, wv2[(size_t)hh * N_], s2);
  }
  const float* dl = &deltaw[((size_t)bi * N_ + tid) * 3];
  s0 *= dl[0];
  s1 *= dl[1];
  s2 *= dl[2];
  s0 = breduce_sum(s0, sred, tid);
  s1 = breduce_sum(s1, sred, tid);
  s2 = breduce_sum(s2, sred, tid);
  if (tid == 0) {
    out[4 + bi * 3 + 0] = s0 + f1b[0];
    out[4 + bi * 3 + 1] = s1 + f2b[0];
    out[4 + bi * 3 + 2] = s2 + f3b[0];
  }
}

// ---------------------------------------------------------------------------
extern "C" void kernel_launch(void* const* d_in, const int* in_sizes, int n_in,
                              void* d_out, int out_size, void* d_ws, size_t ws_size,
                              hipStream_t stream) {
  (void)in_sizes; (void)n_in; (void)out_size; (void)ws_size;
  const int*   atoms     = (const int*)  d_in[0];
  const int*   tags      = (const int*)  d_in[1];
  const float* pos       = (const float*)d_in[2];
  const float* atom_emb  = (const float*)d_in[4];
  const float* tag_emb   = (const float*)d_in[5];
  const float* gbf_means = (const float*)d_in[6];
  const float* gbf_stds  = (const float*)d_in[7];
  const float* gbf_mul   = (const float*)d_in[8];
  const float* gbf_bias  = (const float*)d_in[9];
  const float* bp_w1     = (const float*)d_in[10];
  const float* bp_b1     = (const float*)d_in[11];
  const float* bp_w2     = (const float*)d_in[12];
  const float* bp_b2     = (const float*)d_in[13];
  const float* ep_w      = (const float*)d_in[14];
  const float* ep_b      = (const float*)d_in[15];
  const float* ln1_g     = (const float*)d_in[16];
  const float* ln1_b     = (const float*)d_in[17];
  const float* wqkv      = (const float*)d_in[18];
  const float* bqkv      = (const float*)d_in[19];
  const float* wo        = (const float*)d_in[20];
  const float* bo        = (const float*)d_in[21];
  const float* ln2_g     = (const float*)d_in[22];
  const float* ln2_b     = (const float*)d_in[23];
  const float* w1        = (const float*)d_in[24];
  const float* b1        = (const float*)d_in[25];
  const float* w2        = (const float*)d_in[26];
  const float* b2        = (const float*)d_in[27];
  const float* fln_g     = (const float*)d_in[28];
  const float* fln_b     = (const float*)d_in[29];
  const float* en_w1     = (const float*)d_in[30];
  const float* en_b1     = (const float*)d_in[31];
  const float* en_w2     = (const float*)d_in[32];
  const float* en_b2     = (const float*)d_in[33];
  const float* eagg      = (const float*)d_in[34];
  const float* nq_w      = (const float*)d_in[35];
  const float* nq_b      = (const float*)d_in[36];
  const float* nk_w      = (const float*)d_in[37];
  const float* nk_b      = (const float*)d_in[38];
  const float* nv_w      = (const float*)d_in[39];
  const float* nv_b      = (const float*)d_in[40];
  const float* f1_w      = (const float*)d_in[41];
  const float* f1_b      = (const float*)d_in[42];
  const float* f2_w      = (const float*)d_in[43];
  const float* f2_b      = (const float*)d_in[44];
  const float* f3_w      = (const float*)d_in[45];
  const float* f3_b      = (const float*)d_in[46];

  char* wsB = (char*)d_ws;
  size_t off = 0;
  auto alloc = [&](size_t bytes) {
    void* p = wsB + off;
    off = (off + bytes + 255) & ~(size_t)255;
    return p;
  };
  unsigned short* biasb   = (unsigned short*)alloc((size_t)B_ * H_ * N_ * N_ * 2);
  unsigned short* aprobb  = (unsigned short*)alloc((size_t)B_ * H_ * N_ * N_ * 2);
  float*          deltaw  = (float*)alloc((size_t)B_ * N_ * N_ * 3 * 4);
  float*          xvalw   = (float*)alloc((size_t)B_ * N_ * N_ * 4);
  float*          nsumw   = (float*)alloc((size_t)B_ * N_ * K_ * 4);
  float*          hbuf    = (float*)alloc((size_t)B_ * N_ * D_ * 4);
  unsigned short* qkvb    = (unsigned short*)alloc((size_t)B_ * N_ * 3 * D_ * 2);
  unsigned short* qn4b    = (unsigned short*)alloc((size_t)B_ * N_ * 3072 * 2);
  unsigned short* ybf     = (unsigned short*)alloc((size_t)B_ * N_ * D_ * 2);
  unsigned short* obf     = (unsigned short*)alloc((size_t)B_ * N_ * D_ * 2);
  unsigned short* midbf   = (unsigned short*)alloc((size_t)B_ * N_ * F_ * 2);
  unsigned short* outbf   = (unsigned short*)alloc((size_t)B_ * N_ * D_ * 2);
  unsigned short* arena   = (unsigned short*)alloc((size_t)7077888 * 2);
  unsigned short* headsb  = (unsigned short*)alloc((size_t)2359296 * 2);
  unsigned short* bw1b    = (unsigned short*)alloc((size_t)K_ * K_ * 2);
  unsigned short* bw2b    = (unsigned short*)alloc((size_t)H_ * K_ * 2);
  float*          wopart  = (float*)alloc((size_t)2 * B_ * N_ * D_ * 4);
  float*          ffpart  = (float*)alloc((size_t)4 * B_ * N_ * D_ * 4);
  float*          wvb     = (float*)alloc((size_t)3 * B_ * H_ * N_ * 4);
  float*          engpn   = (float*)alloc((size_t)B_ * N_ * 4);

  const int BN = B_ * N_;  // 1024
  float* outp = (float*)d_out;
  const size_t OQKV = 0, OWO = 1769472, OW1 = 2359296, OW2 = 4718592;

  edge_pre_kernel<<<BN, 256, 0, stream>>>(atoms, pos, gbf_mul, gbf_bias,
                                          gbf_means, gbf_stds, deltaw, xvalw, nsumw);
  cast_bias_kernel<<<20, 256, 0, stream>>>(bp_w1, bp_w2, bw1b, bw2b);
  bias_mfma_kernel<<<B_ * N_ * N_ / 64, 256, 0, stream>>>(
      xvalw, atoms, gbf_means, gbf_stds, bw1b, bp_b1, bw2b, bp_b2, biasb);
  node_init_kernel<<<BN, 256, 0, stream>>>(atoms, tags, atom_emb, tag_emb,
                                           nsumw, ep_w, ep_b, ln1_g, ln1_b,
                                           hbuf, ybf);

  for (int l = 0; l < L_; ++l) {
    castlayer_kernel<<<3456, 256, 0, stream>>>(
        wqkv + (size_t)l * 3 * D_ * D_, wo + (size_t)l * D_ * D_,
        w1 + (size_t)l * F_ * D_, w2 + (size_t)l * D_ * F_, arena);
    // QKV: [1024,2304] bf16
    gemm_mfma<0, 1><<<dim3(36, 16), 256, 0, stream>>>(
        ybf, arena + OQKV, bqkv + (size_t)l * 3 * D_, nullptr, nullptr, nullptr,
        nullptr, qkvb, BN, 3 * D_, D_, D_, D_);
    attn_mfma_kernel<false><<<dim3(B_ * H_, 4), 256, 0, stream>>>(
        qkvb, qkvb + D_, qkvb + 2 * D_, 3 * D_, biasb, obf, nullptr);
    // wo: split-K=2 partials, then reduce + res + ln2 -> ybf
    gemm_mfma<4, 0><<<dim3(12, 16, 2), 256, 0, stream>>>(
        obf, arena + OWO, nullptr, nullptr, nullptr, nullptr,
        wopart, nullptr, BN, D_, 384, D_, D_);
    reduce_ln_kernel<2><<<BN, 256, 0, stream>>>(
        wopart, bo + (size_t)l * D_, hbuf, ln2_g + (size_t)l * D_,
        ln2_b + (size_t)l * D_, ybf);
    // FFN1: gelu -> midbf bf16
    gemm_mfma<1, 1><<<dim3(48, 16), 256, 0, stream>>>(
        ybf, arena + OW1, b1 + (size_t)l * F_, nullptr, nullptr, nullptr,
        nullptr, midbf, BN, F_, D_, D_, D_);
    // FFN2: split-K=4 partials, then reduce + res + ln1(l+1) (or fln) -> y
    gemm_mfma<4, 0><<<dim3(12, 16, 4), 256, 0, stream>>>(
        midbf, arena + OW2, nullptr, nullptr, nullptr, nullptr,
        ffpart, nullptr, BN, D_, 768, F_, F_);
    const bool last = (l == L_ - 1);
    reduce_ln_kernel<4><<<BN, 256, 0, stream>>>(
        ffpart, b2 + (size_t)l * D_, hbuf,
        last ? fln_g : ln1_g + (size_t)(l + 1) * D_,
        last ? fln_b : ln1_b + (size_t)(l + 1) * D_,
        last ? outbf : ybf);
  }

  // head weights -> headsb: [nq | nk | nv | en_w1], 3072 rows of K=768
  castheads_kernel<<<1152, 256, 0, stream>>>(nq_w, nk_w, nv_w, en_w1, headsb);

  // merged head GEMM: N = 3072 (q|k|v|t1), gelu on the en segment, bf16 out
  gemm_mfma<3, 1><<<dim3(48, 16), 256, 0, stream>>>(
      outbf, headsb, nq_b, nk_b, nv_b, en_b1,
      nullptr, qn4b, BN, 3072, D_, D_, D_);

  attn_mfma_kernel<true><<<dim3(B_ * H_, 4), 256, 0, stream>>>(
      qn4b, qn4b + 768, qn4b + 1536, 3072, biasb, nullptr, aprobb);
  wv_kernel<<<3 * B_ * H_ * N_ / 256, 256, 0, stream>>>(
      qn4b + 1536, 3072, f1_w, f2_w, f3_w, wvb);
  nodeout_kernel<<<BN, 256, 0, stream>>>(aprobb, wvb, deltaw,
                                         f1_b, f2_b, f3_b, outp);

  engnode_kernel<<<BN, 256, 0, stream>>>(qn4b + 2304, 3072, en_w2, en_b2,
                                         eagg, tags, engpn);
  engsum_omask_kernel<<<8, 256, 0, stream>>>(engpn, tags, outp);
}

// Round 12
// 1014.878 us; speedup vs baseline: 1.0256x; 1.0122x over previous
//
#include <hip/hip_runtime.h>
#include <math.h>

// Graphormer3D forward — round 11: R8 config (measured best, 1020us) with
// wv folded into the PROBS attention epilogue (one fewer dispatch).
// B=4 N=256 D=768 H=32 HD=24 L=12 F=3072 K=128
constexpr int B_ = 4, N_ = 256, D_ = 768, H_ = 32, HD_ = 24, L_ = 12, F_ = 3072, K_ = 128;
constexpr float SCALE_ = 0.20412414523193150f;   // HD^-0.5
constexpr float ISQRT2_ = 0.70710678118654752f;

typedef short bf16x8 __attribute__((ext_vector_type(8)));
typedef float f32x4 __attribute__((ext_vector_type(4)));
typedef unsigned short u16x4 __attribute__((ext_vector_type(4)));
typedef unsigned short u16x8 __attribute__((ext_vector_type(8)));
typedef unsigned int u32x4 __attribute__((ext_vector_type(4)));

#define DEV __device__ __forceinline__
#define MFMA16(a, b, c) __builtin_amdgcn_mfma_f32_16x16x32_bf16(a, b, c, 0, 0, 0)

DEV void gload_lds16(const unsigned short* g, unsigned short* l) {
  __builtin_amdgcn_global_load_lds(
      (const __attribute__((address_space(1))) unsigned int*)(g),
      (__attribute__((address_space(3))) unsigned int*)(l), 16, 0, 0);
}

DEV float gelu_f(float x) { return 0.5f * x * (1.0f + erff(x * ISQRT2_)); }

DEV unsigned short f2bf(float f) {  // RNE f32 -> bf16
  unsigned u = __float_as_uint(f);
  return (unsigned short)((u + 0x7FFFu + ((u >> 16) & 1u)) >> 16);
}
DEV float bf2f(unsigned short u) { return __uint_as_float(((unsigned)u) << 16); }
DEV unsigned packbf(float a, float b) {
  return (unsigned)f2bf(a) | ((unsigned)f2bf(b) << 16);
}
DEV bf16x8 u4_to_bf8(u32x4 x) { union { u32x4 a; bf16x8 b; } u; u.a = x; return u.b; }

// deterministic block(256) reductions
DEV float breduce_sum(float v, float* sred, int tid) {
#pragma unroll
  for (int o = 32; o > 0; o >>= 1) v += __shfl_xor(v, o);
  if ((tid & 63) == 0) sred[tid >> 6] = v;
  __syncthreads();
  v = (sred[0] + sred[1]) + (sred[2] + sred[3]);
  __syncthreads();
  return v;
}

// ---------------------------------------------------------------------------
// bias-MLP weights (bp_w1 4096 float4 | bp_w2 1024 float4) -> bf16, 1 dispatch
__global__ __launch_bounds__(256) void cast_bias_kernel(
    const float* __restrict__ w1f, const float* __restrict__ w2f,
    unsigned short* __restrict__ d1, unsigned short* __restrict__ d2) {
  const int i = blockIdx.x * 256 + threadIdx.x;  // < 5120
  const float* s;
  unsigned short* d;
  int j;
  if (i < 4096) { s = w1f; d = d1; j = i; }
  else { s = w2f; d = d2; j = i - 4096; }
  const float4 v = ((const float4*)s)[j];
  u16x4 o = {f2bf(v.x), f2bf(v.y), f2bf(v.z), f2bf(v.w)};
  ((u16x4*)d)[j] = o;
}

// per-layer weights -> rotating arena (qkv | wo | w1 | w2), 32B read/16B write
__global__ __launch_bounds__(256) void castlayer_kernel(
    const float* __restrict__ wqkv, const float* __restrict__ wo,
    const float* __restrict__ w1, const float* __restrict__ w2,
    unsigned short* __restrict__ arena) {
  const unsigned i = blockIdx.x * 256 + threadIdx.x;  // u16x8 unit
  const float* s; unsigned j;
  if (i < 221184u) { s = wqkv; j = i; }
  else if (i < 294912u) { s = wo; j = i - 221184u; }
  else if (i < 589824u) { s = w1; j = i - 294912u; }
  else { s = w2; j = i - 589824u; }
  const float4 a = ((const float4*)s)[2u * j];
  const float4 b = ((const float4*)s)[2u * j + 1u];
  u16x8 o = {f2bf(a.x), f2bf(a.y), f2bf(a.z), f2bf(a.w),
             f2bf(b.x), f2bf(b.y), f2bf(b.z), f2bf(b.w)};
  ((u16x8*)arena)[i] = o;
}

// head weights (nq,nk,nv,en_w1) -> headsb; 294912 u16x8 units, grid 1152
__global__ __launch_bounds__(256) void castheads_kernel(
    const float* __restrict__ a, const float* __restrict__ b,
    const float* __restrict__ c, const float* __restrict__ d,
    unsigned short* __restrict__ arena) {
  const unsigned i = blockIdx.x * 256 + threadIdx.x;
  const unsigned r = i / 73728u;
  const unsigned j = i - r * 73728u;
  const float* s = (r == 0) ? a : (r == 1) ? b : (r == 2) ? c : d;
  const float4 a0 = ((const float4*)s)[2u * j];
  const float4 a1 = ((const float4*)s)[2u * j + 1u];
  u16x8 o = {f2bf(a0.x), f2bf(a0.y), f2bf(a0.z), f2bf(a0.w),
             f2bf(a1.x), f2bf(a1.y), f2bf(a1.z), f2bf(a1.w)};
  ((u16x8*)arena)[i] = o;
}

// ---------------------------------------------------------------------------
// Kernel 1: per-(b,i) edge precompute (f32)
__global__ __launch_bounds__(256) void edge_pre_kernel(
    const int* __restrict__ atoms, const float* __restrict__ pos,
    const float* __restrict__ gbf_mul, const float* __restrict__ gbf_bias,
    const float* __restrict__ gbf_means, const float* __restrict__ gbf_stds,
    float* __restrict__ deltaw, float* __restrict__ xvalw, float* __restrict__ nsumw)
{
  const int tid = threadIdx.x;
  const int bi = blockIdx.x;
  const int b = bi >> 8;
  __shared__ float spos[3];
  __shared__ float sxv[256];
  __shared__ int   spad[256];
  __shared__ float red[256];
  if (tid < 3) spos[tid] = pos[(size_t)bi * 3 + tid];
  __syncthreads();
  {
    const int j = tid;
    const float px = pos[(size_t)(b * N_ + j) * 3 + 0];
    const float py = pos[(size_t)(b * N_ + j) * 3 + 1];
    const float pz = pos[(size_t)(b * N_ + j) * 3 + 2];
    const float dx = px - spos[0], dy = py - spos[1], dz = pz - spos[2];
    const float sq = dx * dx + dy * dy + dz * dz;
    const float dist = sqrtf(fmaxf(sq, 1e-24f));
    const float inv = 1.f / (dist + 1e-5f);
    const size_t e = (size_t)bi * N_ + j;
    deltaw[e * 3 + 0] = dx * inv;
    deltaw[e * 3 + 1] = dy * inv;
    deltaw[e * 3 + 2] = dz * inv;
    const int et = atoms[bi] * 64 + atoms[b * N_ + j];
    const float xv = gbf_mul[et] * dist + gbf_bias[et];
    xvalw[e] = xv;
    sxv[j] = xv;
    spad[j] = (atoms[b * N_ + j] == 0);
  }
  __syncthreads();
  const int k = tid & 127;
  const float mean = gbf_means[k];
  const float st = fabsf(gbf_stds[k]) + 1e-5f;
  const float istd = 1.f / st;
  const float coef = 0.39894228040143268f * istd;
  float acc = 0.f;
  const int jbase = tid >> 7;
  for (int t = 0; t < 128; ++t) {
    const int j = jbase + (t << 1);
    if (!spad[j]) {
      const float z = (sxv[j] - mean) * istd;
      acc += __expf(-0.5f * z * z) * coef;
    }
  }
  red[tid] = acc;
  __syncthreads();
  if (tid < 128) nsumw[(size_t)bi * K_ + tid] = red[tid] + red[tid + 128];
}

// ---------------------------------------------------------------------------
// Kernel 2 (MFMA, register datapath): bias MLP per 64-edge tile.
__global__ __launch_bounds__(256) void bias_mfma_kernel(
    const float* __restrict__ xvalw, const int* __restrict__ atoms,
    const float* __restrict__ gbf_means, const float* __restrict__ gbf_stds,
    const unsigned short* __restrict__ w1b, const float* __restrict__ b1,
    const unsigned short* __restrict__ w2b, const float* __restrict__ b2,
    unsigned short* __restrict__ biasb)
{
  __shared__ __align__(16) unsigned short sw1[128 * 128];  // 32 KB, swizzled
  __shared__ __align__(16) unsigned short sw2[32 * 128];   // 8 KB, swizzled
  __shared__ float smean[128], sistd[128], scoef[128], sb1[128], sb2[32];
  const int tid = threadIdx.x;
  const int l = tid & 63;
  const int w = tid >> 6;
  const size_t e0 = (size_t)blockIdx.x * 64;
  const int bB = (int)(e0 >> 16);
  const int iI = (int)((e0 >> 8) & 255);
  const int j0 = (int)(e0 & 255);
  const int lr = l & 15;
  const int lg = l >> 4;

  {
    const int rin = l >> 4;
    const int slot = l & 15;
#pragma unroll
    for (int q = 0; q < 8; ++q) {
      const int rbase = w * 32 + q * 4;
      const int row = rbase + rin;
      const int gs = slot ^ (row & 15);
      gload_lds16(w1b + row * 128 + gs * 8, &sw1[rbase * 128]);
    }
#pragma unroll
    for (int q = 0; q < 2; ++q) {
      const int rbase = w * 8 + q * 4;
      const int row = rbase + rin;
      const int gs = slot ^ (row & 15);
      gload_lds16(w2b + row * 128 + gs * 8, &sw2[rbase * 128]);
    }
  }
  if (tid < 128) {
    const float st = fabsf(gbf_stds[tid]) + 1e-5f;
    const float is = 1.f / st;
    smean[tid] = gbf_means[tid];
    sistd[tid] = is;
    scoef[tid] = 0.39894228040143268f * is;
    sb1[tid] = b1[tid];
  } else if (tid < 160) {
    sb2[tid - 128] = b2[tid - 128];
  }
  const int el = w * 16 + lr;
  const float xv = xvalw[e0 + el];
  const bool padq = (atoms[bB * N_ + j0 + el] == 0);
  __syncthreads();

  bf16x8 bG[4];
#pragma unroll
  for (int ks = 0; ks < 4; ++ks) {
    u16x8 t;
#pragma unroll
    for (int j = 0; j < 8; ++j) {
      const int k = ks * 32 + lg * 8 + j;
      const float z = (xv - smean[k]) * sistd[k];
      t[j] = f2bf(__expf(-0.5f * z * z) * scoef[k]);
    }
    union { u16x8 a; bf16x8 b; } u; u.a = t;
    bG[ks] = u.b;
  }

  f32x4 accM[8];
#pragma unroll
  for (int f = 0; f < 8; ++f) accM[f] = (f32x4)0.f;
#pragma unroll
  for (int ks = 0; ks < 4; ++ks) {
#pragma unroll
    for (int f = 0; f < 8; ++f) {
      const int row = f * 16 + lr;
      const int sl = (ks * 4 + lg) ^ (row & 15);
      const bf16x8 aW = *(const bf16x8*)&sw1[row * 128 + (sl << 3)];
      accM[f] = MFMA16(aW, bG[ks], accM[f]);
    }
  }

  unsigned pm[8][2];
#pragma unroll
  for (int f = 0; f < 8; ++f) {
    float g[4];
#pragma unroll
    for (int r = 0; r < 4; ++r)
      g[r] = gelu_f(accM[f][r] + sb1[f * 16 + lg * 4 + r]);
    pm[f][0] = packbf(g[0], g[1]);
    pm[f][1] = packbf(g[2], g[3]);
  }

  f32x4 accH[2];
  accH[0] = (f32x4)0.f; accH[1] = (f32x4)0.f;
#pragma unroll
  for (int ks = 0; ks < 4; ++ks) {
    const int s0 = ((((lg << 1)) & 3) << 4) + lr;
    const int s1 = ((((lg << 1) + 1) & 3) << 4) + lr;
    const int sel = lg >> 1;
    const unsigned a0 = __shfl(pm[2 * ks][0], s0), b0 = __shfl(pm[2 * ks + 1][0], s0);
    const unsigned a1 = __shfl(pm[2 * ks][1], s0), b1v = __shfl(pm[2 * ks + 1][1], s0);
    const unsigned a2 = __shfl(pm[2 * ks][0], s1), b2v = __shfl(pm[2 * ks + 1][0], s1);
    const unsigned a3 = __shfl(pm[2 * ks][1], s1), b3v = __shfl(pm[2 * ks + 1][1], s1);
    u32x4 bw;
    bw.x = sel ? b0 : a0;
    bw.y = sel ? b1v : a1;
    bw.z = sel ? b2v : a2;
    bw.w = sel ? b3v : a3;
    const bf16x8 bMid = u4_to_bf8(bw);
#pragma unroll
    for (int hf = 0; hf < 2; ++hf) {
      const int row = hf * 16 + lr;
      const int sl = (ks * 4 + lg) ^ (row & 15);
      const bf16x8 aW2 = *(const bf16x8*)&sw2[row * 128 + (sl << 3)];
      accH[hf] = MFMA16(aW2, bMid, accH[hf]);
    }
  }

  const size_t obase = (((size_t)bB * H_) * N_ + iI) * N_ + j0 + el;
#pragma unroll
  for (int hf = 0; hf < 2; ++hf) {
#pragma unroll
    for (int r = 0; r < 4; ++r) {
      const int h = hf * 16 + lg * 4 + r;
      const unsigned short v = padq ? (unsigned short)0xFF80
                                    : f2bf(accH[hf][r] + sb2[h]);
      biasb[obase + (size_t)h * N_ * N_] = v;
    }
  }
}

// ---------------------------------------------------------------------------
// Kernel 3: node init
__global__ __launch_bounds__(256) void node_init_kernel(
    const int* __restrict__ atoms, const int* __restrict__ tags,
    const float* __restrict__ atom_emb, const float* __restrict__ tag_emb,
    const float* __restrict__ nsumw, const float* __restrict__ ep_w,
    const float* __restrict__ ep_b, float* __restrict__ hbuf)
{
  const int bi = blockIdx.x;
  const int tid = threadIdx.x;
  __shared__ float ns[K_];
  if (tid < K_) ns[tid] = nsumw[(size_t)bi * K_ + tid];
  __syncthreads();
  const int at = atoms[bi], tg = tags[bi];
  for (int d = tid; d < D_; d += 256) {
    float acc = tag_emb[tg * D_ + d] + atom_emb[at * D_ + d] + ep_b[d];
    const float* w = ep_w + (size_t)d * K_;
#pragma unroll 8
    for (int kk = 0; kk < K_; ++kk) acc = fmaf(ns[kk], w[kk], acc);
    hbuf[(size_t)bi * D_ + d] = acc;
  }
}

// ---------------------------------------------------------------------------
// LayerNorm -> bf16 out (used once, before layer 0)
__global__ __launch_bounds__(256) void ln_kernel(
    const float* __restrict__ x, const float* __restrict__ gg,
    const float* __restrict__ bb, unsigned short* __restrict__ y)
{
  const int bi = blockIdx.x;
  const int tid = threadIdx.x;
  __shared__ float sred[4];
  const float* row = x + (size_t)bi * D_;
  const float v0 = row[tid], v1 = row[tid + 256], v2 = row[tid + 512];
  float s = breduce_sum(v0 + v1 + v2, sred, tid);
  const float mean = s * (1.f / 768.f);
  const float d0 = v0 - mean, d1 = v1 - mean, d2 = v2 - mean;
  float q = breduce_sum(d0 * d0 + d1 * d1 + d2 * d2, sred, tid);
  const float inv = rsqrtf(q * (1.f / 768.f) + 1e-5f);
  unsigned short* out = y + (size_t)bi * D_;
  out[tid]       = f2bf(d0 * inv * gg[tid]       + bb[tid]);
  out[tid + 256] = f2bf(d1 * inv * gg[tid + 256] + bb[tid + 256]);
  out[tid + 512] = f2bf(d2 * inv * gg[tid + 512] + bb[tid + 512]);
}

// ---------------------------------------------------------------------------
// Split-K reduce + residual + bias + LayerNorm -> bf16 y (and updated hbuf).
template <int S>
__global__ __launch_bounds__(256) void reduce_ln_kernel(
    const float* __restrict__ P, const float* __restrict__ bias,
    float* __restrict__ hbuf, const float* __restrict__ gg,
    const float* __restrict__ bb, unsigned short* __restrict__ y)
{
  const int row = blockIdx.x;
  const int tid = threadIdx.x;
  __shared__ float sred[4];
  float h[3];
#pragma unroll
  for (int t = 0; t < 3; ++t) {
    const int c = tid + (t << 8);
    float s = bias[c];
#pragma unroll
    for (int z = 0; z < S; ++z)
      s += P[((size_t)z * (B_ * N_) + row) * 768 + c];
    const float hv = hbuf[(size_t)row * 768 + c] + s;
    hbuf[(size_t)row * 768 + c] = hv;
    h[t] = hv;
  }
  float sm = breduce_sum(h[0] + h[1] + h[2], sred, tid);
  const float mean = sm * (1.f / 768.f);
  const float d0 = h[0] - mean, d1 = h[1] - mean, d2 = h[2] - mean;
  float q = breduce_sum(d0 * d0 + d1 * d1 + d2 * d2, sred, tid);
  const float inv = rsqrtf(q * (1.f / 768.f) + 1e-5f);
  unsigned short* out = y + (size_t)row * 768;
  out[tid]       = f2bf(d0 * inv * gg[tid]       + bb[tid]);
  out[tid + 256] = f2bf(d1 * inv * gg[tid + 256] + bb[tid + 256]);
  out[tid + 512] = f2bf(d2 * inv * gg[tid + 512] + bb[tid + 512]);
}

// ---------------------------------------------------------------------------
// MFMA GEMM (16x16): A bf16 [M,lda], W bf16 [N,ldw], 64x64 tile, BK=64,
// 4 waves, double-buffered global_load_lds, drain-barrier loop.
// EPI: 0 bias; 1 gelu(bias+); 3 segment-bias (768-chunks, gelu on seg 3);
//      4 split-K raw partial (blockIdx.z selects K-slice, C offset z*M*N).
template <int EPI, int OB>
__global__ __launch_bounds__(256) void gemm_mfma(
    const unsigned short* __restrict__ A, const unsigned short* __restrict__ W,
    const float* __restrict__ bias, const float* __restrict__ bias2,
    const float* __restrict__ bias3, const float* __restrict__ bias4,
    float* __restrict__ C, unsigned short* __restrict__ Cb,
    int M, int N, int K, int lda, int ldw)
{
  if (EPI == 4) {
    const int z = blockIdx.z;
    A += (size_t)z * K;
    W += (size_t)z * K;
    C += (size_t)z * M * N;
  }
  __shared__ __align__(16) unsigned short sA[2][64 * 64];
  __shared__ __align__(16) unsigned short sB[2][64 * 64];
  const int tid = threadIdx.x;
  const int l = tid & 63;
  const int w = tid >> 6;
  const int m0 = blockIdx.y * 64;
  const int n0 = blockIdx.x * 64;
  const int wm = w >> 1, wn = w & 1;
  const int lr = l & 15;
  const int lg = l >> 4;
  const int r0 = (w << 4) + (l >> 3);
  const int s0 = (l & 7) ^ (r0 & 7);

  f32x4 acc[2][2];
#pragma unroll
  for (int mi = 0; mi < 2; ++mi)
#pragma unroll
    for (int ni = 0; ni < 2; ++ni) acc[mi][ni] = (f32x4)0.f;

  auto stage = [&](int buf, int t) {
    const size_t kb = (size_t)t << 6;
    unsigned short* lA = &sA[buf][(w << 4) << 6];
    unsigned short* lB = &sB[buf][(w << 4) << 6];
    gload_lds16(A + (size_t)(m0 + r0) * lda + kb + (s0 << 3), lA);
    gload_lds16(A + (size_t)(m0 + r0 + 8) * lda + kb + (s0 << 3), lA + 8 * 64);
    gload_lds16(W + (size_t)(n0 + r0) * ldw + kb + (s0 << 3), lB);
    gload_lds16(W + (size_t)(n0 + r0 + 8) * ldw + kb + (s0 << 3), lB + 8 * 64);
  };

  stage(0, 0);
  const int nt = K >> 6;
  for (int t = 0; t < nt; ++t) {
    __syncthreads();   // drains vmcnt: buf[t&1] staged; prev reads done
    if (t + 1 < nt) stage((t + 1) & 1, t + 1);
    const unsigned short* bA = sA[t & 1];
    const unsigned short* bBs = sB[t & 1];
    bf16x8 af[2][2], bfr[2][2];
#pragma unroll
    for (int mi = 0; mi < 2; ++mi) {
      const int row = (wm << 5) + (mi << 4) + lr;
#pragma unroll
      for (int kk = 0; kk < 2; ++kk) {
        const int sl = ((kk << 2) + lg) ^ (row & 7);
        af[mi][kk] = *(const bf16x8*)&bA[(row << 6) + (sl << 3)];
      }
    }
#pragma unroll
    for (int ni = 0; ni < 2; ++ni) {
      const int row = (wn << 5) + (ni << 4) + lr;
#pragma unroll
      for (int kk = 0; kk < 2; ++kk) {
        const int sl = ((kk << 2) + lg) ^ (row & 7);
        bfr[ni][kk] = *(const bf16x8*)&bBs[(row << 6) + (sl << 3)];
      }
    }
#pragma unroll
    for (int kk = 0; kk < 2; ++kk)
#pragma unroll
      for (int mi = 0; mi < 2; ++mi)
#pragma unroll
        for (int ni = 0; ni < 2; ++ni)
          acc[mi][ni] = MFMA16(af[mi][kk], bfr[ni][kk], acc[mi][ni]);
  }

#pragma unroll
  for (int mi = 0; mi < 2; ++mi)
#pragma unroll
    for (int ni = 0; ni < 2; ++ni) {
      const int n = n0 + (wn << 5) + (ni << 4) + lr;
      float bv = 0.f;
      int seg = 0;
      if (EPI == 3) {
        seg = n / 768;
        const float* bp = (seg == 0) ? bias : (seg == 1) ? bias2
                         : (seg == 2) ? bias3 : bias4;
        bv = bp[n - seg * 768];
      } else if (EPI != 4) {
        bv = bias[n];
      }
#pragma unroll
      for (int r = 0; r < 4; ++r) {
        const int m = m0 + (wm << 5) + (mi << 4) + lg * 4 + r;
        float v = acc[mi][ni][r] + bv;
        if (EPI == 1) v = gelu_f(v);
        if (EPI == 3 && seg == 3) v = gelu_f(v);
        if (OB) Cb[(size_t)m * N + n] = f2bf(v);
        else C[(size_t)m * N + n] = v;
      }
    }
}

// ---------------------------------------------------------------------------
// MFMA attention, bf16 Q/K/V inputs. grid = (B*H, 4), block = 256 (4 waves).
// PV path: unnormalized P in sP, per-lane invr[] applied to O (defer-norm).
// PROBS path additionally computes wv projections on strip 0 (fused wv).
template <bool PROBS>
__global__ __launch_bounds__(256) void attn_mfma_kernel(
    const unsigned short* __restrict__ Q, const unsigned short* __restrict__ Kp,
    const unsigned short* __restrict__ Vp, const int stride,
    const unsigned short* __restrict__ biasb, unsigned short* __restrict__ obuf,
    unsigned short* __restrict__ aprob,
    const float* __restrict__ f1w, const float* __restrict__ f2w,
    const float* __restrict__ f3w, float* __restrict__ wv)
{
  __shared__ __align__(16) unsigned short sK[256 * 40];   // [j][d pad40]
  __shared__ __align__(16) unsigned short sVt[32 * 264];  // [d][j pad264]
  __shared__ __align__(16) unsigned short sP[64 * 264];   // [i_loc][j pad264]
  const int tid = threadIdx.x;
  const int l = tid & 63, w = tid >> 6;
  const int bh = blockIdx.x, b = bh >> 5, hh = bh & 31;
  const int i0 = blockIdx.y * 64;
  const int lr = l & 15, lg = l >> 4;

#pragma unroll
  for (int it = 0; it < 3; ++it) {
    const int c = tid + (it << 8);        // < 768
    const int row = c / 3, part = c - row * 3;
    *(u16x8*)&sK[row * 40 + part * 8] =
        *(const u16x8*)&Kp[(size_t)(b * N_ + row) * stride + hh * HD_ + part * 8];
  }
  {
    u16x8 z = {0, 0, 0, 0, 0, 0, 0, 0};
    *(u16x8*)&sK[tid * 40 + 24] = z;
  }
  if (!PROBS) {
    const int j = tid;
    const unsigned short* vr = &Vp[(size_t)(b * N_ + j) * stride + hh * HD_];
    const u16x8 v0 = *(const u16x8*)vr;
    const u16x8 v1 = *(const u16x8*)(vr + 8);
    const u16x8 v2 = *(const u16x8*)(vr + 16);
#pragma unroll
    for (int d = 0; d < 8; ++d) {
      sVt[d * 264 + j] = v0[d];
      sVt[(8 + d) * 264 + j] = v1[d];
      sVt[(16 + d) * 264 + j] = v2[d];
    }
  }
  bf16x8 aQ;
  if (lg < 3) {
    const u16x8 q = *(const u16x8*)&Q[(size_t)(b * N_ + i0 + (w << 4) + lr) * stride + hh * HD_ + lg * 8];
    union { u16x8 a; bf16x8 b; } u; u.a = q;
    aQ = u.b;
  } else {
    bf16x8 t = {0, 0, 0, 0, 0, 0, 0, 0};
    aQ = t;
  }
  __syncthreads();

  f32x4 acc[16];
#pragma unroll
  for (int ni = 0; ni < 16; ++ni) {
    const bf16x8 bK = *(const bf16x8*)&sK[(ni * 16 + lr) * 40 + lg * 8];
    acc[ni] = MFMA16(aQ, bK, (f32x4)0.f);
  }

  float invr[4];
#pragma unroll
  for (int r = 0; r < 4; ++r) {
    const int iloc = (w << 4) + lg * 4 + r;
    const unsigned short* bp =
        &biasb[(((size_t)(b * H_ + hh)) * N_ + i0 + iloc) * N_ + lr];
    float mx = -INFINITY;
#pragma unroll
    for (int ni = 0; ni < 16; ++ni) {
      const float s = acc[ni][r] * SCALE_ + bf2f(bp[ni * 16]);
      acc[ni][r] = s;
      mx = fmaxf(mx, s);
    }
    mx = fmaxf(mx, __shfl_xor(mx, 1));
    mx = fmaxf(mx, __shfl_xor(mx, 2));
    mx = fmaxf(mx, __shfl_xor(mx, 4));
    mx = fmaxf(mx, __shfl_xor(mx, 8));
    float sum = 0.f;
#pragma unroll
    for (int ni = 0; ni < 16; ++ni) {
      const float e = __expf(acc[ni][r] - mx);
      acc[ni][r] = e;
      sum += e;
    }
    sum += __shfl_xor(sum, 1);
    sum += __shfl_xor(sum, 2);
    sum += __shfl_xor(sum, 4);
    sum += __shfl_xor(sum, 8);
    const float inv = 1.f / sum;
    invr[r] = inv;
#pragma unroll
    for (int ni = 0; ni < 16; ++ni)
      sP[iloc * 264 + ni * 16 + lr] = f2bf(PROBS ? acc[ni][r] * inv
                                                 : acc[ni][r]);
  }
  __syncthreads();

  if (PROBS) {
#pragma unroll
    for (int it = 0; it < 8; ++it) {
      const int idx = tid + it * 256;     // < 2048
      const int row = idx >> 5, c = idx & 31;
      *(u16x8*)&aprob[(((size_t)(b * H_ + hh)) * N_ + i0 + row) * N_ + c * 8] =
          *(const u16x8*)&sP[row * 264 + c * 8];
    }
    // fused wv (strip 0 only): wv[c][b,hh,j] = sum_d V[b,j,hh,d]*fcw[hh*HD+d]
    if (blockIdx.y == 0) {
      const int j = tid;
      const unsigned short* vr = &Vp[(size_t)(b * N_ + j) * stride + hh * HD_];
      const u16x8 v0 = *(const u16x8*)vr;
      const u16x8 v1 = *(const u16x8*)(vr + 8);
      const u16x8 v2 = *(const u16x8*)(vr + 16);
      float s0 = 0.f, s1 = 0.f, s2 = 0.f;
#pragma unroll
      for (int d = 0; d < 8; ++d) {
        const float e0 = bf2f(v0[d]), e1 = bf2f(v1[d]), e2 = bf2f(v2[d]);
        s0 = fmaf(e0, f1w[hh * HD_ + d], s0);
        s0 = fmaf(e1, f1w[hh * HD_ + 8 + d], s0);
        s0 = fmaf(e2, f1w[hh * HD_ + 16 + d], s0);
        s1 = fmaf(e0, f2w[hh * HD_ + d], s1);
        s1 = fmaf(e1, f2w[hh * HD_ + 8 + d], s1);
        s1 = fmaf(e2, f2w[hh * HD_ + 16 + d], s1);
        s2 = fmaf(e0, f3w[hh * HD_ + d], s2);
        s2 = fmaf(e1, f3w[hh * HD_ + 8 + d], s2);
        s2 = fmaf(e2, f3w[hh * HD_ + 16 + d], s2);
      }
      wv[((size_t)(0 * B_ + b) * H_ + hh) * N_ + j] = s0;
      wv[((size_t)(1 * B_ + b) * H_ + hh) * N_ + j] = s1;
      wv[((size_t)(2 * B_ + b) * H_ + hh) * N_ + j] = s2;
    }
  } else {
    f32x4 accO[2];
    accO[0] = (f32x4)0.f; accO[1] = (f32x4)0.f;
#pragma unroll
    for (int ks = 0; ks < 8; ++ks) {
      const bf16x8 aP = *(const bf16x8*)&sP[((w << 4) + lr) * 264 + ks * 32 + lg * 8];
      const bf16x8 bV0 = *(const bf16x8*)&sVt[lr * 264 + ks * 32 + lg * 8];
      const bf16x8 bV1 = *(const bf16x8*)&sVt[(16 + lr) * 264 + ks * 32 + lg * 8];
      accO[0] = MFMA16(aP, bV0, accO[0]);
      accO[1] = MFMA16(aP, bV1, accO[1]);
    }
#pragma unroll
    for (int ni = 0; ni < 2; ++ni) {
      const int n = ni * 16 + lr;
      if (n < HD_) {
#pragma unroll
        for (int r = 0; r < 4; ++r) {
          const int i = i0 + (w << 4) + lg * 4 + r;
          obuf[(size_t)(b * N_ + i) * D_ + hh * HD_ + n] = f2bf(accO[ni][r] * invr[r]);
        }
      }
    }
  }
}

// ---------------------------------------------------------------------------
// Energy head (t1 bf16, rows strided)
__global__ __launch_bounds__(256) void engnode_kernel(
    const unsigned short* __restrict__ t1, const int stride,
    const float* __restrict__ en_w2, const float* __restrict__ en_b2,
    const float* __restrict__ eagg, const int* __restrict__ tags,
    float* __restrict__ engpn)
{
  const int bi = blockIdx.x;
  const int tid = threadIdx.x;
  __shared__ float sred[4];
  const unsigned short* row = t1 + (size_t)bi * stride;
  float acc = bf2f(row[tid]) * en_w2[tid] + bf2f(row[tid + 256]) * en_w2[tid + 256] +
              bf2f(row[tid + 512]) * en_w2[tid + 512];
  acc = breduce_sum(acc, sred, tid);
  if (tid == 0) {
    const int tg = tags[bi];
    engpn[bi] = (tg > 0) ? (acc + en_b2[0]) * eagg[tg] : 0.f;
  }
}

// engsum (blocks 0..3) + omask (blocks 4..7) merged
__global__ __launch_bounds__(256) void engsum_omask_kernel(
    const float* __restrict__ engpn, const int* __restrict__ tags,
    float* __restrict__ out)
{
  const int bid = blockIdx.x;
  const int tid = threadIdx.x;
  if (bid < 4) {
    __shared__ float sred[4];
    float v = breduce_sum(engpn[bid * N_ + tid], sred, tid);
    if (tid == 0) out[bid] = v;
  } else {
    const int idx = (bid - 4) * 256 + tid;
    out[4 + B_ * N_ * 3 + idx] = (tags[idx] > 0) ? 1.f : 0.f;
  }
}

// merged-c nodeout: grid = BN
__global__ __launch_bounds__(256) void nodeout_kernel(
    const unsigned short* __restrict__ aprob, const float* __restrict__ wv,
    const float* __restrict__ deltaw, const float* __restrict__ f1b,
    const float* __restrict__ f2b, const float* __restrict__ f3b,
    float* __restrict__ out)
{
  const int bi = blockIdx.x;
  const int tid = threadIdx.x;
  const int b = bi >> 8;
  const int i = bi & 255;
  __shared__ float sred[4];
  const unsigned short* ap = aprob + (((size_t)b * H_) * N_ + i) * N_ + tid;
  const float* wv0 = wv + ((size_t)(0 * B_ + b) * H_) * N_ + tid;
  const float* wv1 = wv + ((size_t)(1 * B_ + b) * H_) * N_ + tid;
  const float* wv2 = wv + ((size_t)(2 * B_ + b) * H_) * N_ + tid;
  float s0 = 0.f, s1 = 0.f, s2 = 0.f;
  for (int hh = 0; hh < H_; ++hh) {
    const float p = bf2f(ap[(size_t)hh * N_ * N_]);
    s0 = fmaf(p, wv0[(size_t)hh * N_], s0);
    s1 = fmaf(p, wv1[(size_t)hh * N_], s1);
    s2 = fmaf(p, wv2[(size_t)hh * N_], s2);
  }
  const float* dl = &deltaw[((size_t)bi * N_ + tid) * 3];
  s0 *= dl[0];
  s1 *= dl[1];
  s2 *= dl[2];
  s0 = breduce_sum(s0, sred, tid);
  s1 = breduce_sum(s1, sred, tid);
  s2 = breduce_sum(s2, sred, tid);
  if (tid == 0) {
    out[4 + bi * 3 + 0] = s0 + f1b[0];
    out[4 + bi * 3 + 1] = s1 + f2b[0];
    out[4 + bi * 3 + 2] = s2 + f3b[0];
  }
}

// ---------------------------------------------------------------------------
extern "C" void kernel_launch(void* const* d_in, const int* in_sizes, int n_in,
                              void* d_out, int out_size, void* d_ws, size_t ws_size,
                              hipStream_t stream) {
  (void)in_sizes; (void)n_in; (void)out_size; (void)ws_size;
  const int*   atoms     = (const int*)  d_in[0];
  const int*   tags      = (const int*)  d_in[1];
  const float* pos       = (const float*)d_in[2];
  const float* atom_emb  = (const float*)d_in[4];
  const float* tag_emb   = (const float*)d_in[5];
  const float* gbf_means = (const float*)d_in[6];
  const float* gbf_stds  = (const float*)d_in[7];
  const float* gbf_mul   = (const float*)d_in[8];
  const float* gbf_bias  = (const float*)d_in[9];
  const float* bp_w1     = (const float*)d_in[10];
  const float* bp_b1     = (const float*)d_in[11];
  const float* bp_w2     = (const float*)d_in[12];
  const float* bp_b2     = (const float*)d_in[13];
  const float* ep_w      = (const float*)d_in[14];
  const float* ep_b      = (const float*)d_in[15];
  const float* ln1_g     = (const float*)d_in[16];
  const float* ln1_b     = (const float*)d_in[17];
  const float* wqkv      = (const float*)d_in[18];
  const float* bqkv      = (const float*)d_in[19];
  const float* wo        = (const float*)d_in[20];
  const float* bo        = (const float*)d_in[21];
  const float* ln2_g     = (const float*)d_in[22];
  const float* ln2_b     = (const float*)d_in[23];
  const float* w1        = (const float*)d_in[24];
  const float* b1        = (const float*)d_in[25];
  const float* w2        = (const float*)d_in[26];
  const float* b2        = (const float*)d_in[27];
  const float* fln_g     = (const float*)d_in[28];
  const float* fln_b     = (const float*)d_in[29];
  const float* en_w1     = (const float*)d_in[30];
  const float* en_b1     = (const float*)d_in[31];
  const float* en_w2     = (const float*)d_in[32];
  const float* en_b2     = (const float*)d_in[33];
  const float* eagg      = (const float*)d_in[34];
  const float* nq_w      = (const float*)d_in[35];
  const float* nq_b      = (const float*)d_in[36];
  const float* nk_w      = (const float*)d_in[37];
  const float* nk_b      = (const float*)d_in[38];
  const float* nv_w      = (const float*)d_in[39];
  const float* nv_b      = (const float*)d_in[40];
  const float* f1_w      = (const float*)d_in[41];
  const float* f1_b      = (const float*)d_in[42];
  const float* f2_w      = (const float*)d_in[43];
  const float* f2_b      = (const float*)d_in[44];
  const float* f3_w      = (const float*)d_in[45];
  const float* f3_b      = (const float*)d_in[46];

  char* wsB = (char*)d_ws;
  size_t off = 0;
  auto alloc = [&](size_t bytes) {
    void* p = wsB + off;
    off = (off + bytes + 255) & ~(size_t)255;
    return p;
  };
  unsigned short* biasb   = (unsigned short*)alloc((size_t)B_ * H_ * N_ * N_ * 2);
  unsigned short* aprobb  = (unsigned short*)alloc((size_t)B_ * H_ * N_ * N_ * 2);
  float*          deltaw  = (float*)alloc((size_t)B_ * N_ * N_ * 3 * 4);
  float*          xvalw   = (float*)alloc((size_t)B_ * N_ * N_ * 4);
  float*          nsumw   = (float*)alloc((size_t)B_ * N_ * K_ * 4);
  float*          hbuf    = (float*)alloc((size_t)B_ * N_ * D_ * 4);
  unsigned short* qkvb    = (unsigned short*)alloc((size_t)B_ * N_ * 3 * D_ * 2);
  unsigned short* qn4b    = (unsigned short*)alloc((size_t)B_ * N_ * 3072 * 2);
  unsigned short* ybf     = (unsigned short*)alloc((size_t)B_ * N_ * D_ * 2);
  unsigned short* obf     = (unsigned short*)alloc((size_t)B_ * N_ * D_ * 2);
  unsigned short* midbf   = (unsigned short*)alloc((size_t)B_ * N_ * F_ * 2);
  unsigned short* outbf   = (unsigned short*)alloc((size_t)B_ * N_ * D_ * 2);
  unsigned short* arena   = (unsigned short*)alloc((size_t)7077888 * 2);
  unsigned short* headsb  = (unsigned short*)alloc((size_t)2359296 * 2);
  unsigned short* bw1b    = (unsigned short*)alloc((size_t)K_ * K_ * 2);
  unsigned short* bw2b    = (unsigned short*)alloc((size_t)H_ * K_ * 2);
  float*          wopart  = (float*)alloc((size_t)2 * B_ * N_ * D_ * 4);
  float*          ffpart  = (float*)alloc((size_t)4 * B_ * N_ * D_ * 4);
  float*          wvb     = (float*)alloc((size_t)3 * B_ * H_ * N_ * 4);
  float*          engpn   = (float*)alloc((size_t)B_ * N_ * 4);

  const int BN = B_ * N_;  // 1024
  float* outp = (float*)d_out;
  const size_t OQKV = 0, OWO = 1769472, OW1 = 2359296, OW2 = 4718592;

  edge_pre_kernel<<<BN, 256, 0, stream>>>(atoms, pos, gbf_mul, gbf_bias,
                                          gbf_means, gbf_stds, deltaw, xvalw, nsumw);
  cast_bias_kernel<<<20, 256, 0, stream>>>(bp_w1, bp_w2, bw1b, bw2b);
  bias_mfma_kernel<<<B_ * N_ * N_ / 64, 256, 0, stream>>>(
      xvalw, atoms, gbf_means, gbf_stds, bw1b, bp_b1, bw2b, bp_b2, biasb);
  node_init_kernel<<<BN, 256, 0, stream>>>(atoms, tags, atom_emb, tag_emb,
                                           nsumw, ep_w, ep_b, hbuf);
  ln_kernel<<<BN, 256, 0, stream>>>(hbuf, ln1_g, ln1_b, ybf);

  for (int l = 0; l < L_; ++l) {
    castlayer_kernel<<<3456, 256, 0, stream>>>(
        wqkv + (size_t)l * 3 * D_ * D_, wo + (size_t)l * D_ * D_,
        w1 + (size_t)l * F_ * D_, w2 + (size_t)l * D_ * F_, arena);
    // QKV: [1024,2304] bf16
    gemm_mfma<0, 1><<<dim3(36, 16), 256, 0, stream>>>(
        ybf, arena + OQKV, bqkv + (size_t)l * 3 * D_, nullptr, nullptr, nullptr,
        nullptr, qkvb, BN, 3 * D_, D_, D_, D_);
    attn_mfma_kernel<false><<<dim3(B_ * H_, 4), 256, 0, stream>>>(
        qkvb, qkvb + D_, qkvb + 2 * D_, 3 * D_, biasb, obf, nullptr,
        nullptr, nullptr, nullptr, nullptr);
    // wo: split-K=2 partials, then reduce + res + ln2 -> ybf
    gemm_mfma<4, 0><<<dim3(12, 16, 2), 256, 0, stream>>>(
        obf, arena + OWO, nullptr, nullptr, nullptr, nullptr,
        wopart, nullptr, BN, D_, 384, D_, D_);
    reduce_ln_kernel<2><<<BN, 256, 0, stream>>>(
        wopart, bo + (size_t)l * D_, hbuf, ln2_g + (size_t)l * D_,
        ln2_b + (size_t)l * D_, ybf);
    // FFN1: gelu -> midbf bf16
    gemm_mfma<1, 1><<<dim3(48, 16), 256, 0, stream>>>(
        ybf, arena + OW1, b1 + (size_t)l * F_, nullptr, nullptr, nullptr,
        nullptr, midbf, BN, F_, D_, D_, D_);
    // FFN2: split-K=4 partials, then reduce + res + ln1(l+1) (or fln) -> y
    gemm_mfma<4, 0><<<dim3(12, 16, 4), 256, 0, stream>>>(
        midbf, arena + OW2, nullptr, nullptr, nullptr, nullptr,
        ffpart, nullptr, BN, D_, 768, F_, F_);
    const bool last = (l == L_ - 1);
    reduce_ln_kernel<4><<<BN, 256, 0, stream>>>(
        ffpart, b2 + (size_t)l * D_, hbuf,
        last ? fln_g : ln1_g + (size_t)(l + 1) * D_,
        last ? fln_b : ln1_b + (size_t)(l + 1) * D_,
        last ? outbf : ybf);
  }

  // head weights -> headsb: [nq | nk | nv | en_w1], 3072 rows of K=768
  castheads_kernel<<<1152, 256, 0, stream>>>(nq_w, nk_w, nv_w, en_w1, headsb);

  // merged head GEMM: N = 3072 (q|k|v|t1), gelu on the en segment, bf16 out
  gemm_mfma<3, 1><<<dim3(48, 16), 256, 0, stream>>>(
      outbf, headsb, nq_b, nk_b, nv_b, en_b1,
      nullptr, qn4b, BN, 3072, D_, D_, D_);

  attn_mfma_kernel<true><<<dim3(B_ * H_, 4), 256, 0, stream>>>(
      qn4b, qn4b + 768, qn4b + 1536, 3072, biasb, nullptr, aprobb,
      f1_w, f2_w, f3_w, wvb);
  nodeout_kernel<<<BN, 256, 0, stream>>>(aprobb, wvb, deltaw,
                                         f1_b, f2_b, f3_b, outp);

  engnode_kernel<<<BN, 256, 0, stream>>>(qn4b + 2304, 3072, en_w2, en_b2,
                                         eagg, tags, engpn);
  engsum_omask_kernel<<<8, 256, 0, stream>>>(engpn, tags, outp);
}

// Round 13
// 987.615 us; speedup vs baseline: 1.0539x; 1.0276x over previous
//
#include <hip/hip_runtime.h>
#include <math.h>

// Graphormer3D forward — round 12: R11 (best 1015us) + weight-casts folded
// into reduce_ln dispatches (double-buffered arena, 12 fewer dispatches).
// B=4 N=256 D=768 H=32 HD=24 L=12 F=3072 K=128
constexpr int B_ = 4, N_ = 256, D_ = 768, H_ = 32, HD_ = 24, L_ = 12, F_ = 3072, K_ = 128;
constexpr float SCALE_ = 0.20412414523193150f;   // HD^-0.5
constexpr float ISQRT2_ = 0.70710678118654752f;

typedef short bf16x8 __attribute__((ext_vector_type(8)));
typedef float f32x4 __attribute__((ext_vector_type(4)));
typedef unsigned short u16x4 __attribute__((ext_vector_type(4)));
typedef unsigned short u16x8 __attribute__((ext_vector_type(8)));
typedef unsigned int u32x4 __attribute__((ext_vector_type(4)));

#define DEV __device__ __forceinline__
#define MFMA16(a, b, c) __builtin_amdgcn_mfma_f32_16x16x32_bf16(a, b, c, 0, 0, 0)

DEV void gload_lds16(const unsigned short* g, unsigned short* l) {
  __builtin_amdgcn_global_load_lds(
      (const __attribute__((address_space(1))) unsigned int*)(g),
      (__attribute__((address_space(3))) unsigned int*)(l), 16, 0, 0);
}

DEV float gelu_f(float x) { return 0.5f * x * (1.0f + erff(x * ISQRT2_)); }

DEV unsigned short f2bf(float f) {  // RNE f32 -> bf16
  unsigned u = __float_as_uint(f);
  return (unsigned short)((u + 0x7FFFu + ((u >> 16) & 1u)) >> 16);
}
DEV float bf2f(unsigned short u) { return __uint_as_float(((unsigned)u) << 16); }
DEV unsigned packbf(float a, float b) {
  return (unsigned)f2bf(a) | ((unsigned)f2bf(b) << 16);
}
DEV bf16x8 u4_to_bf8(u32x4 x) { union { u32x4 a; bf16x8 b; } u; u.a = x; return u.b; }

// deterministic block(256) reductions
DEV float breduce_sum(float v, float* sred, int tid) {
#pragma unroll
  for (int o = 32; o > 0; o >>= 1) v += __shfl_xor(v, o);
  if ((tid & 63) == 0) sred[tid >> 6] = v;
  __syncthreads();
  v = (sred[0] + sred[1]) + (sred[2] + sred[3]);
  __syncthreads();
  return v;
}

// ---------------------------------------------------------------------------
// bias-MLP weights (bp_w1 4096 float4 | bp_w2 1024 float4) -> bf16, 1 dispatch
__global__ __launch_bounds__(256) void cast_bias_kernel(
    const float* __restrict__ w1f, const float* __restrict__ w2f,
    unsigned short* __restrict__ d1, unsigned short* __restrict__ d2) {
  const int i = blockIdx.x * 256 + threadIdx.x;  // < 5120
  const float* s;
  unsigned short* d;
  int j;
  if (i < 4096) { s = w1f; d = d1; j = i; }
  else { s = w2f; d = d2; j = i - 4096; }
  const float4 v = ((const float4*)s)[j];
  u16x4 o = {f2bf(v.x), f2bf(v.y), f2bf(v.z), f2bf(v.w)};
  ((u16x4*)d)[j] = o;
}

// per-layer weights -> arena half (qkv | wo | w1 | w2); 884736 u16x8 units
__global__ __launch_bounds__(256) void castlayer_kernel(
    const float* __restrict__ wqkv, const float* __restrict__ wo,
    const float* __restrict__ w1, const float* __restrict__ w2,
    unsigned short* __restrict__ arena) {
  const unsigned i = blockIdx.x * 256 + threadIdx.x;  // u16x8 unit
  const float* s; unsigned j;
  if (i < 221184u) { s = wqkv; j = i; }
  else if (i < 294912u) { s = wo; j = i - 221184u; }
  else if (i < 589824u) { s = w1; j = i - 294912u; }
  else { s = w2; j = i - 589824u; }
  const float4 a = ((const float4*)s)[2u * j];
  const float4 b = ((const float4*)s)[2u * j + 1u];
  u16x8 o = {f2bf(a.x), f2bf(a.y), f2bf(a.z), f2bf(a.w),
             f2bf(b.x), f2bf(b.y), f2bf(b.z), f2bf(b.w)};
  ((u16x8*)arena)[i] = o;
}

// ---------------------------------------------------------------------------
// Kernel 1: per-(b,i) edge precompute (f32)
__global__ __launch_bounds__(256) void edge_pre_kernel(
    const int* __restrict__ atoms, const float* __restrict__ pos,
    const float* __restrict__ gbf_mul, const float* __restrict__ gbf_bias,
    const float* __restrict__ gbf_means, const float* __restrict__ gbf_stds,
    float* __restrict__ deltaw, float* __restrict__ xvalw, float* __restrict__ nsumw)
{
  const int tid = threadIdx.x;
  const int bi = blockIdx.x;
  const int b = bi >> 8;
  __shared__ float spos[3];
  __shared__ float sxv[256];
  __shared__ int   spad[256];
  __shared__ float red[256];
  if (tid < 3) spos[tid] = pos[(size_t)bi * 3 + tid];
  __syncthreads();
  {
    const int j = tid;
    const float px = pos[(size_t)(b * N_ + j) * 3 + 0];
    const float py = pos[(size_t)(b * N_ + j) * 3 + 1];
    const float pz = pos[(size_t)(b * N_ + j) * 3 + 2];
    const float dx = px - spos[0], dy = py - spos[1], dz = pz - spos[2];
    const float sq = dx * dx + dy * dy + dz * dz;
    const float dist = sqrtf(fmaxf(sq, 1e-24f));
    const float inv = 1.f / (dist + 1e-5f);
    const size_t e = (size_t)bi * N_ + j;
    deltaw[e * 3 + 0] = dx * inv;
    deltaw[e * 3 + 1] = dy * inv;
    deltaw[e * 3 + 2] = dz * inv;
    const int et = atoms[bi] * 64 + atoms[b * N_ + j];
    const float xv = gbf_mul[et] * dist + gbf_bias[et];
    xvalw[e] = xv;
    sxv[j] = xv;
    spad[j] = (atoms[b * N_ + j] == 0);
  }
  __syncthreads();
  const int k = tid & 127;
  const float mean = gbf_means[k];
  const float st = fabsf(gbf_stds[k]) + 1e-5f;
  const float istd = 1.f / st;
  const float coef = 0.39894228040143268f * istd;
  float acc = 0.f;
  const int jbase = tid >> 7;
  for (int t = 0; t < 128; ++t) {
    const int j = jbase + (t << 1);
    if (!spad[j]) {
      const float z = (sxv[j] - mean) * istd;
      acc += __expf(-0.5f * z * z) * coef;
    }
  }
  red[tid] = acc;
  __syncthreads();
  if (tid < 128) nsumw[(size_t)bi * K_ + tid] = red[tid] + red[tid + 128];
}

// ---------------------------------------------------------------------------
// Kernel 2 (MFMA, register datapath): bias MLP per 64-edge tile.
__global__ __launch_bounds__(256) void bias_mfma_kernel(
    const float* __restrict__ xvalw, const int* __restrict__ atoms,
    const float* __restrict__ gbf_means, const float* __restrict__ gbf_stds,
    const unsigned short* __restrict__ w1b, const float* __restrict__ b1,
    const unsigned short* __restrict__ w2b, const float* __restrict__ b2,
    unsigned short* __restrict__ biasb)
{
  __shared__ __align__(16) unsigned short sw1[128 * 128];  // 32 KB, swizzled
  __shared__ __align__(16) unsigned short sw2[32 * 128];   // 8 KB, swizzled
  __shared__ float smean[128], sistd[128], scoef[128], sb1[128], sb2[32];
  const int tid = threadIdx.x;
  const int l = tid & 63;
  const int w = tid >> 6;
  const size_t e0 = (size_t)blockIdx.x * 64;
  const int bB = (int)(e0 >> 16);
  const int iI = (int)((e0 >> 8) & 255);
  const int j0 = (int)(e0 & 255);
  const int lr = l & 15;
  const int lg = l >> 4;

  {
    const int rin = l >> 4;
    const int slot = l & 15;
#pragma unroll
    for (int q = 0; q < 8; ++q) {
      const int rbase = w * 32 + q * 4;
      const int row = rbase + rin;
      const int gs = slot ^ (row & 15);
      gload_lds16(w1b + row * 128 + gs * 8, &sw1[rbase * 128]);
    }
#pragma unroll
    for (int q = 0; q < 2; ++q) {
      const int rbase = w * 8 + q * 4;
      const int row = rbase + rin;
      const int gs = slot ^ (row & 15);
      gload_lds16(w2b + row * 128 + gs * 8, &sw2[rbase * 128]);
    }
  }
  if (tid < 128) {
    const float st = fabsf(gbf_stds[tid]) + 1e-5f;
    const float is = 1.f / st;
    smean[tid] = gbf_means[tid];
    sistd[tid] = is;
    scoef[tid] = 0.39894228040143268f * is;
    sb1[tid] = b1[tid];
  } else if (tid < 160) {
    sb2[tid - 128] = b2[tid - 128];
  }
  const int el = w * 16 + lr;
  const float xv = xvalw[e0 + el];
  const bool padq = (atoms[bB * N_ + j0 + el] == 0);
  __syncthreads();

  bf16x8 bG[4];
#pragma unroll
  for (int ks = 0; ks < 4; ++ks) {
    u16x8 t;
#pragma unroll
    for (int j = 0; j < 8; ++j) {
      const int k = ks * 32 + lg * 8 + j;
      const float z = (xv - smean[k]) * sistd[k];
      t[j] = f2bf(__expf(-0.5f * z * z) * scoef[k]);
    }
    union { u16x8 a; bf16x8 b; } u; u.a = t;
    bG[ks] = u.b;
  }

  f32x4 accM[8];
#pragma unroll
  for (int f = 0; f < 8; ++f) accM[f] = (f32x4)0.f;
#pragma unroll
  for (int ks = 0; ks < 4; ++ks) {
#pragma unroll
    for (int f = 0; f < 8; ++f) {
      const int row = f * 16 + lr;
      const int sl = (ks * 4 + lg) ^ (row & 15);
      const bf16x8 aW = *(const bf16x8*)&sw1[row * 128 + (sl << 3)];
      accM[f] = MFMA16(aW, bG[ks], accM[f]);
    }
  }

  unsigned pm[8][2];
#pragma unroll
  for (int f = 0; f < 8; ++f) {
    float g[4];
#pragma unroll
    for (int r = 0; r < 4; ++r)
      g[r] = gelu_f(accM[f][r] + sb1[f * 16 + lg * 4 + r]);
    pm[f][0] = packbf(g[0], g[1]);
    pm[f][1] = packbf(g[2], g[3]);
  }

  f32x4 accH[2];
  accH[0] = (f32x4)0.f; accH[1] = (f32x4)0.f;
#pragma unroll
  for (int ks = 0; ks < 4; ++ks) {
    const int s0 = ((((lg << 1)) & 3) << 4) + lr;
    const int s1 = ((((lg << 1) + 1) & 3) << 4) + lr;
    const int sel = lg >> 1;
    const unsigned a0 = __shfl(pm[2 * ks][0], s0), b0 = __shfl(pm[2 * ks + 1][0], s0);
    const unsigned a1 = __shfl(pm[2 * ks][1], s0), b1v = __shfl(pm[2 * ks + 1][1], s0);
    const unsigned a2 = __shfl(pm[2 * ks][0], s1), b2v = __shfl(pm[2 * ks + 1][0], s1);
    const unsigned a3 = __shfl(pm[2 * ks][1], s1), b3v = __shfl(pm[2 * ks + 1][1], s1);
    u32x4 bw;
    bw.x = sel ? b0 : a0;
    bw.y = sel ? b1v : a1;
    bw.z = sel ? b2v : a2;
    bw.w = sel ? b3v : a3;
    const bf16x8 bMid = u4_to_bf8(bw);
#pragma unroll
    for (int hf = 0; hf < 2; ++hf) {
      const int row = hf * 16 + lr;
      const int sl = (ks * 4 + lg) ^ (row & 15);
      const bf16x8 aW2 = *(const bf16x8*)&sw2[row * 128 + (sl << 3)];
      accH[hf] = MFMA16(aW2, bMid, accH[hf]);
    }
  }

  const size_t obase = (((size_t)bB * H_) * N_ + iI) * N_ + j0 + el;
#pragma unroll
  for (int hf = 0; hf < 2; ++hf) {
#pragma unroll
    for (int r = 0; r < 4; ++r) {
      const int h = hf * 16 + lg * 4 + r;
      const unsigned short v = padq ? (unsigned short)0xFF80
                                    : f2bf(accH[hf][r] + sb2[h]);
      biasb[obase + (size_t)h * N_ * N_] = v;
    }
  }
}

// ---------------------------------------------------------------------------
// Kernel 3: node init
__global__ __launch_bounds__(256) void node_init_kernel(
    const int* __restrict__ atoms, const int* __restrict__ tags,
    const float* __restrict__ atom_emb, const float* __restrict__ tag_emb,
    const float* __restrict__ nsumw, const float* __restrict__ ep_w,
    const float* __restrict__ ep_b, float* __restrict__ hbuf)
{
  const int bi = blockIdx.x;
  const int tid = threadIdx.x;
  __shared__ float ns[K_];
  if (tid < K_) ns[tid] = nsumw[(size_t)bi * K_ + tid];
  __syncthreads();
  const int at = atoms[bi], tg = tags[bi];
  for (int d = tid; d < D_; d += 256) {
    float acc = tag_emb[tg * D_ + d] + atom_emb[at * D_ + d] + ep_b[d];
    const float* w = ep_w + (size_t)d * K_;
#pragma unroll 8
    for (int kk = 0; kk < K_; ++kk) acc = fmaf(ns[kk], w[kk], acc);
    hbuf[(size_t)bi * D_ + d] = acc;
  }
}

// ---------------------------------------------------------------------------
// LayerNorm -> bf16 out (used once, before layer 0)
__global__ __launch_bounds__(256) void ln_kernel(
    const float* __restrict__ x, const float* __restrict__ gg,
    const float* __restrict__ bb, unsigned short* __restrict__ y)
{
  const int bi = blockIdx.x;
  const int tid = threadIdx.x;
  __shared__ float sred[4];
  const float* row = x + (size_t)bi * D_;
  const float v0 = row[tid], v1 = row[tid + 256], v2 = row[tid + 512];
  float s = breduce_sum(v0 + v1 + v2, sred, tid);
  const float mean = s * (1.f / 768.f);
  const float d0 = v0 - mean, d1 = v1 - mean, d2 = v2 - mean;
  float q = breduce_sum(d0 * d0 + d1 * d1 + d2 * d2, sred, tid);
  const float inv = rsqrtf(q * (1.f / 768.f) + 1e-5f);
  unsigned short* out = y + (size_t)bi * D_;
  out[tid]       = f2bf(d0 * inv * gg[tid]       + bb[tid]);
  out[tid + 256] = f2bf(d1 * inv * gg[tid + 256] + bb[tid + 256]);
  out[tid + 512] = f2bf(d2 * inv * gg[tid + 512] + bb[tid + 512]);
}

// ---------------------------------------------------------------------------
// Split-K reduce + residual + bias + LayerNorm -> bf16 y (and updated hbuf),
// with optional piggy-backed weight cast on extra blocks:
//   mode 0: none; mode 1: cast next layer (c0..c3 -> cdst, 3456 blocks);
//   mode 2: cast heads (c0..c3 each 73728 u16x8 -> cdst, 1152 blocks).
template <int S>
__global__ __launch_bounds__(256) void reduce_ln_kernel(
    const float* __restrict__ P, const float* __restrict__ bias,
    float* __restrict__ hbuf, const float* __restrict__ gg,
    const float* __restrict__ bb, unsigned short* __restrict__ y,
    const float* __restrict__ c0, const float* __restrict__ c1,
    const float* __restrict__ c2, const float* __restrict__ c3,
    unsigned short* __restrict__ cdst, int mode)
{
  const int tid = threadIdx.x;
  if (blockIdx.x >= B_ * N_) {
    const unsigned ci = (blockIdx.x - B_ * N_) * 256u + tid;  // u16x8 unit
    const float* s;
    unsigned j;
    if (mode == 1) {
      if (ci < 221184u) { s = c0; j = ci; }
      else if (ci < 294912u) { s = c1; j = ci - 221184u; }
      else if (ci < 589824u) { s = c2; j = ci - 294912u; }
      else { s = c3; j = ci - 589824u; }
    } else {
      const unsigned r = ci / 73728u;
      j = ci - r * 73728u;
      s = (r == 0) ? c0 : (r == 1) ? c1 : (r == 2) ? c2 : c3;
    }
    const float4 a = ((const float4*)s)[2u * j];
    const float4 b = ((const float4*)s)[2u * j + 1u];
    u16x8 o = {f2bf(a.x), f2bf(a.y), f2bf(a.z), f2bf(a.w),
               f2bf(b.x), f2bf(b.y), f2bf(b.z), f2bf(b.w)};
    ((u16x8*)cdst)[ci] = o;
    return;
  }
  const int row = blockIdx.x;
  __shared__ float sred[4];
  float h[3];
#pragma unroll
  for (int t = 0; t < 3; ++t) {
    const int c = tid + (t << 8);
    float s = bias[c];
#pragma unroll
    for (int z = 0; z < S; ++z)
      s += P[((size_t)z * (B_ * N_) + row) * 768 + c];
    const float hv = hbuf[(size_t)row * 768 + c] + s;
    hbuf[(size_t)row * 768 + c] = hv;
    h[t] = hv;
  }
  float sm = breduce_sum(h[0] + h[1] + h[2], sred, tid);
  const float mean = sm * (1.f / 768.f);
  const float d0 = h[0] - mean, d1 = h[1] - mean, d2 = h[2] - mean;
  float q = breduce_sum(d0 * d0 + d1 * d1 + d2 * d2, sred, tid);
  const float inv = rsqrtf(q * (1.f / 768.f) + 1e-5f);
  unsigned short* out = y + (size_t)row * 768;
  out[tid]       = f2bf(d0 * inv * gg[tid]       + bb[tid]);
  out[tid + 256] = f2bf(d1 * inv * gg[tid + 256] + bb[tid + 256]);
  out[tid + 512] = f2bf(d2 * inv * gg[tid + 512] + bb[tid + 512]);
}

// ---------------------------------------------------------------------------
// MFMA GEMM (16x16): A bf16 [M,lda], W bf16 [N,ldw], 64x64 tile, BK=64,
// 4 waves, double-buffered global_load_lds, drain-barrier loop.
// EPI: 0 bias; 1 gelu(bias+); 3 segment-bias (768-chunks, gelu on seg 3);
//      4 split-K raw partial (blockIdx.z selects K-slice, C offset z*M*N).
template <int EPI, int OB>
__global__ __launch_bounds__(256) void gemm_mfma(
    const unsigned short* __restrict__ A, const unsigned short* __restrict__ W,
    const float* __restrict__ bias, const float* __restrict__ bias2,
    const float* __restrict__ bias3, const float* __restrict__ bias4,
    float* __restrict__ C, unsigned short* __restrict__ Cb,
    int M, int N, int K, int lda, int ldw)
{
  if (EPI == 4) {
    const int z = blockIdx.z;
    A += (size_t)z * K;
    W += (size_t)z * K;
    C += (size_t)z * M * N;
  }
  __shared__ __align__(16) unsigned short sA[2][64 * 64];
  __shared__ __align__(16) unsigned short sB[2][64 * 64];
  const int tid = threadIdx.x;
  const int l = tid & 63;
  const int w = tid >> 6;
  const int m0 = blockIdx.y * 64;
  const int n0 = blockIdx.x * 64;
  const int wm = w >> 1, wn = w & 1;
  const int lr = l & 15;
  const int lg = l >> 4;
  const int r0 = (w << 4) + (l >> 3);
  const int s0 = (l & 7) ^ (r0 & 7);

  f32x4 acc[2][2];
#pragma unroll
  for (int mi = 0; mi < 2; ++mi)
#pragma unroll
    for (int ni = 0; ni < 2; ++ni) acc[mi][ni] = (f32x4)0.f;

  auto stage = [&](int buf, int t) {
    const size_t kb = (size_t)t << 6;
    unsigned short* lA = &sA[buf][(w << 4) << 6];
    unsigned short* lB = &sB[buf][(w << 4) << 6];
    gload_lds16(A + (size_t)(m0 + r0) * lda + kb + (s0 << 3), lA);
    gload_lds16(A + (size_t)(m0 + r0 + 8) * lda + kb + (s0 << 3), lA + 8 * 64);
    gload_lds16(W + (size_t)(n0 + r0) * ldw + kb + (s0 << 3), lB);
    gload_lds16(W + (size_t)(n0 + r0 + 8) * ldw + kb + (s0 << 3), lB + 8 * 64);
  };

  stage(0, 0);
  const int nt = K >> 6;
  for (int t = 0; t < nt; ++t) {
    __syncthreads();   // drains vmcnt: buf[t&1] staged; prev reads done
    if (t + 1 < nt) stage((t + 1) & 1, t + 1);
    const unsigned short* bA = sA[t & 1];
    const unsigned short* bBs = sB[t & 1];
    bf16x8 af[2][2], bfr[2][2];
#pragma unroll
    for (int mi = 0; mi < 2; ++mi) {
      const int row = (wm << 5) + (mi << 4) + lr;
#pragma unroll
      for (int kk = 0; kk < 2; ++kk) {
        const int sl = ((kk << 2) + lg) ^ (row & 7);
        af[mi][kk] = *(const bf16x8*)&bA[(row << 6) + (sl << 3)];
      }
    }
#pragma unroll
    for (int ni = 0; ni < 2; ++ni) {
      const int row = (wn << 5) + (ni << 4) + lr;
#pragma unroll
      for (int kk = 0; kk < 2; ++kk) {
        const int sl = ((kk << 2) + lg) ^ (row & 7);
        bfr[ni][kk] = *(const bf16x8*)&bBs[(row << 6) + (sl << 3)];
      }
    }
#pragma unroll
    for (int kk = 0; kk < 2; ++kk)
#pragma unroll
      for (int mi = 0; mi < 2; ++mi)
#pragma unroll
        for (int ni = 0; ni < 2; ++ni)
          acc[mi][ni] = MFMA16(af[mi][kk], bfr[ni][kk], acc[mi][ni]);
  }

#pragma unroll
  for (int mi = 0; mi < 2; ++mi)
#pragma unroll
    for (int ni = 0; ni < 2; ++ni) {
      const int n = n0 + (wn << 5) + (ni << 4) + lr;
      float bv = 0.f;
      int seg = 0;
      if (EPI == 3) {
        seg = n / 768;
        const float* bp = (seg == 0) ? bias : (seg == 1) ? bias2
                         : (seg == 2) ? bias3 : bias4;
        bv = bp[n - seg * 768];
      } else if (EPI != 4) {
        bv = bias[n];
      }
#pragma unroll
      for (int r = 0; r < 4; ++r) {
        const int m = m0 + (wm << 5) + (mi << 4) + lg * 4 + r;
        float v = acc[mi][ni][r] + bv;
        if (EPI == 1) v = gelu_f(v);
        if (EPI == 3 && seg == 3) v = gelu_f(v);
        if (OB) Cb[(size_t)m * N + n] = f2bf(v);
        else C[(size_t)m * N + n] = v;
      }
    }
}

// ---------------------------------------------------------------------------
// MFMA attention, bf16 Q/K/V inputs. grid = (B*H, 4), block = 256 (4 waves).
// PV path: unnormalized P in sP, per-lane invr[] applied to O (defer-norm).
// PROBS path additionally computes wv projections on strip 0 (fused wv).
template <bool PROBS>
__global__ __launch_bounds__(256) void attn_mfma_kernel(
    const unsigned short* __restrict__ Q, const unsigned short* __restrict__ Kp,
    const unsigned short* __restrict__ Vp, const int stride,
    const unsigned short* __restrict__ biasb, unsigned short* __restrict__ obuf,
    unsigned short* __restrict__ aprob,
    const float* __restrict__ f1w, const float* __restrict__ f2w,
    const float* __restrict__ f3w, float* __restrict__ wv)
{
  __shared__ __align__(16) unsigned short sK[256 * 40];   // [j][d pad40]
  __shared__ __align__(16) unsigned short sVt[32 * 264];  // [d][j pad264]
  __shared__ __align__(16) unsigned short sP[64 * 264];   // [i_loc][j pad264]
  const int tid = threadIdx.x;
  const int l = tid & 63, w = tid >> 6;
  const int bh = blockIdx.x, b = bh >> 5, hh = bh & 31;
  const int i0 = blockIdx.y * 64;
  const int lr = l & 15, lg = l >> 4;

#pragma unroll
  for (int it = 0; it < 3; ++it) {
    const int c = tid + (it << 8);        // < 768
    const int row = c / 3, part = c - row * 3;
    *(u16x8*)&sK[row * 40 + part * 8] =
        *(const u16x8*)&Kp[(size_t)(b * N_ + row) * stride + hh * HD_ + part * 8];
  }
  {
    u16x8 z = {0, 0, 0, 0, 0, 0, 0, 0};
    *(u16x8*)&sK[tid * 40 + 24] = z;
  }
  if (!PROBS) {
    const int j = tid;
    const unsigned short* vr = &Vp[(size_t)(b * N_ + j) * stride + hh * HD_];
    const u16x8 v0 = *(const u16x8*)vr;
    const u16x8 v1 = *(const u16x8*)(vr + 8);
    const u16x8 v2 = *(const u16x8*)(vr + 16);
#pragma unroll
    for (int d = 0; d < 8; ++d) {
      sVt[d * 264 + j] = v0[d];
      sVt[(8 + d) * 264 + j] = v1[d];
      sVt[(16 + d) * 264 + j] = v2[d];
    }
  }
  bf16x8 aQ;
  if (lg < 3) {
    const u16x8 q = *(const u16x8*)&Q[(size_t)(b * N_ + i0 + (w << 4) + lr) * stride + hh * HD_ + lg * 8];
    union { u16x8 a; bf16x8 b; } u; u.a = q;
    aQ = u.b;
  } else {
    bf16x8 t = {0, 0, 0, 0, 0, 0, 0, 0};
    aQ = t;
  }
  __syncthreads();

  f32x4 acc[16];
#pragma unroll
  for (int ni = 0; ni < 16; ++ni) {
    const bf16x8 bK = *(const bf16x8*)&sK[(ni * 16 + lr) * 40 + lg * 8];
    acc[ni] = MFMA16(aQ, bK, (f32x4)0.f);
  }

  float invr[4];
#pragma unroll
  for (int r = 0; r < 4; ++r) {
    const int iloc = (w << 4) + lg * 4 + r;
    const unsigned short* bp =
        &biasb[(((size_t)(b * H_ + hh)) * N_ + i0 + iloc) * N_ + lr];
    float mx = -INFINITY;
#pragma unroll
    for (int ni = 0; ni < 16; ++ni) {
      const float s = acc[ni][r] * SCALE_ + bf2f(bp[ni * 16]);
      acc[ni][r] = s;
      mx = fmaxf(mx, s);
    }
    mx = fmaxf(mx, __shfl_xor(mx, 1));
    mx = fmaxf(mx, __shfl_xor(mx, 2));
    mx = fmaxf(mx, __shfl_xor(mx, 4));
    mx = fmaxf(mx, __shfl_xor(mx, 8));
    float sum = 0.f;
#pragma unroll
    for (int ni = 0; ni < 16; ++ni) {
      const float e = __expf(acc[ni][r] - mx);
      acc[ni][r] = e;
      sum += e;
    }
    sum += __shfl_xor(sum, 1);
    sum += __shfl_xor(sum, 2);
    sum += __shfl_xor(sum, 4);
    sum += __shfl_xor(sum, 8);
    const float inv = 1.f / sum;
    invr[r] = inv;
#pragma unroll
    for (int ni = 0; ni < 16; ++ni)
      sP[iloc * 264 + ni * 16 + lr] = f2bf(PROBS ? acc[ni][r] * inv
                                                 : acc[ni][r]);
  }
  __syncthreads();

  if (PROBS) {
#pragma unroll
    for (int it = 0; it < 8; ++it) {
      const int idx = tid + it * 256;     // < 2048
      const int row = idx >> 5, c = idx & 31;
      *(u16x8*)&aprob[(((size_t)(b * H_ + hh)) * N_ + i0 + row) * N_ + c * 8] =
          *(const u16x8*)&sP[row * 264 + c * 8];
    }
    // fused wv (strip 0 only): wv[c][b,hh,j] = sum_d V[b,j,hh,d]*fcw[hh*HD+d]
    if (blockIdx.y == 0) {
      const int j = tid;
      const unsigned short* vr = &Vp[(size_t)(b * N_ + j) * stride + hh * HD_];
      const u16x8 v0 = *(const u16x8*)vr;
      const u16x8 v1 = *(const u16x8*)(vr + 8);
      const u16x8 v2 = *(const u16x8*)(vr + 16);
      float s0 = 0.f, s1 = 0.f, s2 = 0.f;
#pragma unroll
      for (int d = 0; d < 8; ++d) {
        const float e0 = bf2f(v0[d]), e1 = bf2f(v1[d]), e2 = bf2f(v2[d]);
        s0 = fmaf(e0, f1w[hh * HD_ + d], s0);
        s0 = fmaf(e1, f1w[hh * HD_ + 8 + d], s0);
        s0 = fmaf(e2, f1w[hh * HD_ + 16 + d], s0);
        s1 = fmaf(e0, f2w[hh * HD_ + d], s1);
        s1 = fmaf(e1, f2w[hh * HD_ + 8 + d], s1);
        s1 = fmaf(e2, f2w[hh * HD_ + 16 + d], s1);
        s2 = fmaf(e0, f3w[hh * HD_ + d], s2);
        s2 = fmaf(e1, f3w[hh * HD_ + 8 + d], s2);
        s2 = fmaf(e2, f3w[hh * HD_ + 16 + d], s2);
      }
      wv[((size_t)(0 * B_ + b) * H_ + hh) * N_ + j] = s0;
      wv[((size_t)(1 * B_ + b) * H_ + hh) * N_ + j] = s1;
      wv[((size_t)(2 * B_ + b) * H_ + hh) * N_ + j] = s2;
    }
  } else {
    f32x4 accO[2];
    accO[0] = (f32x4)0.f; accO[1] = (f32x4)0.f;
#pragma unroll
    for (int ks = 0; ks < 8; ++ks) {
      const bf16x8 aP = *(const bf16x8*)&sP[((w << 4) + lr) * 264 + ks * 32 + lg * 8];
      const bf16x8 bV0 = *(const bf16x8*)&sVt[lr * 264 + ks * 32 + lg * 8];
      const bf16x8 bV1 = *(const bf16x8*)&sVt[(16 + lr) * 264 + ks * 32 + lg * 8];
      accO[0] = MFMA16(aP, bV0, accO[0]);
      accO[1] = MFMA16(aP, bV1, accO[1]);
    }
#pragma unroll
    for (int ni = 0; ni < 2; ++ni) {
      const int n = ni * 16 + lr;
      if (n < HD_) {
#pragma unroll
        for (int r = 0; r < 4; ++r) {
          const int i = i0 + (w << 4) + lg * 4 + r;
          obuf[(size_t)(b * N_ + i) * D_ + hh * HD_ + n] = f2bf(accO[ni][r] * invr[r]);
        }
      }
    }
  }
}

// ---------------------------------------------------------------------------
// Energy head (t1 bf16, rows strided)
__global__ __launch_bounds__(256) void engnode_kernel(
    const unsigned short* __restrict__ t1, const int stride,
    const float* __restrict__ en_w2, const float* __restrict__ en_b2,
    const float* __restrict__ eagg, const int* __restrict__ tags,
    float* __restrict__ engpn)
{
  const int bi = blockIdx.x;
  const int tid = threadIdx.x;
  __shared__ float sred[4];
  const unsigned short* row = t1 + (size_t)bi * stride;
  float acc = bf2f(row[tid]) * en_w2[tid] + bf2f(row[tid + 256]) * en_w2[tid + 256] +
              bf2f(row[tid + 512]) * en_w2[tid + 512];
  acc = breduce_sum(acc, sred, tid);
  if (tid == 0) {
    const int tg = tags[bi];
    engpn[bi] = (tg > 0) ? (acc + en_b2[0]) * eagg[tg] : 0.f;
  }
}

// engsum (blocks 0..3) + omask (blocks 4..7) merged
__global__ __launch_bounds__(256) void engsum_omask_kernel(
    const float* __restrict__ engpn, const int* __restrict__ tags,
    float* __restrict__ out)
{
  const int bid = blockIdx.x;
  const int tid = threadIdx.x;
  if (bid < 4) {
    __shared__ float sred[4];
    float v = breduce_sum(engpn[bid * N_ + tid], sred, tid);
    if (tid == 0) out[bid] = v;
  } else {
    const int idx = (bid - 4) * 256 + tid;
    out[4 + B_ * N_ * 3 + idx] = (tags[idx] > 0) ? 1.f : 0.f;
  }
}

// merged-c nodeout: grid = BN
__global__ __launch_bounds__(256) void nodeout_kernel(
    const unsigned short* __restrict__ aprob, const float* __restrict__ wv,
    const float* __restrict__ deltaw, const float* __restrict__ f1b,
    const float* __restrict__ f2b, const float* __restrict__ f3b,
    float* __restrict__ out)
{
  const int bi = blockIdx.x;
  const int tid = threadIdx.x;
  const int b = bi >> 8;
  const int i = bi & 255;
  __shared__ float sred[4];
  const unsigned short* ap = aprob + (((size_t)b * H_) * N_ + i) * N_ + tid;
  const float* wv0 = wv + ((size_t)(0 * B_ + b) * H_) * N_ + tid;
  const float* wv1 = wv + ((size_t)(1 * B_ + b) * H_) * N_ + tid;
  const float* wv2 = wv + ((size_t)(2 * B_ + b) * H_) * N_ + tid;
  float s0 = 0.f, s1 = 0.f, s2 = 0.f;
  for (int hh = 0; hh < H_; ++hh) {
    const float p = bf2f(ap[(size_t)hh * N_ * N_]);
    s0 = fmaf(p, wv0[(size_t)hh * N_], s0);
    s1 = fmaf(p, wv1[(size_t)hh * N_], s1);
    s2 = fmaf(p, wv2[(size_t)hh * N_], s2);
  }
  const float* dl = &deltaw[((size_t)bi * N_ + tid) * 3];
  s0 *= dl[0];
  s1 *= dl[1];
  s2 *= dl[2];
  s0 = breduce_sum(s0, sred, tid);
  s1 = breduce_sum(s1, sred, tid);
  s2 = breduce_sum(s2, sred, tid);
  if (tid == 0) {
    out[4 + bi * 3 + 0] = s0 + f1b[0];
    out[4 + bi * 3 + 1] = s1 + f2b[0];
    out[4 + bi * 3 + 2] = s2 + f3b[0];
  }
}

// ---------------------------------------------------------------------------
extern "C" void kernel_launch(void* const* d_in, const int* in_sizes, int n_in,
                              void* d_out, int out_size, void* d_ws, size_t ws_size,
                              hipStream_t stream) {
  (void)in_sizes; (void)n_in; (void)out_size; (void)ws_size;
  const int*   atoms     = (const int*)  d_in[0];
  const int*   tags      = (const int*)  d_in[1];
  const float* pos       = (const float*)d_in[2];
  const float* atom_emb  = (const float*)d_in[4];
  const float* tag_emb   = (const float*)d_in[5];
  const float* gbf_means = (const float*)d_in[6];
  const float* gbf_stds  = (const float*)d_in[7];
  const float* gbf_mul   = (const float*)d_in[8];
  const float* gbf_bias  = (const float*)d_in[9];
  const float* bp_w1     = (const float*)d_in[10];
  const float* bp_b1     = (const float*)d_in[11];
  const float* bp_w2     = (const float*)d_in[12];
  const float* bp_b2     = (const float*)d_in[13];
  const float* ep_w      = (const float*)d_in[14];
  const float* ep_b      = (const float*)d_in[15];
  const float* ln1_g     = (const float*)d_in[16];
  const float* ln1_b     = (const float*)d_in[17];
  const float* wqkv      = (const float*)d_in[18];
  const float* bqkv      = (const float*)d_in[19];
  const float* wo        = (const float*)d_in[20];
  const float* bo        = (const float*)d_in[21];
  const float* ln2_g     = (const float*)d_in[22];
  const float* ln2_b     = (const float*)d_in[23];
  const float* w1        = (const float*)d_in[24];
  const float* b1        = (const float*)d_in[25];
  const float* w2        = (const float*)d_in[26];
  const float* b2        = (const float*)d_in[27];
  const float* fln_g     = (const float*)d_in[28];
  const float* fln_b     = (const float*)d_in[29];
  const float* en_w1     = (const float*)d_in[30];
  const float* en_b1     = (const float*)d_in[31];
  const float* en_w2     = (const float*)d_in[32];
  const float* en_b2     = (const float*)d_in[33];
  const float* eagg      = (const float*)d_in[34];
  const float* nq_w      = (const float*)d_in[35];
  const float* nq_b      = (const float*)d_in[36];
  const float* nk_w      = (const float*)d_in[37];
  const float* nk_b      = (const float*)d_in[38];
  const float* nv_w      = (const float*)d_in[39];
  const float* nv_b      = (const float*)d_in[40];
  const float* f1_w      = (const float*)d_in[41];
  const float* f1_b      = (const float*)d_in[42];
  const float* f2_w      = (const float*)d_in[43];
  const float* f2_b      = (const float*)d_in[44];
  const float* f3_w      = (const float*)d_in[45];
  const float* f3_b      = (const float*)d_in[46];

  char* wsB = (char*)d_ws;
  size_t off = 0;
  auto alloc = [&](size_t bytes) {
    void* p = wsB + off;
    off = (off + bytes + 255) & ~(size_t)255;
    return p;
  };
  unsigned short* biasb   = (unsigned short*)alloc((size_t)B_ * H_ * N_ * N_ * 2);
  unsigned short* aprobb  = (unsigned short*)alloc((size_t)B_ * H_ * N_ * N_ * 2);
  float*          deltaw  = (float*)alloc((size_t)B_ * N_ * N_ * 3 * 4);
  float*          xvalw   = (float*)alloc((size_t)B_ * N_ * N_ * 4);
  float*          nsumw   = (float*)alloc((size_t)B_ * N_ * K_ * 4);
  float*          hbuf    = (float*)alloc((size_t)B_ * N_ * D_ * 4);
  unsigned short* qkvb    = (unsigned short*)alloc((size_t)B_ * N_ * 3 * D_ * 2);
  unsigned short* qn4b    = (unsigned short*)alloc((size_t)B_ * N_ * 3072 * 2);
  unsigned short* ybf     = (unsigned short*)alloc((size_t)B_ * N_ * D_ * 2);
  unsigned short* obf     = (unsigned short*)alloc((size_t)B_ * N_ * D_ * 2);
  unsigned short* midbf   = (unsigned short*)alloc((size_t)B_ * N_ * F_ * 2);
  unsigned short* outbf   = (unsigned short*)alloc((size_t)B_ * N_ * D_ * 2);
  unsigned short* arena   = (unsigned short*)alloc((size_t)2 * 7077888 * 2);  // double-buffered
  unsigned short* headsb  = (unsigned short*)alloc((size_t)2359296 * 2);
  unsigned short* bw1b    = (unsigned short*)alloc((size_t)K_ * K_ * 2);
  unsigned short* bw2b    = (unsigned short*)alloc((size_t)H_ * K_ * 2);
  float*          wopart  = (float*)alloc((size_t)2 * B_ * N_ * D_ * 4);
  float*          ffpart  = (float*)alloc((size_t)4 * B_ * N_ * D_ * 4);
  float*          wvb     = (float*)alloc((size_t)3 * B_ * H_ * N_ * 4);
  float*          engpn   = (float*)alloc((size_t)B_ * N_ * 4);

  const int BN = B_ * N_;  // 1024
  float* outp = (float*)d_out;
  const size_t AR = 7077888;
  const size_t OQKV = 0, OWO = 1769472, OW1 = 2359296, OW2 = 4718592;

  edge_pre_kernel<<<BN, 256, 0, stream>>>(atoms, pos, gbf_mul, gbf_bias,
                                          gbf_means, gbf_stds, deltaw, xvalw, nsumw);
  cast_bias_kernel<<<20, 256, 0, stream>>>(bp_w1, bp_w2, bw1b, bw2b);
  bias_mfma_kernel<<<B_ * N_ * N_ / 64, 256, 0, stream>>>(
      xvalw, atoms, gbf_means, gbf_stds, bw1b, bp_b1, bw2b, bp_b2, biasb);
  node_init_kernel<<<BN, 256, 0, stream>>>(atoms, tags, atom_emb, tag_emb,
                                           nsumw, ep_w, ep_b, hbuf);
  ln_kernel<<<BN, 256, 0, stream>>>(hbuf, ln1_g, ln1_b, ybf);
  // prologue: cast layer 0 into arena half 0
  castlayer_kernel<<<3456, 256, 0, stream>>>(
      wqkv, wo, w1, w2, arena);

  for (int l = 0; l < L_; ++l) {
    unsigned short* ar = arena + (size_t)(l & 1) * AR;
    // QKV: [1024,2304] bf16
    gemm_mfma<0, 1><<<dim3(36, 16), 256, 0, stream>>>(
        ybf, ar + OQKV, bqkv + (size_t)l * 3 * D_, nullptr, nullptr, nullptr,
        nullptr, qkvb, BN, 3 * D_, D_, D_, D_);
    attn_mfma_kernel<false><<<dim3(B_ * H_, 4), 256, 0, stream>>>(
        qkvb, qkvb + D_, qkvb + 2 * D_, 3 * D_, biasb, obf, nullptr,
        nullptr, nullptr, nullptr, nullptr);
    // wo: split-K=2 partials
    gemm_mfma<4, 0><<<dim3(12, 16, 2), 256, 0, stream>>>(
        obf, ar + OWO, nullptr, nullptr, nullptr, nullptr,
        wopart, nullptr, BN, D_, 384, D_, D_);
    // reduce + res + ln2 -> ybf, piggy-backing next layer's (or heads') cast
    if (l + 1 < L_) {
      const int lc = l + 1;
      reduce_ln_kernel<2><<<BN + 3456, 256, 0, stream>>>(
          wopart, bo + (size_t)l * D_, hbuf, ln2_g + (size_t)l * D_,
          ln2_b + (size_t)l * D_, ybf,
          wqkv + (size_t)lc * 3 * D_ * D_, wo + (size_t)lc * D_ * D_,
          w1 + (size_t)lc * F_ * D_, w2 + (size_t)lc * D_ * F_,
          arena + (size_t)(lc & 1) * AR, 1);
    } else {
      reduce_ln_kernel<2><<<BN + 1152, 256, 0, stream>>>(
          wopart, bo + (size_t)l * D_, hbuf, ln2_g + (size_t)l * D_,
          ln2_b + (size_t)l * D_, ybf,
          nq_w, nk_w, nv_w, en_w1, headsb, 2);
    }
    // FFN1: gelu -> midbf bf16
    gemm_mfma<1, 1><<<dim3(48, 16), 256, 0, stream>>>(
        ybf, ar + OW1, b1 + (size_t)l * F_, nullptr, nullptr, nullptr,
        nullptr, midbf, BN, F_, D_, D_, D_);
    // FFN2: split-K=4 partials, then reduce + res + ln1(l+1) (or fln) -> y
    gemm_mfma<4, 0><<<dim3(12, 16, 4), 256, 0, stream>>>(
        midbf, ar + OW2, nullptr, nullptr, nullptr, nullptr,
        ffpart, nullptr, BN, D_, 768, F_, F_);
    const bool last = (l == L_ - 1);
    reduce_ln_kernel<4><<<BN, 256, 0, stream>>>(
        ffpart, b2 + (size_t)l * D_, hbuf,
        last ? fln_g : ln1_g + (size_t)(l + 1) * D_,
        last ? fln_b : ln1_b + (size_t)(l + 1) * D_,
        last ? outbf : ybf,
        nullptr, nullptr, nullptr, nullptr, nullptr, 0);
  }

  // merged head GEMM: N = 3072 (q|k|v|t1), gelu on the en segment, bf16 out
  gemm_mfma<3, 1><<<dim3(48, 16), 256, 0, stream>>>(
      outbf, headsb, nq_b, nk_b, nv_b, en_b1,
      nullptr, qn4b, BN, 3072, D_, D_, D_);

  attn_mfma_kernel<true><<<dim3(B_ * H_, 4), 256, 0, stream>>>(
      qn4b, qn4b + 768, qn4b + 1536, 3072, biasb, nullptr, aprobb,
      f1_w, f2_w, f3_w, wvb);
  nodeout_kernel<<<BN, 256, 0, stream>>>(aprobb, wvb, deltaw,
                                         f1_b, f2_b, f3_b, outp);

  engnode_kernel<<<BN, 256, 0, stream>>>(qn4b + 2304, 3072, en_w2, en_b2,
                                         eagg, tags, engpn);
  engsum_omask_kernel<<<8, 256, 0, stream>>>(engpn, tags, outp);
}

// Round 14
// 978.614 us; speedup vs baseline: 1.0636x; 1.0092x over previous
//
#include <hip/hip_runtime.h>
#include <math.h>

// Graphormer3D forward — round 13: R12 (best 988us) + layer0/bias casts
// piggybacked into edge_pre + merged nodeout/engnode tail.
// B=4 N=256 D=768 H=32 HD=24 L=12 F=3072 K=128
constexpr int B_ = 4, N_ = 256, D_ = 768, H_ = 32, HD_ = 24, L_ = 12, F_ = 3072, K_ = 128;
constexpr float SCALE_ = 0.20412414523193150f;   // HD^-0.5
constexpr float ISQRT2_ = 0.70710678118654752f;

typedef short bf16x8 __attribute__((ext_vector_type(8)));
typedef float f32x4 __attribute__((ext_vector_type(4)));
typedef unsigned short u16x4 __attribute__((ext_vector_type(4)));
typedef unsigned short u16x8 __attribute__((ext_vector_type(8)));
typedef unsigned int u32x4 __attribute__((ext_vector_type(4)));

#define DEV __device__ __forceinline__
#define MFMA16(a, b, c) __builtin_amdgcn_mfma_f32_16x16x32_bf16(a, b, c, 0, 0, 0)

DEV void gload_lds16(const unsigned short* g, unsigned short* l) {
  __builtin_amdgcn_global_load_lds(
      (const __attribute__((address_space(1))) unsigned int*)(g),
      (__attribute__((address_space(3))) unsigned int*)(l), 16, 0, 0);
}

DEV float gelu_f(float x) { return 0.5f * x * (1.0f + erff(x * ISQRT2_)); }

DEV unsigned short f2bf(float f) {  // RNE f32 -> bf16
  unsigned u = __float_as_uint(f);
  return (unsigned short)((u + 0x7FFFu + ((u >> 16) & 1u)) >> 16);
}
DEV float bf2f(unsigned short u) { return __uint_as_float(((unsigned)u) << 16); }
DEV unsigned packbf(float a, float b) {
  return (unsigned)f2bf(a) | ((unsigned)f2bf(b) << 16);
}
DEV bf16x8 u4_to_bf8(u32x4 x) { union { u32x4 a; bf16x8 b; } u; u.a = x; return u.b; }

// deterministic block(256) reductions
DEV float breduce_sum(float v, float* sred, int tid) {
#pragma unroll
  for (int o = 32; o > 0; o >>= 1) v += __shfl_xor(v, o);
  if ((tid & 63) == 0) sred[tid >> 6] = v;
  __syncthreads();
  v = (sred[0] + sred[1]) + (sred[2] + sred[3]);
  __syncthreads();
  return v;
}

// ---------------------------------------------------------------------------
// Kernel 1: per-(b,i) edge precompute (f32), with piggy-backed casts:
//   blocks [BN, BN+3456): layer-0 weight cast -> arena half 0
//   blocks [BN+3456, BN+3476): bias-MLP weight cast -> bw1b/bw2b
__global__ __launch_bounds__(256) void edge_pre_kernel(
    const int* __restrict__ atoms, const float* __restrict__ pos,
    const float* __restrict__ gbf_mul, const float* __restrict__ gbf_bias,
    const float* __restrict__ gbf_means, const float* __restrict__ gbf_stds,
    float* __restrict__ deltaw, float* __restrict__ xvalw, float* __restrict__ nsumw,
    const float* __restrict__ wqkv0, const float* __restrict__ wo0,
    const float* __restrict__ w10, const float* __restrict__ w20,
    unsigned short* __restrict__ arena0,
    const float* __restrict__ bpw1, const float* __restrict__ bpw2,
    unsigned short* __restrict__ bw1b, unsigned short* __restrict__ bw2b)
{
  const int tid = threadIdx.x;
  if (blockIdx.x >= B_ * N_) {
    const unsigned cb = blockIdx.x - B_ * N_;
    if (cb < 3456u) {
      const unsigned i = cb * 256u + tid;  // u16x8 unit, < 884736
      const float* s; unsigned j;
      if (i < 221184u) { s = wqkv0; j = i; }
      else if (i < 294912u) { s = wo0; j = i - 221184u; }
      else if (i < 589824u) { s = w10; j = i - 294912u; }
      else { s = w20; j = i - 589824u; }
      const float4 a = ((const float4*)s)[2u * j];
      const float4 b = ((const float4*)s)[2u * j + 1u];
      u16x8 o = {f2bf(a.x), f2bf(a.y), f2bf(a.z), f2bf(a.w),
                 f2bf(b.x), f2bf(b.y), f2bf(b.z), f2bf(b.w)};
      ((u16x8*)arena0)[i] = o;
    } else {
      const int i = (cb - 3456u) * 256 + tid;  // float4 unit, < 5120
      const float* s;
      unsigned short* d;
      int j;
      if (i < 4096) { s = bpw1; d = bw1b; j = i; }
      else { s = bpw2; d = bw2b; j = i - 4096; }
      const float4 v = ((const float4*)s)[j];
      u16x4 o = {f2bf(v.x), f2bf(v.y), f2bf(v.z), f2bf(v.w)};
      ((u16x4*)d)[j] = o;
    }
    return;
  }
  const int bi = blockIdx.x;
  const int b = bi >> 8;
  __shared__ float spos[3];
  __shared__ float sxv[256];
  __shared__ int   spad[256];
  __shared__ float red[256];
  if (tid < 3) spos[tid] = pos[(size_t)bi * 3 + tid];
  __syncthreads();
  {
    const int j = tid;
    const float px = pos[(size_t)(b * N_ + j) * 3 + 0];
    const float py = pos[(size_t)(b * N_ + j) * 3 + 1];
    const float pz = pos[(size_t)(b * N_ + j) * 3 + 2];
    const float dx = px - spos[0], dy = py - spos[1], dz = pz - spos[2];
    const float sq = dx * dx + dy * dy + dz * dz;
    const float dist = sqrtf(fmaxf(sq, 1e-24f));
    const float inv = 1.f / (dist + 1e-5f);
    const size_t e = (size_t)bi * N_ + j;
    deltaw[e * 3 + 0] = dx * inv;
    deltaw[e * 3 + 1] = dy * inv;
    deltaw[e * 3 + 2] = dz * inv;
    const int et = atoms[bi] * 64 + atoms[b * N_ + j];
    const float xv = gbf_mul[et] * dist + gbf_bias[et];
    xvalw[e] = xv;
    sxv[j] = xv;
    spad[j] = (atoms[b * N_ + j] == 0);
  }
  __syncthreads();
  const int k = tid & 127;
  const float mean = gbf_means[k];
  const float st = fabsf(gbf_stds[k]) + 1e-5f;
  const float istd = 1.f / st;
  const float coef = 0.39894228040143268f * istd;
  float acc = 0.f;
  const int jbase = tid >> 7;
  for (int t = 0; t < 128; ++t) {
    const int j = jbase + (t << 1);
    if (!spad[j]) {
      const float z = (sxv[j] - mean) * istd;
      acc += __expf(-0.5f * z * z) * coef;
    }
  }
  red[tid] = acc;
  __syncthreads();
  if (tid < 128) nsumw[(size_t)bi * K_ + tid] = red[tid] + red[tid + 128];
}

// ---------------------------------------------------------------------------
// Kernel 2 (MFMA, register datapath): bias MLP per 64-edge tile.
__global__ __launch_bounds__(256) void bias_mfma_kernel(
    const float* __restrict__ xvalw, const int* __restrict__ atoms,
    const float* __restrict__ gbf_means, const float* __restrict__ gbf_stds,
    const unsigned short* __restrict__ w1b, const float* __restrict__ b1,
    const unsigned short* __restrict__ w2b, const float* __restrict__ b2,
    unsigned short* __restrict__ biasb)
{
  __shared__ __align__(16) unsigned short sw1[128 * 128];  // 32 KB, swizzled
  __shared__ __align__(16) unsigned short sw2[32 * 128];   // 8 KB, swizzled
  __shared__ float smean[128], sistd[128], scoef[128], sb1[128], sb2[32];
  const int tid = threadIdx.x;
  const int l = tid & 63;
  const int w = tid >> 6;
  const size_t e0 = (size_t)blockIdx.x * 64;
  const int bB = (int)(e0 >> 16);
  const int iI = (int)((e0 >> 8) & 255);
  const int j0 = (int)(e0 & 255);
  const int lr = l & 15;
  const int lg = l >> 4;

  {
    const int rin = l >> 4;
    const int slot = l & 15;
#pragma unroll
    for (int q = 0; q < 8; ++q) {
      const int rbase = w * 32 + q * 4;
      const int row = rbase + rin;
      const int gs = slot ^ (row & 15);
      gload_lds16(w1b + row * 128 + gs * 8, &sw1[rbase * 128]);
    }
#pragma unroll
    for (int q = 0; q < 2; ++q) {
      const int rbase = w * 8 + q * 4;
      const int row = rbase + rin;
      const int gs = slot ^ (row & 15);
      gload_lds16(w2b + row * 128 + gs * 8, &sw2[rbase * 128]);
    }
  }
  if (tid < 128) {
    const float st = fabsf(gbf_stds[tid]) + 1e-5f;
    const float is = 1.f / st;
    smean[tid] = gbf_means[tid];
    sistd[tid] = is;
    scoef[tid] = 0.39894228040143268f * is;
    sb1[tid] = b1[tid];
  } else if (tid < 160) {
    sb2[tid - 128] = b2[tid - 128];
  }
  const int el = w * 16 + lr;
  const float xv = xvalw[e0 + el];
  const bool padq = (atoms[bB * N_ + j0 + el] == 0);
  __syncthreads();

  bf16x8 bG[4];
#pragma unroll
  for (int ks = 0; ks < 4; ++ks) {
    u16x8 t;
#pragma unroll
    for (int j = 0; j < 8; ++j) {
      const int k = ks * 32 + lg * 8 + j;
      const float z = (xv - smean[k]) * sistd[k];
      t[j] = f2bf(__expf(-0.5f * z * z) * scoef[k]);
    }
    union { u16x8 a; bf16x8 b; } u; u.a = t;
    bG[ks] = u.b;
  }

  f32x4 accM[8];
#pragma unroll
  for (int f = 0; f < 8; ++f) accM[f] = (f32x4)0.f;
#pragma unroll
  for (int ks = 0; ks < 4; ++ks) {
#pragma unroll
    for (int f = 0; f < 8; ++f) {
      const int row = f * 16 + lr;
      const int sl = (ks * 4 + lg) ^ (row & 15);
      const bf16x8 aW = *(const bf16x8*)&sw1[row * 128 + (sl << 3)];
      accM[f] = MFMA16(aW, bG[ks], accM[f]);
    }
  }

  unsigned pm[8][2];
#pragma unroll
  for (int f = 0; f < 8; ++f) {
    float g[4];
#pragma unroll
    for (int r = 0; r < 4; ++r)
      g[r] = gelu_f(accM[f][r] + sb1[f * 16 + lg * 4 + r]);
    pm[f][0] = packbf(g[0], g[1]);
    pm[f][1] = packbf(g[2], g[3]);
  }

  f32x4 accH[2];
  accH[0] = (f32x4)0.f; accH[1] = (f32x4)0.f;
#pragma unroll
  for (int ks = 0; ks < 4; ++ks) {
    const int s0 = ((((lg << 1)) & 3) << 4) + lr;
    const int s1 = ((((lg << 1) + 1) & 3) << 4) + lr;
    const int sel = lg >> 1;
    const unsigned a0 = __shfl(pm[2 * ks][0], s0), b0 = __shfl(pm[2 * ks + 1][0], s0);
    const unsigned a1 = __shfl(pm[2 * ks][1], s0), b1v = __shfl(pm[2 * ks + 1][1], s0);
    const unsigned a2 = __shfl(pm[2 * ks][0], s1), b2v = __shfl(pm[2 * ks + 1][0], s1);
    const unsigned a3 = __shfl(pm[2 * ks][1], s1), b3v = __shfl(pm[2 * ks + 1][1], s1);
    u32x4 bw;
    bw.x = sel ? b0 : a0;
    bw.y = sel ? b1v : a1;
    bw.z = sel ? b2v : a2;
    bw.w = sel ? b3v : a3;
    const bf16x8 bMid = u4_to_bf8(bw);
#pragma unroll
    for (int hf = 0; hf < 2; ++hf) {
      const int row = hf * 16 + lr;
      const int sl = (ks * 4 + lg) ^ (row & 15);
      const bf16x8 aW2 = *(const bf16x8*)&sw2[row * 128 + (sl << 3)];
      accH[hf] = MFMA16(aW2, bMid, accH[hf]);
    }
  }

  const size_t obase = (((size_t)bB * H_) * N_ + iI) * N_ + j0 + el;
#pragma unroll
  for (int hf = 0; hf < 2; ++hf) {
#pragma unroll
    for (int r = 0; r < 4; ++r) {
      const int h = hf * 16 + lg * 4 + r;
      const unsigned short v = padq ? (unsigned short)0xFF80
                                    : f2bf(accH[hf][r] + sb2[h]);
      biasb[obase + (size_t)h * N_ * N_] = v;
    }
  }
}

// ---------------------------------------------------------------------------
// Kernel 3: node init
__global__ __launch_bounds__(256) void node_init_kernel(
    const int* __restrict__ atoms, const int* __restrict__ tags,
    const float* __restrict__ atom_emb, const float* __restrict__ tag_emb,
    const float* __restrict__ nsumw, const float* __restrict__ ep_w,
    const float* __restrict__ ep_b, float* __restrict__ hbuf)
{
  const int bi = blockIdx.x;
  const int tid = threadIdx.x;
  __shared__ float ns[K_];
  if (tid < K_) ns[tid] = nsumw[(size_t)bi * K_ + tid];
  __syncthreads();
  const int at = atoms[bi], tg = tags[bi];
  for (int d = tid; d < D_; d += 256) {
    float acc = tag_emb[tg * D_ + d] + atom_emb[at * D_ + d] + ep_b[d];
    const float* w = ep_w + (size_t)d * K_;
#pragma unroll 8
    for (int kk = 0; kk < K_; ++kk) acc = fmaf(ns[kk], w[kk], acc);
    hbuf[(size_t)bi * D_ + d] = acc;
  }
}

// ---------------------------------------------------------------------------
// LayerNorm -> bf16 out (used once, before layer 0)
__global__ __launch_bounds__(256) void ln_kernel(
    const float* __restrict__ x, const float* __restrict__ gg,
    const float* __restrict__ bb, unsigned short* __restrict__ y)
{
  const int bi = blockIdx.x;
  const int tid = threadIdx.x;
  __shared__ float sred[4];
  const float* row = x + (size_t)bi * D_;
  const float v0 = row[tid], v1 = row[tid + 256], v2 = row[tid + 512];
  float s = breduce_sum(v0 + v1 + v2, sred, tid);
  const float mean = s * (1.f / 768.f);
  const float d0 = v0 - mean, d1 = v1 - mean, d2 = v2 - mean;
  float q = breduce_sum(d0 * d0 + d1 * d1 + d2 * d2, sred, tid);
  const float inv = rsqrtf(q * (1.f / 768.f) + 1e-5f);
  unsigned short* out = y + (size_t)bi * D_;
  out[tid]       = f2bf(d0 * inv * gg[tid]       + bb[tid]);
  out[tid + 256] = f2bf(d1 * inv * gg[tid + 256] + bb[tid + 256]);
  out[tid + 512] = f2bf(d2 * inv * gg[tid + 512] + bb[tid + 512]);
}

// ---------------------------------------------------------------------------
// Split-K reduce + residual + bias + LayerNorm -> bf16 y (and updated hbuf),
// with optional piggy-backed weight cast on extra blocks:
//   mode 0: none; mode 1: cast next layer (c0..c3 -> cdst, 3456 blocks);
//   mode 2: cast heads (c0..c3 each 73728 u16x8 -> cdst, 1152 blocks).
template <int S>
__global__ __launch_bounds__(256) void reduce_ln_kernel(
    const float* __restrict__ P, const float* __restrict__ bias,
    float* __restrict__ hbuf, const float* __restrict__ gg,
    const float* __restrict__ bb, unsigned short* __restrict__ y,
    const float* __restrict__ c0, const float* __restrict__ c1,
    const float* __restrict__ c2, const float* __restrict__ c3,
    unsigned short* __restrict__ cdst, int mode)
{
  const int tid = threadIdx.x;
  if (blockIdx.x >= B_ * N_) {
    const unsigned ci = (blockIdx.x - B_ * N_) * 256u + tid;  // u16x8 unit
    const float* s;
    unsigned j;
    if (mode == 1) {
      if (ci < 221184u) { s = c0; j = ci; }
      else if (ci < 294912u) { s = c1; j = ci - 221184u; }
      else if (ci < 589824u) { s = c2; j = ci - 294912u; }
      else { s = c3; j = ci - 589824u; }
    } else {
      const unsigned r = ci / 73728u;
      j = ci - r * 73728u;
      s = (r == 0) ? c0 : (r == 1) ? c1 : (r == 2) ? c2 : c3;
    }
    const float4 a = ((const float4*)s)[2u * j];
    const float4 b = ((const float4*)s)[2u * j + 1u];
    u16x8 o = {f2bf(a.x), f2bf(a.y), f2bf(a.z), f2bf(a.w),
               f2bf(b.x), f2bf(b.y), f2bf(b.z), f2bf(b.w)};
    ((u16x8*)cdst)[ci] = o;
    return;
  }
  const int row = blockIdx.x;
  __shared__ float sred[4];
  float h[3];
#pragma unroll
  for (int t = 0; t < 3; ++t) {
    const int c = tid + (t << 8);
    float s = bias[c];
#pragma unroll
    for (int z = 0; z < S; ++z)
      s += P[((size_t)z * (B_ * N_) + row) * 768 + c];
    const float hv = hbuf[(size_t)row * 768 + c] + s;
    hbuf[(size_t)row * 768 + c] = hv;
    h[t] = hv;
  }
  float sm = breduce_sum(h[0] + h[1] + h[2], sred, tid);
  const float mean = sm * (1.f / 768.f);
  const float d0 = h[0] - mean, d1 = h[1] - mean, d2 = h[2] - mean;
  float q = breduce_sum(d0 * d0 + d1 * d1 + d2 * d2, sred, tid);
  const float inv = rsqrtf(q * (1.f / 768.f) + 1e-5f);
  unsigned short* out = y + (size_t)row * 768;
  out[tid]       = f2bf(d0 * inv * gg[tid]       + bb[tid]);
  out[tid + 256] = f2bf(d1 * inv * gg[tid + 256] + bb[tid + 256]);
  out[tid + 512] = f2bf(d2 * inv * gg[tid + 512] + bb[tid + 512]);
}

// ---------------------------------------------------------------------------
// MFMA GEMM (16x16): A bf16 [M,lda], W bf16 [N,ldw], 64x64 tile, BK=64,
// 4 waves, double-buffered global_load_lds, drain-barrier loop.
// EPI: 0 bias; 1 gelu(bias+); 3 segment-bias (768-chunks, gelu on seg 3);
//      4 split-K raw partial (blockIdx.z selects K-slice, C offset z*M*N).
template <int EPI, int OB>
__global__ __launch_bounds__(256) void gemm_mfma(
    const unsigned short* __restrict__ A, const unsigned short* __restrict__ W,
    const float* __restrict__ bias, const float* __restrict__ bias2,
    const float* __restrict__ bias3, const float* __restrict__ bias4,
    float* __restrict__ C, unsigned short* __restrict__ Cb,
    int M, int N, int K, int lda, int ldw)
{
  if (EPI == 4) {
    const int z = blockIdx.z;
    A += (size_t)z * K;
    W += (size_t)z * K;
    C += (size_t)z * M * N;
  }
  __shared__ __align__(16) unsigned short sA[2][64 * 64];
  __shared__ __align__(16) unsigned short sB[2][64 * 64];
  const int tid = threadIdx.x;
  const int l = tid & 63;
  const int w = tid >> 6;
  const int m0 = blockIdx.y * 64;
  const int n0 = blockIdx.x * 64;
  const int wm = w >> 1, wn = w & 1;
  const int lr = l & 15;
  const int lg = l >> 4;
  const int r0 = (w << 4) + (l >> 3);
  const int s0 = (l & 7) ^ (r0 & 7);

  f32x4 acc[2][2];
#pragma unroll
  for (int mi = 0; mi < 2; ++mi)
#pragma unroll
    for (int ni = 0; ni < 2; ++ni) acc[mi][ni] = (f32x4)0.f;

  auto stage = [&](int buf, int t) {
    const size_t kb = (size_t)t << 6;
    unsigned short* lA = &sA[buf][(w << 4) << 6];
    unsigned short* lB = &sB[buf][(w << 4) << 6];
    gload_lds16(A + (size_t)(m0 + r0) * lda + kb + (s0 << 3), lA);
    gload_lds16(A + (size_t)(m0 + r0 + 8) * lda + kb + (s0 << 3), lA + 8 * 64);
    gload_lds16(W + (size_t)(n0 + r0) * ldw + kb + (s0 << 3), lB);
    gload_lds16(W + (size_t)(n0 + r0 + 8) * ldw + kb + (s0 << 3), lB + 8 * 64);
  };

  stage(0, 0);
  const int nt = K >> 6;
  for (int t = 0; t < nt; ++t) {
    __syncthreads();   // drains vmcnt: buf[t&1] staged; prev reads done
    if (t + 1 < nt) stage((t + 1) & 1, t + 1);
    const unsigned short* bA = sA[t & 1];
    const unsigned short* bBs = sB[t & 1];
    bf16x8 af[2][2], bfr[2][2];
#pragma unroll
    for (int mi = 0; mi < 2; ++mi) {
      const int row = (wm << 5) + (mi << 4) + lr;
#pragma unroll
      for (int kk = 0; kk < 2; ++kk) {
        const int sl = ((kk << 2) + lg) ^ (row & 7);
        af[mi][kk] = *(const bf16x8*)&bA[(row << 6) + (sl << 3)];
      }
    }
#pragma unroll
    for (int ni = 0; ni < 2; ++ni) {
      const int row = (wn << 5) + (ni << 4) + lr;
#pragma unroll
      for (int kk = 0; kk < 2; ++kk) {
        const int sl = ((kk << 2) + lg) ^ (row & 7);
        bfr[ni][kk] = *(const bf16x8*)&bBs[(row << 6) + (sl << 3)];
      }
    }
#pragma unroll
    for (int kk = 0; kk < 2; ++kk)
#pragma unroll
      for (int mi = 0; mi < 2; ++mi)
#pragma unroll
        for (int ni = 0; ni < 2; ++ni)
          acc[mi][ni] = MFMA16(af[mi][kk], bfr[ni][kk], acc[mi][ni]);
  }

#pragma unroll
  for (int mi = 0; mi < 2; ++mi)
#pragma unroll
    for (int ni = 0; ni < 2; ++ni) {
      const int n = n0 + (wn << 5) + (ni << 4) + lr;
      float bv = 0.f;
      int seg = 0;
      if (EPI == 3) {
        seg = n / 768;
        const float* bp = (seg == 0) ? bias : (seg == 1) ? bias2
                         : (seg == 2) ? bias3 : bias4;
        bv = bp[n - seg * 768];
      } else if (EPI != 4) {
        bv = bias[n];
      }
#pragma unroll
      for (int r = 0; r < 4; ++r) {
        const int m = m0 + (wm << 5) + (mi << 4) + lg * 4 + r;
        float v = acc[mi][ni][r] + bv;
        if (EPI == 1) v = gelu_f(v);
        if (EPI == 3 && seg == 3) v = gelu_f(v);
        if (OB) Cb[(size_t)m * N + n] = f2bf(v);
        else C[(size_t)m * N + n] = v;
      }
    }
}

// ---------------------------------------------------------------------------
// MFMA attention, bf16 Q/K/V inputs. grid = (B*H, 4), block = 256 (4 waves).
// PV path: unnormalized P in sP, per-lane invr[] applied to O (defer-norm).
// PROBS path additionally computes wv projections on strip 0 (fused wv).
template <bool PROBS>
__global__ __launch_bounds__(256) void attn_mfma_kernel(
    const unsigned short* __restrict__ Q, const unsigned short* __restrict__ Kp,
    const unsigned short* __restrict__ Vp, const int stride,
    const unsigned short* __restrict__ biasb, unsigned short* __restrict__ obuf,
    unsigned short* __restrict__ aprob,
    const float* __restrict__ f1w, const float* __restrict__ f2w,
    const float* __restrict__ f3w, float* __restrict__ wv)
{
  __shared__ __align__(16) unsigned short sK[256 * 40];   // [j][d pad40]
  __shared__ __align__(16) unsigned short sVt[32 * 264];  // [d][j pad264]
  __shared__ __align__(16) unsigned short sP[64 * 264];   // [i_loc][j pad264]
  const int tid = threadIdx.x;
  const int l = tid & 63, w = tid >> 6;
  const int bh = blockIdx.x, b = bh >> 5, hh = bh & 31;
  const int i0 = blockIdx.y * 64;
  const int lr = l & 15, lg = l >> 4;

#pragma unroll
  for (int it = 0; it < 3; ++it) {
    const int c = tid + (it << 8);        // < 768
    const int row = c / 3, part = c - row * 3;
    *(u16x8*)&sK[row * 40 + part * 8] =
        *(const u16x8*)&Kp[(size_t)(b * N_ + row) * stride + hh * HD_ + part * 8];
  }
  {
    u16x8 z = {0, 0, 0, 0, 0, 0, 0, 0};
    *(u16x8*)&sK[tid * 40 + 24] = z;
  }
  if (!PROBS) {
    const int j = tid;
    const unsigned short* vr = &Vp[(size_t)(b * N_ + j) * stride + hh * HD_];
    const u16x8 v0 = *(const u16x8*)vr;
    const u16x8 v1 = *(const u16x8*)(vr + 8);
    const u16x8 v2 = *(const u16x8*)(vr + 16);
#pragma unroll
    for (int d = 0; d < 8; ++d) {
      sVt[d * 264 + j] = v0[d];
      sVt[(8 + d) * 264 + j] = v1[d];
      sVt[(16 + d) * 264 + j] = v2[d];
    }
  }
  bf16x8 aQ;
  if (lg < 3) {
    const u16x8 q = *(const u16x8*)&Q[(size_t)(b * N_ + i0 + (w << 4) + lr) * stride + hh * HD_ + lg * 8];
    union { u16x8 a; bf16x8 b; } u; u.a = q;
    aQ = u.b;
  } else {
    bf16x8 t = {0, 0, 0, 0, 0, 0, 0, 0};
    aQ = t;
  }
  __syncthreads();

  f32x4 acc[16];
#pragma unroll
  for (int ni = 0; ni < 16; ++ni) {
    const bf16x8 bK = *(const bf16x8*)&sK[(ni * 16 + lr) * 40 + lg * 8];
    acc[ni] = MFMA16(aQ, bK, (f32x4)0.f);
  }

  float invr[4];
#pragma unroll
  for (int r = 0; r < 4; ++r) {
    const int iloc = (w << 4) + lg * 4 + r;
    const unsigned short* bp =
        &biasb[(((size_t)(b * H_ + hh)) * N_ + i0 + iloc) * N_ + lr];
    float mx = -INFINITY;
#pragma unroll
    for (int ni = 0; ni < 16; ++ni) {
      const float s = acc[ni][r] * SCALE_ + bf2f(bp[ni * 16]);
      acc[ni][r] = s;
      mx = fmaxf(mx, s);
    }
    mx = fmaxf(mx, __shfl_xor(mx, 1));
    mx = fmaxf(mx, __shfl_xor(mx, 2));
    mx = fmaxf(mx, __shfl_xor(mx, 4));
    mx = fmaxf(mx, __shfl_xor(mx, 8));
    float sum = 0.f;
#pragma unroll
    for (int ni = 0; ni < 16; ++ni) {
      const float e = __expf(acc[ni][r] - mx);
      acc[ni][r] = e;
      sum += e;
    }
    sum += __shfl_xor(sum, 1);
    sum += __shfl_xor(sum, 2);
    sum += __shfl_xor(sum, 4);
    sum += __shfl_xor(sum, 8);
    const float inv = 1.f / sum;
    invr[r] = inv;
#pragma unroll
    for (int ni = 0; ni < 16; ++ni)
      sP[iloc * 264 + ni * 16 + lr] = f2bf(PROBS ? acc[ni][r] * inv
                                                 : acc[ni][r]);
  }
  __syncthreads();

  if (PROBS) {
#pragma unroll
    for (int it = 0; it < 8; ++it) {
      const int idx = tid + it * 256;     // < 2048
      const int row = idx >> 5, c = idx & 31;
      *(u16x8*)&aprob[(((size_t)(b * H_ + hh)) * N_ + i0 + row) * N_ + c * 8] =
          *(const u16x8*)&sP[row * 264 + c * 8];
    }
    // fused wv (strip 0 only): wv[c][b,hh,j] = sum_d V[b,j,hh,d]*fcw[hh*HD+d]
    if (blockIdx.y == 0) {
      const int j = tid;
      const unsigned short* vr = &Vp[(size_t)(b * N_ + j) * stride + hh * HD_];
      const u16x8 v0 = *(const u16x8*)vr;
      const u16x8 v1 = *(const u16x8*)(vr + 8);
      const u16x8 v2 = *(const u16x8*)(vr + 16);
      float s0 = 0.f, s1 = 0.f, s2 = 0.f;
#pragma unroll
      for (int d = 0; d < 8; ++d) {
        const float e0 = bf2f(v0[d]), e1 = bf2f(v1[d]), e2 = bf2f(v2[d]);
        s0 = fmaf(e0, f1w[hh * HD_ + d], s0);
        s0 = fmaf(e1, f1w[hh * HD_ + 8 + d], s0);
        s0 = fmaf(e2, f1w[hh * HD_ + 16 + d], s0);
        s1 = fmaf(e0, f2w[hh * HD_ + d], s1);
        s1 = fmaf(e1, f2w[hh * HD_ + 8 + d], s1);
        s1 = fmaf(e2, f2w[hh * HD_ + 16 + d], s1);
        s2 = fmaf(e0, f3w[hh * HD_ + d], s2);
        s2 = fmaf(e1, f3w[hh * HD_ + 8 + d], s2);
        s2 = fmaf(e2, f3w[hh * HD_ + 16 + d], s2);
      }
      wv[((size_t)(0 * B_ + b) * H_ + hh) * N_ + j] = s0;
      wv[((size_t)(1 * B_ + b) * H_ + hh) * N_ + j] = s1;
      wv[((size_t)(2 * B_ + b) * H_ + hh) * N_ + j] = s2;
    }
  } else {
    f32x4 accO[2];
    accO[0] = (f32x4)0.f; accO[1] = (f32x4)0.f;
#pragma unroll
    for (int ks = 0; ks < 8; ++ks) {
      const bf16x8 aP = *(const bf16x8*)&sP[((w << 4) + lr) * 264 + ks * 32 + lg * 8];
      const bf16x8 bV0 = *(const bf16x8*)&sVt[lr * 264 + ks * 32 + lg * 8];
      const bf16x8 bV1 = *(const bf16x8*)&sVt[(16 + lr) * 264 + ks * 32 + lg * 8];
      accO[0] = MFMA16(aP, bV0, accO[0]);
      accO[1] = MFMA16(aP, bV1, accO[1]);
    }
#pragma unroll
    for (int ni = 0; ni < 2; ++ni) {
      const int n = ni * 16 + lr;
      if (n < HD_) {
#pragma unroll
        for (int r = 0; r < 4; ++r) {
          const int i = i0 + (w << 4) + lg * 4 + r;
          obuf[(size_t)(b * N_ + i) * D_ + hh * HD_ + n] = f2bf(accO[ni][r] * invr[r]);
        }
      }
    }
  }
}

// ---------------------------------------------------------------------------
// Merged tail: blocks [0,BN) nodeout; blocks [BN,2*BN) engnode.
__global__ __launch_bounds__(256) void nodeout_eng_kernel(
    const unsigned short* __restrict__ aprob, const float* __restrict__ wv,
    const float* __restrict__ deltaw, const float* __restrict__ f1b,
    const float* __restrict__ f2b, const float* __restrict__ f3b,
    const unsigned short* __restrict__ t1, const int stride,
    const float* __restrict__ en_w2, const float* __restrict__ en_b2,
    const float* __restrict__ eagg, const int* __restrict__ tags,
    float* __restrict__ engpn, float* __restrict__ out)
{
  const int tid = threadIdx.x;
  __shared__ float sred[4];
  if (blockIdx.x >= B_ * N_) {
    const int bi = blockIdx.x - B_ * N_;
    const unsigned short* row = t1 + (size_t)bi * stride;
    float acc = bf2f(row[tid]) * en_w2[tid] + bf2f(row[tid + 256]) * en_w2[tid + 256] +
                bf2f(row[tid + 512]) * en_w2[tid + 512];
    acc = breduce_sum(acc, sred, tid);
    if (tid == 0) {
      const int tg = tags[bi];
      engpn[bi] = (tg > 0) ? (acc + en_b2[0]) * eagg[tg] : 0.f;
    }
    return;
  }
  const int bi = blockIdx.x;
  const int b = bi >> 8;
  const int i = bi & 255;
  const unsigned short* ap = aprob + (((size_t)b * H_) * N_ + i) * N_ + tid;
  const float* wv0 = wv + ((size_t)(0 * B_ + b) * H_) * N_ + tid;
  const float* wv1 = wv + ((size_t)(1 * B_ + b) * H_) * N_ + tid;
  const float* wv2 = wv + ((size_t)(2 * B_ + b) * H_) * N_ + tid;
  float s0 = 0.f, s1 = 0.f, s2 = 0.f;
  for (int hh = 0; hh < H_; ++hh) {
    const float p = bf2f(ap[(size_t)hh * N_ * N_]);
    s0 = fmaf(p, wv0[(size_t)hh * N_], s0);
    s1 = fmaf(p, wv1[(size_t)hh * N_], s1);
    s2 = fmaf(p, wv2[(size_t)hh * N_], s2);
  }
  const float* dl = &deltaw[((size_t)bi * N_ + tid) * 3];
  s0 *= dl[0];
  s1 *= dl[1];
  s2 *= dl[2];
  s0 = breduce_sum(s0, sred, tid);
  s1 = breduce_sum(s1, sred, tid);
  s2 = breduce_sum(s2, sred, tid);
  if (tid == 0) {
    out[4 + bi * 3 + 0] = s0 + f1b[0];
    out[4 + bi * 3 + 1] = s1 + f2b[0];
    out[4 + bi * 3 + 2] = s2 + f3b[0];
  }
}

// engsum (blocks 0..3) + omask (blocks 4..7) merged
__global__ __launch_bounds__(256) void engsum_omask_kernel(
    const float* __restrict__ engpn, const int* __restrict__ tags,
    float* __restrict__ out)
{
  const int bid = blockIdx.x;
  const int tid = threadIdx.x;
  if (bid < 4) {
    __shared__ float sred[4];
    float v = breduce_sum(engpn[bid * N_ + tid], sred, tid);
    if (tid == 0) out[bid] = v;
  } else {
    const int idx = (bid - 4) * 256 + tid;
    out[4 + B_ * N_ * 3 + idx] = (tags[idx] > 0) ? 1.f : 0.f;
  }
}

// ---------------------------------------------------------------------------
extern "C" void kernel_launch(void* const* d_in, const int* in_sizes, int n_in,
                              void* d_out, int out_size, void* d_ws, size_t ws_size,
                              hipStream_t stream) {
  (void)in_sizes; (void)n_in; (void)out_size; (void)ws_size;
  const int*   atoms     = (const int*)  d_in[0];
  const int*   tags      = (const int*)  d_in[1];
  const float* pos       = (const float*)d_in[2];
  const float* atom_emb  = (const float*)d_in[4];
  const float* tag_emb   = (const float*)d_in[5];
  const float* gbf_means = (const float*)d_in[6];
  const float* gbf_stds  = (const float*)d_in[7];
  const float* gbf_mul   = (const float*)d_in[8];
  const float* gbf_bias  = (const float*)d_in[9];
  const float* bp_w1     = (const float*)d_in[10];
  const float* bp_b1     = (const float*)d_in[11];
  const float* bp_w2     = (const float*)d_in[12];
  const float* bp_b2     = (const float*)d_in[13];
  const float* ep_w      = (const float*)d_in[14];
  const float* ep_b      = (const float*)d_in[15];
  const float* ln1_g     = (const float*)d_in[16];
  const float* ln1_b     = (const float*)d_in[17];
  const float* wqkv      = (const float*)d_in[18];
  const float* bqkv      = (const float*)d_in[19];
  const float* wo        = (const float*)d_in[20];
  const float* bo        = (const float*)d_in[21];
  const float* ln2_g     = (const float*)d_in[22];
  const float* ln2_b     = (const float*)d_in[23];
  const float* w1        = (const float*)d_in[24];
  const float* b1        = (const float*)d_in[25];
  const float* w2        = (const float*)d_in[26];
  const float* b2        = (const float*)d_in[27];
  const float* fln_g     = (const float*)d_in[28];
  const float* fln_b     = (const float*)d_in[29];
  const float* en_w1     = (const float*)d_in[30];
  const float* en_b1     = (const float*)d_in[31];
  const float* en_w2     = (const float*)d_in[32];
  const float* en_b2     = (const float*)d_in[33];
  const float* eagg      = (const float*)d_in[34];
  const float* nq_w      = (const float*)d_in[35];
  const float* nq_b      = (const float*)d_in[36];
  const float* nk_w      = (const float*)d_in[37];
  const float* nk_b      = (const float*)d_in[38];
  const float* nv_w      = (const float*)d_in[39];
  const float* nv_b      = (const float*)d_in[40];
  const float* f1_w      = (const float*)d_in[41];
  const float* f1_b      = (const float*)d_in[42];
  const float* f2_w      = (const float*)d_in[43];
  const float* f2_b      = (const float*)d_in[44];
  const float* f3_w      = (const float*)d_in[45];
  const float* f3_b      = (const float*)d_in[46];

  char* wsB = (char*)d_ws;
  size_t off = 0;
  auto alloc = [&](size_t bytes) {
    void* p = wsB + off;
    off = (off + bytes + 255) & ~(size_t)255;
    return p;
  };
  unsigned short* biasb   = (unsigned short*)alloc((size_t)B_ * H_ * N_ * N_ * 2);
  unsigned short* aprobb  = (unsigned short*)alloc((size_t)B_ * H_ * N_ * N_ * 2);
  float*          deltaw  = (float*)alloc((size_t)B_ * N_ * N_ * 3 * 4);
  float*          xvalw   = (float*)alloc((size_t)B_ * N_ * N_ * 4);
  float*          nsumw   = (float*)alloc((size_t)B_ * N_ * K_ * 4);
  float*          hbuf    = (float*)alloc((size_t)B_ * N_ * D_ * 4);
  unsigned short* qkvb    = (unsigned short*)alloc((size_t)B_ * N_ * 3 * D_ * 2);
  unsigned short* qn4b    = (unsigned short*)alloc((size_t)B_ * N_ * 3072 * 2);
  unsigned short* ybf     = (unsigned short*)alloc((size_t)B_ * N_ * D_ * 2);
  unsigned short* obf     = (unsigned short*)alloc((size_t)B_ * N_ * D_ * 2);
  unsigned short* midbf   = (unsigned short*)alloc((size_t)B_ * N_ * F_ * 2);
  unsigned short* outbf   = (unsigned short*)alloc((size_t)B_ * N_ * D_ * 2);
  unsigned short* arena   = (unsigned short*)alloc((size_t)2 * 7077888 * 2);  // double-buffered
  unsigned short* headsb  = (unsigned short*)alloc((size_t)2359296 * 2);
  unsigned short* bw1b    = (unsigned short*)alloc((size_t)K_ * K_ * 2);
  unsigned short* bw2b    = (unsigned short*)alloc((size_t)H_ * K_ * 2);
  float*          wopart  = (float*)alloc((size_t)2 * B_ * N_ * D_ * 4);
  float*          ffpart  = (float*)alloc((size_t)4 * B_ * N_ * D_ * 4);
  float*          wvb     = (float*)alloc((size_t)3 * B_ * H_ * N_ * 4);
  float*          engpn   = (float*)alloc((size_t)B_ * N_ * 4);

  const int BN = B_ * N_;  // 1024
  float* outp = (float*)d_out;
  const size_t AR = 7077888;
  const size_t OQKV = 0, OWO = 1769472, OW1 = 2359296, OW2 = 4718592;

  // edge precompute + piggy-backed layer-0 & bias-MLP casts
  edge_pre_kernel<<<BN + 3456 + 20, 256, 0, stream>>>(
      atoms, pos, gbf_mul, gbf_bias, gbf_means, gbf_stds,
      deltaw, xvalw, nsumw,
      wqkv, wo, w1, w2, arena, bp_w1, bp_w2, bw1b, bw2b);
  bias_mfma_kernel<<<B_ * N_ * N_ / 64, 256, 0, stream>>>(
      xvalw, atoms, gbf_means, gbf_stds, bw1b, bp_b1, bw2b, bp_b2, biasb);
  node_init_kernel<<<BN, 256, 0, stream>>>(atoms, tags, atom_emb, tag_emb,
                                           nsumw, ep_w, ep_b, hbuf);
  ln_kernel<<<BN, 256, 0, stream>>>(hbuf, ln1_g, ln1_b, ybf);

  for (int l = 0; l < L_; ++l) {
    unsigned short* ar = arena + (size_t)(l & 1) * AR;
    // QKV: [1024,2304] bf16
    gemm_mfma<0, 1><<<dim3(36, 16), 256, 0, stream>>>(
        ybf, ar + OQKV, bqkv + (size_t)l * 3 * D_, nullptr, nullptr, nullptr,
        nullptr, qkvb, BN, 3 * D_, D_, D_, D_);
    attn_mfma_kernel<false><<<dim3(B_ * H_, 4), 256, 0, stream>>>(
        qkvb, qkvb + D_, qkvb + 2 * D_, 3 * D_, biasb, obf, nullptr,
        nullptr, nullptr, nullptr, nullptr);
    // wo: split-K=2 partials
    gemm_mfma<4, 0><<<dim3(12, 16, 2), 256, 0, stream>>>(
        obf, ar + OWO, nullptr, nullptr, nullptr, nullptr,
        wopart, nullptr, BN, D_, 384, D_, D_);
    // reduce + res + ln2 -> ybf, piggy-backing next layer's (or heads') cast
    if (l + 1 < L_) {
      const int lc = l + 1;
      reduce_ln_kernel<2><<<BN + 3456, 256, 0, stream>>>(
          wopart, bo + (size_t)l * D_, hbuf, ln2_g + (size_t)l * D_,
          ln2_b + (size_t)l * D_, ybf,
          wqkv + (size_t)lc * 3 * D_ * D_, wo + (size_t)lc * D_ * D_,
          w1 + (size_t)lc * F_ * D_, w2 + (size_t)lc * D_ * F_,
          arena + (size_t)(lc & 1) * AR, 1);
    } else {
      reduce_ln_kernel<2><<<BN + 1152, 256, 0, stream>>>(
          wopart, bo + (size_t)l * D_, hbuf, ln2_g + (size_t)l * D_,
          ln2_b + (size_t)l * D_, ybf,
          nq_w, nk_w, nv_w, en_w1, headsb, 2);
    }
    // FFN1: gelu -> midbf bf16
    gemm_mfma<1, 1><<<dim3(48, 16), 256, 0, stream>>>(
        ybf, ar + OW1, b1 + (size_t)l * F_, nullptr, nullptr, nullptr,
        nullptr, midbf, BN, F_, D_, D_, D_);
    // FFN2: split-K=4 partials, then reduce + res + ln1(l+1) (or fln) -> y
    gemm_mfma<4, 0><<<dim3(12, 16, 4), 256, 0, stream>>>(
        midbf, ar + OW2, nullptr, nullptr, nullptr, nullptr,
        ffpart, nullptr, BN, D_, 768, F_, F_);
    const bool last = (l == L_ - 1);
    reduce_ln_kernel<4><<<BN, 256, 0, stream>>>(
        ffpart, b2 + (size_t)l * D_, hbuf,
        last ? fln_g : ln1_g + (size_t)(l + 1) * D_,
        last ? fln_b : ln1_b + (size_t)(l + 1) * D_,
        last ? outbf : ybf,
        nullptr, nullptr, nullptr, nullptr, nullptr, 0);
  }

  // merged head GEMM: N = 3072 (q|k|v|t1), gelu on the en segment, bf16 out
  gemm_mfma<3, 1><<<dim3(48, 16), 256, 0, stream>>>(
      outbf, headsb, nq_b, nk_b, nv_b, en_b1,
      nullptr, qn4b, BN, 3072, D_, D_, D_);

  attn_mfma_kernel<true><<<dim3(B_ * H_, 4), 256, 0, stream>>>(
      qn4b, qn4b + 768, qn4b + 1536, 3072, biasb, nullptr, aprobb,
      f1_w, f2_w, f3_w, wvb);
  // merged nodeout + engnode tail
  nodeout_eng_kernel<<<2 * BN, 256, 0, stream>>>(
      aprobb, wvb, deltaw, f1_b, f2_b, f3_b,
      qn4b + 2304, 3072, en_w2, en_b2, eagg, tags, engpn, outp);
  engsum_omask_kernel<<<8, 256, 0, stream>>>(engpn, tags, outp);
}